// Round 11
// baseline (16444.502 us; speedup 1.0000x reference)
//
#include <hip/hip_runtime.h>
#include <hip/hip_bf16.h>

typedef __hip_bfloat16 bf16;
typedef unsigned short u16;

#define R_RECON 3145728
#define N_IDX   65536

// dual-dtype input load: fl=1 -> fp32 (expected), fl=0 -> bf16
__device__ __forceinline__ float ldg_in(const void* p, int i, int fl) {
  return fl ? ((const float*)p)[i] : __bfloat162float(((const bf16*)p)[i]);
}

// fp32 misread as bf16 shows |v|>16384/NaN among low-half words over 4096 samples.
__global__ __launch_bounds__(256) void k_detect(const u16* __restrict__ p, int* __restrict__ flag) {
  __shared__ int s;
  if (threadIdx.x == 0) s = 0;
  __syncthreads();
  for (int i = threadIdx.x; i < 4096; i += 256) {
    float f = __uint_as_float(((unsigned)p[i]) << 16);
    if (!(fabsf(f) < 16384.f)) atomicOr(&s, 1);
  }
  __syncthreads();
  if (threadIdx.x == 0) flag[0] = s;
}

// ---------------- enc1: stride-2 4x4 conv from global input (Cin=3) ----------------
template<bool GIN>
__global__ __launch_bounds__(256) void k_conv_s2k4(
    const void* __restrict__ inp, const void* __restrict__ w,
    const void* __restrict__ bias, float* __restrict__ out,
    const int* __restrict__ flag, int in_off,
    int Cin, int Hin, int Cout, int Hout)
{
  __shared__ float sW[1024];
  int fl = flag[0];
  int tid = threadIdx.x;
  int idx = blockIdx.x * 256 + tid;
  int hw = Hout * Hout;
  int co = (idx / hw) % Cout;          // uniform (256 divides hw)
  for (int i = tid; i < Cin * 16; i += 256)
    sW[i] = ldg_in(w, co * Cin * 16 + i, fl);
  __syncthreads();
  int ox = idx % Hout; int t = idx / Hout;
  int oy = t % Hout;
  int n = idx / (hw * Cout);
  float acc = ldg_in(bias, co, fl);
  int iy0 = 2 * oy - 1, ix0 = 2 * ox - 1;
  const float* inf = (const float*)inp;
  for (int ci = 0; ci < Cin; ++ci) {
    int base_in = (n * Cin + ci) * Hin * Hin;
    const float* wp = sW + ci * 16;
    #pragma unroll
    for (int ky = 0; ky < 4; ++ky) {
      int iy = iy0 + ky;
      if ((unsigned)iy >= (unsigned)Hin) continue;
      int rb = base_in + iy * Hin;
      #pragma unroll
      for (int kx = 0; kx < 4; ++kx) {
        int ix = ix0 + kx;
        if ((unsigned)ix >= (unsigned)Hin) continue;
        float v = GIN ? ldg_in(inp, in_off + rb + ix, fl) : inf[rb + ix];
        acc = fmaf(v, wp[ky * 4 + kx], acc);
      }
    }
  }
  out[idx] = fmaxf(acc, 0.f);
}

// ---------------- enc2: stride-2 4x4, Cin=64 Hin=64 -> Cout=128 Hout=32, 4-wide ox ----------------
__global__ __launch_bounds__(256) void k_enc2(
    const float* __restrict__ in, const void* __restrict__ w,
    const void* __restrict__ bias, float* __restrict__ out,
    const int* __restrict__ flag)
{
  const int Cin = 64, Hin = 64, Cout = 128;
  __shared__ float sW[1024];           // 64*16
  int fl = flag[0];
  int bid = blockIdx.x;
  int co = bid % Cout, n = bid / Cout;
  int tid = threadIdx.x;
  for (int i = tid; i < Cin * 16; i += 256)
    sW[i] = ldg_in(w, co * Cin * 16 + i, fl);
  __syncthreads();
  int oy = tid >> 3, ox0 = (tid & 7) << 2;
  float bv = ldg_in(bias, co, fl);
  float a0 = bv, a1 = bv, a2 = bv, a3 = bv;
  int ry0 = 2 * oy - 1;                // rows ry0..ry0+3
  int cx0 = 2 * ox0 - 1;               // cols cx0..cx0+9
  const float* ip = in + (size_t)n * Cin * Hin * Hin;
  for (int ci = 0; ci < Cin; ++ci) {
    const float* p = ip + ci * 4096;
    float x[4][10];
    #pragma unroll
    for (int r = 0; r < 4; ++r) {
      int iy = ry0 + r;
      bool vr = (unsigned)iy < 64u;
      const float* rp = p + iy * 64;
      #pragma unroll
      for (int c = 0; c < 10; ++c) {
        int ix = cx0 + c;
        x[r][c] = (vr && (unsigned)ix < 64u) ? rp[ix] : 0.f;
      }
    }
    const float* W = sW + ci * 16;
    #pragma unroll
    for (int ky = 0; ky < 4; ++ky)
      #pragma unroll
      for (int kx = 0; kx < 4; ++kx) {
        float wv = W[ky * 4 + kx];
        a0 = fmaf(wv, x[ky][kx], a0);
        a1 = fmaf(wv, x[ky][2 + kx], a1);
        a2 = fmaf(wv, x[ky][4 + kx], a2);
        a3 = fmaf(wv, x[ky][6 + kx], a3);
      }
  }
  float* op = out + (size_t)(n * Cout + co) * 1024 + oy * 32 + ox0;
  op[0] = fmaxf(a0, 0.f); op[1] = fmaxf(a1, 0.f);
  op[2] = fmaxf(a2, 0.f); op[3] = fmaxf(a3, 0.f);
}

// ---------------- 3x3 conv s1 p1 @32x32: 2x4 register tile, 2 co per block ----------------
// TRANS_W: torch ConvTranspose layout (I,O,3,3); flip applied at staging.
template<bool IN_RELU, bool TRANS_W, bool OUT_RELU, bool HAS_BIAS>
__global__ __launch_bounds__(256) void k_conv3x3_t2(
    const float* __restrict__ in, const void* __restrict__ w,
    const void* __restrict__ bias, float* __restrict__ out,
    const int* __restrict__ flag, int Cin, int Cout)
{
  const int HW = 1024;
  __shared__ float sW[2304];           // 2 * Cin*9, Cin<=128
  int fl = flag[0];
  int nh = Cout >> 1;
  int bid = blockIdx.x;
  int cp = bid % nh, n = bid / nh;
  int co0 = cp * 2;
  int tid = threadIdx.x;
  int tot = 2 * Cin * 9;
  for (int i = tid; i < tot; i += 256) {
    int cl = i / (Cin * 9), rem = i % (Cin * 9);
    int ci = rem / 9, k = rem % 9;
    int src = TRANS_W ? ((ci * Cout + co0 + cl) * 9 + (8 - k))
                      : (((co0 + cl) * Cin + ci) * 9 + k);
    sW[i] = ldg_in(w, src, fl);
  }
  __syncthreads();
  int half = tid >> 7;                 // co selector (uniform per wave)
  int tt = tid & 127;
  int r2 = tt >> 3;                    // 0..15
  int c4 = tt & 7;                     // 0..7
  int co = co0 + half;
  int oy0 = r2 * 2, ox0 = c4 * 4;
  const float* Wb = sW + half * Cin * 9;
  float bv = HAS_BIAS ? ldg_in(bias, co, fl) : 0.f;
  float acc[2][4];
  #pragma unroll
  for (int r = 0; r < 2; ++r)
    #pragma unroll
    for (int q = 0; q < 4; ++q) acc[r][q] = bv;
  const float* ip = in + (size_t)n * Cin * HW;
  for (int ci = 0; ci < Cin; ++ci) {
    const float* p = ip + ci * HW;
    float x[4][6];
    #pragma unroll
    for (int r = 0; r < 4; ++r) {
      int iy = oy0 - 1 + r;
      bool vr = (unsigned)iy < 32u;
      const float* rp = p + iy * 32;
      #pragma unroll
      for (int c = 0; c < 6; ++c) {
        int ix = ox0 - 1 + c;
        float v = (vr && (unsigned)ix < 32u) ? rp[ix] : 0.f;
        if (IN_RELU) v = fmaxf(v, 0.f);
        x[r][c] = v;
      }
    }
    const float* W = Wb + ci * 9;
    #pragma unroll
    for (int ky = 0; ky < 3; ++ky)
      #pragma unroll
      for (int kx = 0; kx < 3; ++kx) {
        float wv = W[ky * 3 + kx];
        #pragma unroll
        for (int r = 0; r < 2; ++r)
          #pragma unroll
          for (int q = 0; q < 4; ++q)
            acc[r][q] = fmaf(wv, x[r + ky][q + kx], acc[r][q]);
      }
  }
  #pragma unroll
  for (int r = 0; r < 2; ++r) {
    float* op = out + (size_t)(n * Cout + co) * HW + (oy0 + r) * 32 + ox0;
    #pragma unroll
    for (int q = 0; q < 4; ++q) {
      float v = acc[r][q];
      if (OUT_RELU) v = fmaxf(v, 0.f);
      op[q] = v;
    }
  }
}

// ---------------- 1x1 conv @32x32: 4co x 4p register tile ----------------
template<bool ACCUM, bool HAS_BIAS, bool OUT_RELU>
__global__ __launch_bounds__(256) void k_conv1x1_t4(
    const float* __restrict__ in, const void* __restrict__ w,
    const void* __restrict__ bias, float* __restrict__ out,
    const int* __restrict__ flag, int Cin, int Cout)
{
  const int HW = 1024;
  __shared__ float sW[512];            // 4 * Cin, Cin<=128
  int fl = flag[0];
  int nq = Cout >> 2;
  int bid = blockIdx.x;
  int qc = bid % nq, n = bid / nq;
  int co0 = qc * 4;
  int tid = threadIdx.x;
  for (int i = tid; i < 4 * Cin; i += 256)
    sW[i] = ldg_in(w, co0 * Cin + i, fl);   // (co0+c)*Cin+ci == co0*Cin + i
  __syncthreads();
  float acc[4][4];
  #pragma unroll
  for (int c = 0; c < 4; ++c) {
    float bv = HAS_BIAS ? ldg_in(bias, co0 + c, fl) : 0.f;
    #pragma unroll
    for (int k = 0; k < 4; ++k) acc[c][k] = bv;
  }
  const float* ip = in + (size_t)n * Cin * HW + tid;
  for (int ci = 0; ci < Cin; ++ci) {
    const float* p = ip + ci * HW;
    float x0 = p[0], x1 = p[256], x2 = p[512], x3 = p[768];
    #pragma unroll
    for (int c = 0; c < 4; ++c) {
      float wv = sW[c * Cin + ci];
      acc[c][0] = fmaf(wv, x0, acc[c][0]);
      acc[c][1] = fmaf(wv, x1, acc[c][1]);
      acc[c][2] = fmaf(wv, x2, acc[c][2]);
      acc[c][3] = fmaf(wv, x3, acc[c][3]);
    }
  }
  #pragma unroll
  for (int c = 0; c < 4; ++c) {
    float* op = out + (size_t)(n * Cout + co0 + c) * HW + tid;
    #pragma unroll
    for (int k = 0; k < 4; ++k) {
      float v = acc[c][k];
      if (ACCUM) v += op[k * 256];
      if (OUT_RELU) v = fmaxf(v, 0.f);
      op[k * 256] = v;
    }
  }
}

// ---------------- ConvTranspose s2 k4 p1: parity-quad form ----------------
// Output quad (2qa..2qa+1, 2qb..2qb+1) uses input rows qa-1..qa+1, cols qb-1..qb+1:
//  y[0][0]=w11*x11+w13*x10+w31*x01+w33*x00   y[0][1]=w10*x12+w12*x11+w30*x02+w32*x01
//  y[1][0]=w01*x21+w03*x20+w21*x11+w23*x10   y[1][1]=w00*x22+w02*x21+w20*x12+w22*x11
// (x[r][c]: r=0 row qa-1, r=1 row qa, r=2 row qa+1; verified against gather form)
template<bool OUT_RELU, int HQ>
__global__ __launch_bounds__(256) void k_convT_quad(
    const float* __restrict__ in, const void* __restrict__ w,
    const void* __restrict__ bias, float* __restrict__ out,
    const int* __restrict__ flag, int Cin, int Cout)
{
  constexpr int HO = HQ * 2;
  constexpr int QPB = (HQ * HQ) / 1024; // sub-tiles per (n,co)
  constexpr int LPR = HQ / 4;           // lanes per quad-row
  constexpr int RPB = 256 / LPR;        // quad-rows per block
  __shared__ float sW[2048];            // Cin*16, Cin<=128
  int fl = flag[0];
  int bid = blockIdx.x;
  int s = bid % QPB;
  int t2 = bid / QPB;
  int co = t2 % Cout;
  int n = t2 / Cout;
  int tid = threadIdx.x;
  for (int i = tid; i < Cin * 16; i += 256)
    sW[i] = ldg_in(w, ((i >> 4) * Cout + co) * 16 + (i & 15), fl);
  __syncthreads();
  int qa = s * RPB + tid / LPR;
  int qb0 = (tid % LPR) * 4;
  float bv = ldg_in(bias, co, fl);
  float a00[4], a01[4], a10[4], a11[4];
  #pragma unroll
  for (int j = 0; j < 4; ++j) { a00[j] = bv; a01[j] = bv; a10[j] = bv; a11[j] = bv; }
  const float* ip = in + (size_t)n * Cin * HQ * HQ;
  bool v0 = qa >= 1, v2 = qa + 1 < HQ;
  for (int ci = 0; ci < Cin; ++ci) {
    const float* p = ip + ci * HQ * HQ;
    const float* r0 = p + (qa - 1) * HQ;
    const float* r1 = p + qa * HQ;
    const float* r2 = p + (qa + 1) * HQ;
    float x0[6], x1[6], x2[6];
    #pragma unroll
    for (int c = 0; c < 6; ++c) {
      int ix = qb0 - 1 + c;
      bool vc = (unsigned)ix < (unsigned)HQ;
      x0[c] = (v0 && vc) ? r0[ix] : 0.f;
      x1[c] = vc ? r1[ix] : 0.f;
      x2[c] = (v2 && vc) ? r2[ix] : 0.f;
    }
    const float* W = sW + ci * 16;
    float w00 = W[0], w01 = W[1], w02 = W[2], w03 = W[3];
    float w10 = W[4], w11 = W[5], w12 = W[6], w13 = W[7];
    float w20 = W[8], w21 = W[9], w22 = W[10], w23 = W[11];
    float w30 = W[12], w31 = W[13], w32 = W[14], w33 = W[15];
    #pragma unroll
    for (int j = 0; j < 4; ++j) {
      a00[j] = fmaf(w11, x1[j+1], fmaf(w13, x1[j],   fmaf(w31, x0[j+1], fmaf(w33, x0[j],   a00[j]))));
      a01[j] = fmaf(w10, x1[j+2], fmaf(w12, x1[j+1], fmaf(w30, x0[j+2], fmaf(w32, x0[j+1], a01[j]))));
      a10[j] = fmaf(w01, x2[j+1], fmaf(w03, x2[j],   fmaf(w21, x1[j+1], fmaf(w23, x1[j],   a10[j]))));
      a11[j] = fmaf(w00, x2[j+2], fmaf(w02, x2[j+1], fmaf(w20, x1[j+2], fmaf(w22, x1[j+1], a11[j]))));
    }
  }
  float* op = out + ((size_t)(n * Cout + co) * HO + 2 * qa) * HO + 2 * qb0;
  #pragma unroll
  for (int j = 0; j < 4; ++j) {
    float y00 = a00[j], y01 = a01[j], y10 = a10[j], y11 = a11[j];
    if (OUT_RELU) {
      y00 = fmaxf(y00, 0.f); y01 = fmaxf(y01, 0.f);
      y10 = fmaxf(y10, 0.f); y11 = fmaxf(y11, 0.f);
    }
    op[2*j] = y00; op[2*j + 1] = y01;
    op[HO + 2*j] = y10; op[HO + 2*j + 1] = y11;
  }
}

// ---------------- VQ: argmin (first-min), zq in-place, idx (fp32) to d_out ----------------
__global__ __launch_bounds__(256) void k_vq(
    const float* __restrict__ z, const void* __restrict__ emb,
    float* __restrict__ zq, float* __restrict__ idx_out,
    const int* __restrict__ flag, float* __restrict__ lossp, int lossbase)
{
  __shared__ float sE[8192];
  __shared__ float sEE[128];
  __shared__ float wsum[4];
  int fl = flag[0];
  int tid = threadIdx.x;
  int n = blockIdx.x * 256 + tid;
  int nb = n >> 10, p = n & 1023;
  const float* zp = z + nb * 65536 + p;
  float zv[64];
  float zz = 0.f;
  #pragma unroll
  for (int d = 0; d < 64; ++d) { zv[d] = zp[d * 1024]; zz = fmaf(zv[d], zv[d], zz); }
  float best = 3.4e38f; int bidx = 0;
  for (int kb = 0; kb < 8; ++kb) {
    __syncthreads();
    for (int i = tid; i < 8192; i += 256) sE[i] = ldg_in(emb, kb * 8192 + i, fl);
    __syncthreads();
    if (tid < 128) {
      float s = 0.f;
      #pragma unroll
      for (int d = 0; d < 64; ++d) s = fmaf(sE[tid * 64 + d], sE[tid * 64 + d], s);
      sEE[tid] = s;
    }
    __syncthreads();
    for (int k = 0; k < 128; ++k) {
      const float* ep = sE + k * 64;
      float dot = 0.f;
      #pragma unroll
      for (int d = 0; d < 64; ++d) dot = fmaf(zv[d], ep[d], dot);
      float dist = zz + sEE[k] - 2.f * dot;
      if (dist < best) { best = dist; bidx = kb * 128 + k; }  // strict <: first min wins
    }
  }
  idx_out[n] = (float)bidx;
  float ls = 0.f;
  float* qp = zq + nb * 65536 + p;
  #pragma unroll
  for (int d = 0; d < 64; ++d) {
    float e = ldg_in(emb, bidx * 64 + d, fl);
    qp[d * 1024] = e;                  // in-place over z: thread owns its column
    float df = e - zv[d];
    ls = fmaf(df, df, ls);
  }
  #pragma unroll
  for (int off = 32; off > 0; off >>= 1) ls += __shfl_down(ls, off);
  if ((tid & 63) == 0) wsum[tid >> 6] = ls;
  __syncthreads();
  if (tid == 0) lossp[lossbase + blockIdx.x] = wsum[0] + wsum[1] + wsum[2] + wsum[3];
}

__global__ void k_loss_final(const float* __restrict__ lossp, float* __restrict__ out) {
  if (threadIdx.x == 0 && blockIdx.x == 0) {
    float s = 0.f;
    for (int i = 0; i < 256; ++i) s += lossp[i];
    float L = s * (1.f / 4194304.f);   // mean over 64*32*32*64
    out[R_RECON + 0] = L;              // codebook_loss
    out[R_RECON + 1] = L;              // commitment_loss (identical forward value)
  }
}

extern "C" void kernel_launch(void* const* d_in, const int* in_sizes, int n_in,
                              void* d_out, int out_size, void* d_ws, size_t ws_size,
                              hipStream_t stream)
{
  float* out = (float*)d_out;          // output is fp32 (established R8-R10)

  float* F = (float*)d_ws;
  float* LOSSP = F;
  int* FLAG = (int*)(F + 256);
  float* A = F + 272;

  int Bc = 64;
  while (Bc > 1 && 4ull * (272ull + (size_t)Bc * 393216ull) > ws_size) Bc >>= 1;
  float* H1 = A;                               // [0, Bc*262144)
  float* H2 = A + (size_t)Bc * 262144;         // [.., Bc*393216)
  float* H3 = A;                               // reuses H1 (dead)
  float* T  = A + (size_t)Bc * 131072;
  float* Z  = A + (size_t)Bc * 163840;
  float* D1 = H2;
  float* D2 = A;

  const void* patch = d_in[0];
  const void* ew1 = d_in[1];  const void* eb1 = d_in[2];
  const void* ew2 = d_in[3];  const void* eb2 = d_in[4];
  const void* ew3 = d_in[5];  const void* eb3 = d_in[6];
  const void* er1a = d_in[7]; const void* er1b = d_in[8];
  const void* er2a = d_in[9]; const void* er2b = d_in[10];
  const void* pqw = d_in[11]; const void* pqb = d_in[12];
  const void* emb = d_in[13];
  const void* dw1 = d_in[14]; const void* db1 = d_in[15];
  const void* dr1a = d_in[16]; const void* dr1b = d_in[17];
  const void* dr2a = d_in[18]; const void* dr2b = d_in[19];
  const void* dw2 = d_in[20]; const void* db2 = d_in[21];
  const void* dw3 = d_in[22]; const void* db3 = d_in[23];

  k_detect<<<1, 256, 0, stream>>>((const u16*)patch, FLAG);

  int NC = 64 / Bc;
  for (int c = 0; c < NC; ++c) {
    int b0 = c * Bc;

    // ---- encoder ----
    k_conv_s2k4<true><<<Bc * 1024, 256, 0, stream>>>(patch, ew1, eb1, H1, FLAG,
                                                     b0 * 49152, 3, 128, 64, 64);
    k_enc2<<<Bc * 128, 256, 0, stream>>>(H1, ew2, eb2, H2, FLAG);
    k_conv3x3_t2<false, false, false, true><<<Bc * 64, 256, 0, stream>>>(H2, ew3, eb3, H3, FLAG, 128, 128);
    // res1: T = relu(conv3x3(relu(x))); x += conv1x1(T)    (x stays pre-relu)
    k_conv3x3_t2<true, false, true, false><<<Bc * 16, 256, 0, stream>>>(H3, er1a, nullptr, T, FLAG, 128, 32);
    k_conv1x1_t4<true, false, false><<<Bc * 32, 256, 0, stream>>>(T, er1b, nullptr, H3, FLAG, 32, 128);
    // res2: same, but final relu fused into the accumulate write
    k_conv3x3_t2<true, false, true, false><<<Bc * 16, 256, 0, stream>>>(H3, er2a, nullptr, T, FLAG, 128, 32);
    k_conv1x1_t4<true, false, true><<<Bc * 32, 256, 0, stream>>>(T, er2b, nullptr, H3, FLAG, 32, 128);
    // pre-quant 1x1 (input already relu'd at res2 write)
    k_conv1x1_t4<false, true, false><<<Bc * 16, 256, 0, stream>>>(H3, pqw, pqb, Z, FLAG, 128, 64);

    // ---- VQ ----
    k_vq<<<Bc * 4, 256, 0, stream>>>(Z, emb, Z, out + R_RECON + 2 + (size_t)b0 * 1024,
                                     FLAG, LOSSP, b0 * 4);

    // ---- decoder ----
    k_conv3x3_t2<false, true, false, true><<<Bc * 64, 256, 0, stream>>>(Z, dw1, db1, D1, FLAG, 64, 128);
    k_conv3x3_t2<true, false, true, false><<<Bc * 16, 256, 0, stream>>>(D1, dr1a, nullptr, T, FLAG, 128, 32);
    k_conv1x1_t4<true, false, false><<<Bc * 32, 256, 0, stream>>>(T, dr1b, nullptr, D1, FLAG, 32, 128);
    k_conv3x3_t2<true, false, true, false><<<Bc * 16, 256, 0, stream>>>(D1, dr2a, nullptr, T, FLAG, 128, 32);
    k_conv1x1_t4<true, false, true><<<Bc * 32, 256, 0, stream>>>(T, dr2b, nullptr, D1, FLAG, 32, 128);
    // up1 (input relu'd at res2 write; output relu'd)
    k_convT_quad<true, 32><<<Bc * 64, 256, 0, stream>>>(D1, dw2, db2, D2, FLAG, 128, 64);
    // up2 -> recon (fp32 straight to d_out)
    k_convT_quad<false, 64><<<Bc * 12, 256, 0, stream>>>(D2, dw3, db3,
                                     out + (size_t)b0 * 49152, FLAG, 64, 3);
  }

  k_loss_final<<<1, 64, 0, stream>>>(LOSSP, out);
}

// Round 12
// 8287.505 us; speedup vs baseline: 1.9843x; 1.9843x over previous
//
#include <hip/hip_runtime.h>
#include <hip/hip_bf16.h>

typedef __hip_bfloat16 bf16;
typedef unsigned short u16;

#define R_RECON 3145728
#define N_IDX   65536

// dual-dtype input load: fl=1 -> fp32 (expected), fl=0 -> bf16
__device__ __forceinline__ float ldg_in(const void* p, int i, int fl) {
  return fl ? ((const float*)p)[i] : __bfloat162float(((const bf16*)p)[i]);
}

__global__ __launch_bounds__(256) void k_detect(const u16* __restrict__ p, int* __restrict__ flag) {
  __shared__ int s;
  if (threadIdx.x == 0) s = 0;
  __syncthreads();
  for (int i = threadIdx.x; i < 4096; i += 256) {
    float f = __uint_as_float(((unsigned)p[i]) << 16);
    if (!(fabsf(f) < 16384.f)) atomicOr(&s, 1);
  }
  __syncthreads();
  if (threadIdx.x == 0) flag[0] = s;
}

// ---------------- enc1: stride-2 4x4 conv from global input (Cin=3) ----------------
template<bool GIN>
__global__ __launch_bounds__(256) void k_conv_s2k4(
    const void* __restrict__ inp, const void* __restrict__ w,
    const void* __restrict__ bias, float* __restrict__ out,
    const int* __restrict__ flag, int in_off,
    int Cin, int Hin, int Cout, int Hout)
{
  __shared__ float sW[1024];
  int fl = flag[0];
  int tid = threadIdx.x;
  int idx = blockIdx.x * 256 + tid;
  int hw = Hout * Hout;
  int co = (idx / hw) % Cout;          // uniform (256 divides hw)
  for (int i = tid; i < Cin * 16; i += 256)
    sW[i] = ldg_in(w, co * Cin * 16 + i, fl);
  __syncthreads();
  int ox = idx % Hout; int t = idx / Hout;
  int oy = t % Hout;
  int n = idx / (hw * Cout);
  float acc = ldg_in(bias, co, fl);
  int iy0 = 2 * oy - 1, ix0 = 2 * ox - 1;
  const float* inf = (const float*)inp;
  for (int ci = 0; ci < Cin; ++ci) {
    int base_in = (n * Cin + ci) * Hin * Hin;
    const float* wp = sW + ci * 16;
    #pragma unroll
    for (int ky = 0; ky < 4; ++ky) {
      int iy = iy0 + ky;
      if ((unsigned)iy >= (unsigned)Hin) continue;
      int rb = base_in + iy * Hin;
      #pragma unroll
      for (int kx = 0; kx < 4; ++kx) {
        int ix = ix0 + kx;
        if ((unsigned)ix >= (unsigned)Hin) continue;
        float v = GIN ? ldg_in(inp, in_off + rb + ix, fl) : inf[rb + ix];
        acc = fmaf(v, wp[ky * 4 + kx], acc);
      }
    }
  }
  out[idx] = fmaxf(acc, 0.f);
}

// ---------------- enc2: stride-2 4x4, Cin=64 Hin=64 -> Cout=128 Hout=32 ----------------
// Row-wise SCALAR windows (no per-thread array -> no scratch spill; R11 lesson:
// x[4][10] array spilled at VGPR_Count=36 and cost 8.5 ms).
__global__ __launch_bounds__(256) void k_enc2(
    const float* __restrict__ in, const void* __restrict__ w,
    const void* __restrict__ bias, float* __restrict__ out,
    const int* __restrict__ flag)
{
  const int Cin = 64, Cout = 128;
  __shared__ float sW[1024];           // 64*16
  int fl = flag[0];
  int bid = blockIdx.x;
  int co = bid % Cout, n = bid / Cout;
  int tid = threadIdx.x;
  for (int i = tid; i < Cin * 16; i += 256)
    sW[i] = ldg_in(w, co * Cin * 16 + i, fl);
  __syncthreads();
  int oy = tid >> 3, ox0 = (tid & 7) << 2;
  float bv = ldg_in(bias, co, fl);
  float a0 = bv, a1 = bv, a2 = bv, a3 = bv;
  int ry0 = 2 * oy - 1;
  int cx0 = 2 * ox0 - 1;               // -1..55; cols cx0..cx0+9
  const float* ip = in + (size_t)n * Cin * 4096;
  for (int ci = 0; ci < Cin; ++ci) {
    const float* p = ip + ci * 4096;
    const float* W = sW + ci * 16;
    #pragma unroll
    for (int ky = 0; ky < 4; ++ky) {
      int iy = ry0 + ky;
      if ((unsigned)iy < 64u) {
        const float* rp = p + iy * 64;
        float x0 = (cx0 >= 0) ? rp[cx0] : 0.f;
        float x1 = rp[cx0 + 1], x2 = rp[cx0 + 2], x3 = rp[cx0 + 3], x4 = rp[cx0 + 4];
        float x5 = rp[cx0 + 5], x6 = rp[cx0 + 6], x7 = rp[cx0 + 7], x8 = rp[cx0 + 8];
        float x9 = (cx0 + 9 < 64) ? rp[cx0 + 9] : 0.f;
        float w0 = W[ky * 4], w1 = W[ky * 4 + 1], w2 = W[ky * 4 + 2], w3 = W[ky * 4 + 3];
        a0 = fmaf(x0, w0, fmaf(x1, w1, fmaf(x2, w2, fmaf(x3, w3, a0))));
        a1 = fmaf(x2, w0, fmaf(x3, w1, fmaf(x4, w2, fmaf(x5, w3, a1))));
        a2 = fmaf(x4, w0, fmaf(x5, w1, fmaf(x6, w2, fmaf(x7, w3, a2))));
        a3 = fmaf(x6, w0, fmaf(x7, w1, fmaf(x8, w2, fmaf(x9, w3, a3))));
      }
    }
  }
  float* op = out + (size_t)(n * Cout + co) * 1024 + oy * 32 + ox0;
  op[0] = fmaxf(a0, 0.f); op[1] = fmaxf(a1, 0.f);
  op[2] = fmaxf(a2, 0.f); op[3] = fmaxf(a3, 0.f);
}

// ---------------- 3x3 conv s1 p1 @32x32: 2x4 tile, 2 co/block, scalar rows ----------------
// TRANS_W: torch ConvTranspose layout (I,O,3,3); flip applied at staging.
template<bool IN_RELU, bool TRANS_W, bool OUT_RELU, bool HAS_BIAS>
__global__ __launch_bounds__(256) void k_conv3x3_t2(
    const float* __restrict__ in, const void* __restrict__ w,
    const void* __restrict__ bias, float* __restrict__ out,
    const int* __restrict__ flag, int Cin, int Cout)
{
  const int HW = 1024;
  __shared__ float sW[2304];           // 2 * Cin*9, Cin<=128
  int fl = flag[0];
  int nh = Cout >> 1;
  int bid = blockIdx.x;
  int cp = bid % nh, n = bid / nh;
  int co0 = cp * 2;
  int tid = threadIdx.x;
  int tot = 2 * Cin * 9;
  for (int i = tid; i < tot; i += 256) {
    int cl = i / (Cin * 9), rem = i % (Cin * 9);
    int ci = rem / 9, k = rem % 9;
    int src = TRANS_W ? ((ci * Cout + co0 + cl) * 9 + (8 - k))
                      : (((co0 + cl) * Cin + ci) * 9 + k);
    sW[i] = ldg_in(w, src, fl);
  }
  __syncthreads();
  int half = tid >> 7;                 // co selector (uniform per wave)
  int tt = tid & 127;
  int r2 = tt >> 3;                    // 0..15
  int c4 = tt & 7;                     // 0..7
  int co = co0 + half;
  int oy0 = r2 * 2, ox0 = c4 * 4;
  const float* Wb = sW + half * Cin * 9;
  float bv = HAS_BIAS ? ldg_in(bias, co, fl) : 0.f;
  float acc[2][4];
  #pragma unroll
  for (int r = 0; r < 2; ++r)
    #pragma unroll
    for (int q = 0; q < 4; ++q) acc[r][q] = bv;
  const float* ip = in + (size_t)n * Cin * HW;
  for (int ci = 0; ci < Cin; ++ci) {
    const float* p = ip + ci * HW;
    const float* W = Wb + ci * 9;
    #pragma unroll
    for (int r = 0; r < 4; ++r) {
      int iy = oy0 - 1 + r;
      if ((unsigned)iy < 32u) {
        const float* rp = p + iy * 32;
        float x0, x5;
        {
          int ix = ox0 - 1;
          x0 = ((unsigned)ix < 32u) ? rp[ix] : 0.f;
          ix = ox0 + 4;
          x5 = ((unsigned)ix < 32u) ? rp[ix] : 0.f;
        }
        float x1 = rp[ox0], x2 = rp[ox0 + 1], x3 = rp[ox0 + 2], x4 = rp[ox0 + 3];
        if (IN_RELU) {
          x0 = fmaxf(x0, 0.f); x1 = fmaxf(x1, 0.f); x2 = fmaxf(x2, 0.f);
          x3 = fmaxf(x3, 0.f); x4 = fmaxf(x4, 0.f); x5 = fmaxf(x5, 0.f);
        }
        #pragma unroll
        for (int t = 0; t < 2; ++t) {
          int ky = r - t;              // compile-time after unroll
          if (ky >= 0 && ky <= 2) {
            float w0 = W[ky * 3], w1 = W[ky * 3 + 1], w2 = W[ky * 3 + 2];
            acc[t][0] = fmaf(x0, w0, fmaf(x1, w1, fmaf(x2, w2, acc[t][0])));
            acc[t][1] = fmaf(x1, w0, fmaf(x2, w1, fmaf(x3, w2, acc[t][1])));
            acc[t][2] = fmaf(x2, w0, fmaf(x3, w1, fmaf(x4, w2, acc[t][2])));
            acc[t][3] = fmaf(x3, w0, fmaf(x4, w1, fmaf(x5, w2, acc[t][3])));
          }
        }
      }
    }
  }
  #pragma unroll
  for (int r = 0; r < 2; ++r) {
    float* op = out + (size_t)(n * Cout + co) * HW + (oy0 + r) * 32 + ox0;
    #pragma unroll
    for (int q = 0; q < 4; ++q) {
      float v = acc[r][q];
      if (OUT_RELU) v = fmaxf(v, 0.f);
      op[q] = v;
    }
  }
}

// ---------------- 1x1 conv @32x32: 4co x 4p register tile ----------------
template<bool ACCUM, bool HAS_BIAS, bool OUT_RELU>
__global__ __launch_bounds__(256) void k_conv1x1_t4(
    const float* __restrict__ in, const void* __restrict__ w,
    const void* __restrict__ bias, float* __restrict__ out,
    const int* __restrict__ flag, int Cin, int Cout)
{
  const int HW = 1024;
  __shared__ float sW[512];            // 4 * Cin, Cin<=128
  int fl = flag[0];
  int nq = Cout >> 2;
  int bid = blockIdx.x;
  int qc = bid % nq, n = bid / nq;
  int co0 = qc * 4;
  int tid = threadIdx.x;
  for (int i = tid; i < 4 * Cin; i += 256)
    sW[i] = ldg_in(w, co0 * Cin + i, fl);
  __syncthreads();
  float acc[4][4];
  #pragma unroll
  for (int c = 0; c < 4; ++c) {
    float bv = HAS_BIAS ? ldg_in(bias, co0 + c, fl) : 0.f;
    #pragma unroll
    for (int k = 0; k < 4; ++k) acc[c][k] = bv;
  }
  const float* ip = in + (size_t)n * Cin * HW + tid;
  for (int ci = 0; ci < Cin; ++ci) {
    const float* p = ip + ci * HW;
    float x0 = p[0], x1 = p[256], x2 = p[512], x3 = p[768];
    #pragma unroll
    for (int c = 0; c < 4; ++c) {
      float wv = sW[c * Cin + ci];
      acc[c][0] = fmaf(wv, x0, acc[c][0]);
      acc[c][1] = fmaf(wv, x1, acc[c][1]);
      acc[c][2] = fmaf(wv, x2, acc[c][2]);
      acc[c][3] = fmaf(wv, x3, acc[c][3]);
    }
  }
  #pragma unroll
  for (int c = 0; c < 4; ++c) {
    float* op = out + (size_t)(n * Cout + co0 + c) * HW + tid;
    #pragma unroll
    for (int k = 0; k < 4; ++k) {
      float v = acc[c][k];
      if (ACCUM) v += op[k * 256];
      if (OUT_RELU) v = fmaxf(v, 0.f);
      op[k * 256] = v;
    }
  }
}

// ---------------- ConvTranspose s2 k4 p1: parity-quad form ----------------
template<bool OUT_RELU, int HQ>
__global__ __launch_bounds__(256) void k_convT_quad(
    const float* __restrict__ in, const void* __restrict__ w,
    const void* __restrict__ bias, float* __restrict__ out,
    const int* __restrict__ flag, int Cin, int Cout)
{
  constexpr int HO = HQ * 2;
  constexpr int QPB = (HQ * HQ) / 1024;
  constexpr int LPR = HQ / 4;
  constexpr int RPB = 256 / LPR;
  __shared__ float sW[2048];
  int fl = flag[0];
  int bid = blockIdx.x;
  int s = bid % QPB;
  int t2 = bid / QPB;
  int co = t2 % Cout;
  int n = t2 / Cout;
  int tid = threadIdx.x;
  for (int i = tid; i < Cin * 16; i += 256)
    sW[i] = ldg_in(w, ((i >> 4) * Cout + co) * 16 + (i & 15), fl);
  __syncthreads();
  int qa = s * RPB + tid / LPR;
  int qb0 = (tid % LPR) * 4;
  float bv = ldg_in(bias, co, fl);
  float a00[4], a01[4], a10[4], a11[4];
  #pragma unroll
  for (int j = 0; j < 4; ++j) { a00[j] = bv; a01[j] = bv; a10[j] = bv; a11[j] = bv; }
  const float* ip = in + (size_t)n * Cin * HQ * HQ;
  bool v0 = qa >= 1, v2 = qa + 1 < HQ;
  for (int ci = 0; ci < Cin; ++ci) {
    const float* p = ip + ci * HQ * HQ;
    const float* r0 = p + (qa - 1) * HQ;
    const float* r1 = p + qa * HQ;
    const float* r2 = p + (qa + 1) * HQ;
    float x0[6], x1[6], x2[6];
    #pragma unroll
    for (int c = 0; c < 6; ++c) {
      int ix = qb0 - 1 + c;
      bool vc = (unsigned)ix < (unsigned)HQ;
      x0[c] = (v0 && vc) ? r0[ix] : 0.f;
      x1[c] = vc ? r1[ix] : 0.f;
      x2[c] = (v2 && vc) ? r2[ix] : 0.f;
    }
    const float* W = sW + ci * 16;
    float w00 = W[0], w01 = W[1], w02 = W[2], w03 = W[3];
    float w10 = W[4], w11 = W[5], w12 = W[6], w13 = W[7];
    float w20 = W[8], w21 = W[9], w22 = W[10], w23 = W[11];
    float w30 = W[12], w31 = W[13], w32 = W[14], w33 = W[15];
    #pragma unroll
    for (int j = 0; j < 4; ++j) {
      a00[j] = fmaf(w11, x1[j+1], fmaf(w13, x1[j],   fmaf(w31, x0[j+1], fmaf(w33, x0[j],   a00[j]))));
      a01[j] = fmaf(w10, x1[j+2], fmaf(w12, x1[j+1], fmaf(w30, x0[j+2], fmaf(w32, x0[j+1], a01[j]))));
      a10[j] = fmaf(w01, x2[j+1], fmaf(w03, x2[j],   fmaf(w21, x1[j+1], fmaf(w23, x1[j],   a10[j]))));
      a11[j] = fmaf(w00, x2[j+2], fmaf(w02, x2[j+1], fmaf(w20, x1[j+2], fmaf(w22, x1[j+1], a11[j]))));
    }
  }
  float* op = out + ((size_t)(n * Cout + co) * HO + 2 * qa) * HO + 2 * qb0;
  #pragma unroll
  for (int j = 0; j < 4; ++j) {
    float y00 = a00[j], y01 = a01[j], y10 = a10[j], y11 = a11[j];
    if (OUT_RELU) {
      y00 = fmaxf(y00, 0.f); y01 = fmaxf(y01, 0.f);
      y10 = fmaxf(y10, 0.f); y11 = fmaxf(y11, 0.f);
    }
    op[2*j] = y00; op[2*j + 1] = y01;
    op[HO + 2*j] = y10; op[HO + 2*j + 1] = y11;
  }
}

// ---------------- VQ: argmin (first-min), zq in-place, idx (fp32) to d_out ----------------
__global__ __launch_bounds__(256) void k_vq(
    const float* __restrict__ z, const void* __restrict__ emb,
    float* __restrict__ zq, float* __restrict__ idx_out,
    const int* __restrict__ flag, float* __restrict__ lossp, int lossbase)
{
  __shared__ float sE[8192];
  __shared__ float sEE[128];
  __shared__ float wsum[4];
  int fl = flag[0];
  int tid = threadIdx.x;
  int n = blockIdx.x * 256 + tid;
  int nb = n >> 10, p = n & 1023;
  const float* zp = z + nb * 65536 + p;
  float zv[64];
  float zz = 0.f;
  #pragma unroll
  for (int d = 0; d < 64; ++d) { zv[d] = zp[d * 1024]; zz = fmaf(zv[d], zv[d], zz); }
  float best = 3.4e38f; int bidx = 0;
  for (int kb = 0; kb < 8; ++kb) {
    __syncthreads();
    for (int i = tid; i < 8192; i += 256) sE[i] = ldg_in(emb, kb * 8192 + i, fl);
    __syncthreads();
    if (tid < 128) {
      float s = 0.f;
      #pragma unroll
      for (int d = 0; d < 64; ++d) s = fmaf(sE[tid * 64 + d], sE[tid * 64 + d], s);
      sEE[tid] = s;
    }
    __syncthreads();
    for (int k = 0; k < 128; ++k) {
      const float* ep = sE + k * 64;
      float dot = 0.f;
      #pragma unroll
      for (int d = 0; d < 64; ++d) dot = fmaf(zv[d], ep[d], dot);
      float dist = zz + sEE[k] - 2.f * dot;
      if (dist < best) { best = dist; bidx = kb * 128 + k; }  // strict <: first min wins
    }
  }
  idx_out[n] = (float)bidx;
  float ls = 0.f;
  float* qp = zq + nb * 65536 + p;
  #pragma unroll
  for (int d = 0; d < 64; ++d) {
    float e = ldg_in(emb, bidx * 64 + d, fl);
    qp[d * 1024] = e;                  // in-place over z: thread owns its column
    float df = e - zv[d];
    ls = fmaf(df, df, ls);
  }
  #pragma unroll
  for (int off = 32; off > 0; off >>= 1) ls += __shfl_down(ls, off);
  if ((tid & 63) == 0) wsum[tid >> 6] = ls;
  __syncthreads();
  if (tid == 0) lossp[lossbase + blockIdx.x] = wsum[0] + wsum[1] + wsum[2] + wsum[3];
}

__global__ void k_loss_final(const float* __restrict__ lossp, float* __restrict__ out) {
  if (threadIdx.x == 0 && blockIdx.x == 0) {
    float s = 0.f;
    for (int i = 0; i < 256; ++i) s += lossp[i];
    float L = s * (1.f / 4194304.f);   // mean over 64*32*32*64
    out[R_RECON + 0] = L;              // codebook_loss
    out[R_RECON + 1] = L;              // commitment_loss (identical forward value)
  }
}

extern "C" void kernel_launch(void* const* d_in, const int* in_sizes, int n_in,
                              void* d_out, int out_size, void* d_ws, size_t ws_size,
                              hipStream_t stream)
{
  float* out = (float*)d_out;          // output is fp32 (established R8-R10)

  float* F = (float*)d_ws;
  float* LOSSP = F;
  int* FLAG = (int*)(F + 256);
  float* A = F + 272;

  int Bc = 64;
  while (Bc > 1 && 4ull * (272ull + (size_t)Bc * 393216ull) > ws_size) Bc >>= 1;
  float* H1 = A;                               // [0, Bc*262144)
  float* H2 = A + (size_t)Bc * 262144;         // [.., Bc*393216)
  float* H3 = A;                               // reuses H1 (dead)
  float* T  = A + (size_t)Bc * 131072;
  float* Z  = A + (size_t)Bc * 163840;
  float* D1 = H2;
  float* D2 = A;

  const void* patch = d_in[0];
  const void* ew1 = d_in[1];  const void* eb1 = d_in[2];
  const void* ew2 = d_in[3];  const void* eb2 = d_in[4];
  const void* ew3 = d_in[5];  const void* eb3 = d_in[6];
  const void* er1a = d_in[7]; const void* er1b = d_in[8];
  const void* er2a = d_in[9]; const void* er2b = d_in[10];
  const void* pqw = d_in[11]; const void* pqb = d_in[12];
  const void* emb = d_in[13];
  const void* dw1 = d_in[14]; const void* db1 = d_in[15];
  const void* dr1a = d_in[16]; const void* dr1b = d_in[17];
  const void* dr2a = d_in[18]; const void* dr2b = d_in[19];
  const void* dw2 = d_in[20]; const void* db2 = d_in[21];
  const void* dw3 = d_in[22]; const void* db3 = d_in[23];

  k_detect<<<1, 256, 0, stream>>>((const u16*)patch, FLAG);

  int NC = 64 / Bc;
  for (int c = 0; c < NC; ++c) {
    int b0 = c * Bc;

    // ---- encoder ----
    k_conv_s2k4<true><<<Bc * 1024, 256, 0, stream>>>(patch, ew1, eb1, H1, FLAG,
                                                     b0 * 49152, 3, 128, 64, 64);
    k_enc2<<<Bc * 128, 256, 0, stream>>>(H1, ew2, eb2, H2, FLAG);
    k_conv3x3_t2<false, false, false, true><<<Bc * 64, 256, 0, stream>>>(H2, ew3, eb3, H3, FLAG, 128, 128);
    // res1: T = relu(conv3x3(relu(x))); x += conv1x1(T)
    k_conv3x3_t2<true, false, true, false><<<Bc * 16, 256, 0, stream>>>(H3, er1a, nullptr, T, FLAG, 128, 32);
    k_conv1x1_t4<true, false, false><<<Bc * 32, 256, 0, stream>>>(T, er1b, nullptr, H3, FLAG, 32, 128);
    // res2: final relu fused into the accumulate write
    k_conv3x3_t2<true, false, true, false><<<Bc * 16, 256, 0, stream>>>(H3, er2a, nullptr, T, FLAG, 128, 32);
    k_conv1x1_t4<true, false, true><<<Bc * 32, 256, 0, stream>>>(T, er2b, nullptr, H3, FLAG, 32, 128);
    // pre-quant 1x1 (input already relu'd at res2 write)
    k_conv1x1_t4<false, true, false><<<Bc * 16, 256, 0, stream>>>(H3, pqw, pqb, Z, FLAG, 128, 64);

    // ---- VQ ----
    k_vq<<<Bc * 4, 256, 0, stream>>>(Z, emb, Z, out + R_RECON + 2 + (size_t)b0 * 1024,
                                     FLAG, LOSSP, b0 * 4);

    // ---- decoder ----
    k_conv3x3_t2<false, true, false, true><<<Bc * 64, 256, 0, stream>>>(Z, dw1, db1, D1, FLAG, 64, 128);
    k_conv3x3_t2<true, false, true, false><<<Bc * 16, 256, 0, stream>>>(D1, dr1a, nullptr, T, FLAG, 128, 32);
    k_conv1x1_t4<true, false, false><<<Bc * 32, 256, 0, stream>>>(T, dr1b, nullptr, D1, FLAG, 32, 128);
    k_conv3x3_t2<true, false, true, false><<<Bc * 16, 256, 0, stream>>>(D1, dr2a, nullptr, T, FLAG, 128, 32);
    k_conv1x1_t4<true, false, true><<<Bc * 32, 256, 0, stream>>>(T, dr2b, nullptr, D1, FLAG, 32, 128);
    // up1 (input relu'd at res2 write; output relu'd)
    k_convT_quad<true, 32><<<Bc * 64, 256, 0, stream>>>(D1, dw2, db2, D2, FLAG, 128, 64);
    // up2 -> recon (fp32 straight to d_out)
    k_convT_quad<false, 64><<<Bc * 12, 256, 0, stream>>>(D2, dw3, db3,
                                     out + (size_t)b0 * 49152, FLAG, 64, 3);
  }

  k_loss_final<<<1, 64, 0, stream>>>(LOSSP, out);
}

// Round 13
// 4989.861 us; speedup vs baseline: 3.2956x; 1.6609x over previous
//
#include <hip/hip_runtime.h>
#include <hip/hip_bf16.h>

typedef __hip_bfloat16 bf16;
typedef unsigned short u16;

#define R_RECON 3145728
#define N_IDX   65536

// dual-dtype input load: fl=1 -> fp32 (expected), fl=0 -> bf16
__device__ __forceinline__ float ldg_in(const void* p, int i, int fl) {
  return fl ? ((const float*)p)[i] : __bfloat162float(((const bf16*)p)[i]);
}

__global__ __launch_bounds__(256) void k_detect(const u16* __restrict__ p, int* __restrict__ flag) {
  __shared__ int s;
  if (threadIdx.x == 0) s = 0;
  __syncthreads();
  for (int i = threadIdx.x; i < 4096; i += 256) {
    float f = __uint_as_float(((unsigned)p[i]) << 16);
    if (!(fabsf(f) < 16384.f)) atomicOr(&s, 1);
  }
  __syncthreads();
  if (threadIdx.x == 0) flag[0] = s;
}

// ---------------- enc1: stride-2 4x4 conv from global input (Cin=3) ----------------
template<bool GIN>
__global__ __launch_bounds__(256) void k_conv_s2k4(
    const void* __restrict__ inp, const void* __restrict__ w,
    const void* __restrict__ bias, float* __restrict__ out,
    const int* __restrict__ flag, int in_off,
    int Cin, int Hin, int Cout, int Hout)
{
  __shared__ float sW[1024];
  int fl = flag[0];
  int tid = threadIdx.x;
  int idx = blockIdx.x * 256 + tid;
  int hw = Hout * Hout;
  int co = (idx / hw) % Cout;          // uniform (256 divides hw)
  for (int i = tid; i < Cin * 16; i += 256)
    sW[i] = ldg_in(w, co * Cin * 16 + i, fl);
  __syncthreads();
  int ox = idx % Hout; int t = idx / Hout;
  int oy = t % Hout;
  int n = idx / (hw * Cout);
  float acc = ldg_in(bias, co, fl);
  int iy0 = 2 * oy - 1, ix0 = 2 * ox - 1;
  const float* inf = (const float*)inp;
  for (int ci = 0; ci < Cin; ++ci) {
    int base_in = (n * Cin + ci) * Hin * Hin;
    const float* wp = sW + ci * 16;
    #pragma unroll
    for (int ky = 0; ky < 4; ++ky) {
      int iy = iy0 + ky;
      if ((unsigned)iy >= (unsigned)Hin) continue;
      int rb = base_in + iy * Hin;
      #pragma unroll
      for (int kx = 0; kx < 4; ++kx) {
        int ix = ix0 + kx;
        if ((unsigned)ix >= (unsigned)Hin) continue;
        float v = GIN ? ldg_in(inp, in_off + rb + ix, fl) : inf[rb + ix];
        acc = fmaf(v, wp[ky * 4 + kx], acc);
      }
    }
  }
  out[idx] = fmaxf(acc, 0.f);
}

// ---------------- enc2: s2 k4, 64ch 64x64 -> 128ch 32x32; 2 co per thread ----------------
// Scalar row windows (no runtime-indexed arrays -> no scratch; R11 lesson).
__global__ __launch_bounds__(256) void k_enc2(
    const float* __restrict__ in, const void* __restrict__ w,
    const void* __restrict__ bias, float* __restrict__ out,
    const int* __restrict__ flag)
{
  const int Cin = 64, Cout = 128;
  __shared__ float sW[2048];           // 2 co x 64ci x 16
  int fl = flag[0];
  int bid = blockIdx.x;
  int cp = bid & 63, n = bid >> 6;     // Cout/2 = 64 pairs
  int co0 = cp * 2;
  int tid = threadIdx.x;
  for (int i = tid; i < 2048; i += 256)
    sW[i] = ldg_in(w, co0 * Cin * 16 + i, fl);   // co0, co0+1 contiguous
  __syncthreads();
  int oy = tid >> 3, ox0 = (tid & 7) << 2;
  float bv0 = ldg_in(bias, co0, fl), bv1 = ldg_in(bias, co0 + 1, fl);
  float a0 = bv0, a1 = bv0, a2 = bv0, a3 = bv0;
  float b0 = bv1, b1 = bv1, b2 = bv1, b3 = bv1;
  int ry0 = 2 * oy - 1;
  int cx0 = 2 * ox0 - 1;
  const float* ip = in + (size_t)n * Cin * 4096;
  for (int ci = 0; ci < Cin; ++ci) {
    const float* p = ip + ci * 4096;
    #pragma unroll
    for (int ky = 0; ky < 4; ++ky) {
      int iy = ry0 + ky;
      if ((unsigned)iy < 64u) {
        const float* rp = p + iy * 64;
        float x0 = (cx0 >= 0) ? rp[cx0] : 0.f;
        float x1 = rp[cx0 + 1], x2 = rp[cx0 + 2], x3 = rp[cx0 + 3], x4 = rp[cx0 + 4];
        float x5 = rp[cx0 + 5], x6 = rp[cx0 + 6], x7 = rp[cx0 + 7], x8 = rp[cx0 + 8];
        float x9 = (cx0 + 9 < 64) ? rp[cx0 + 9] : 0.f;
        const float* WA = sW + ci * 16 + ky * 4;
        const float* WB = WA + 1024;
        float wa0 = WA[0], wa1 = WA[1], wa2 = WA[2], wa3 = WA[3];
        a0 = fmaf(x0, wa0, fmaf(x1, wa1, fmaf(x2, wa2, fmaf(x3, wa3, a0))));
        a1 = fmaf(x2, wa0, fmaf(x3, wa1, fmaf(x4, wa2, fmaf(x5, wa3, a1))));
        a2 = fmaf(x4, wa0, fmaf(x5, wa1, fmaf(x6, wa2, fmaf(x7, wa3, a2))));
        a3 = fmaf(x6, wa0, fmaf(x7, wa1, fmaf(x8, wa2, fmaf(x9, wa3, a3))));
        float wb0 = WB[0], wb1 = WB[1], wb2 = WB[2], wb3 = WB[3];
        b0 = fmaf(x0, wb0, fmaf(x1, wb1, fmaf(x2, wb2, fmaf(x3, wb3, b0))));
        b1 = fmaf(x2, wb0, fmaf(x3, wb1, fmaf(x4, wb2, fmaf(x5, wb3, b1))));
        b2 = fmaf(x4, wb0, fmaf(x5, wb1, fmaf(x6, wb2, fmaf(x7, wb3, b2))));
        b3 = fmaf(x6, wb0, fmaf(x7, wb1, fmaf(x8, wb2, fmaf(x9, wb3, b3))));
      }
    }
  }
  float* op0 = out + (size_t)(n * Cout + co0) * 1024 + oy * 32 + ox0;
  op0[0] = fmaxf(a0, 0.f); op0[1] = fmaxf(a1, 0.f);
  op0[2] = fmaxf(a2, 0.f); op0[3] = fmaxf(a3, 0.f);
  float* op1 = op0 + 1024;
  op1[0] = fmaxf(b0, 0.f); op1[1] = fmaxf(b1, 0.f);
  op1[2] = fmaxf(b2, 0.f); op1[3] = fmaxf(b3, 0.f);
}

// ---------------- 3x3 conv s1 p1 @32x32: 4 co/block, 2 co/thread, 2x4 px tile ----------------
// TRANS_W: torch ConvTranspose layout (I,O,3,3); flip applied at staging.
template<bool IN_RELU, bool TRANS_W, bool OUT_RELU, bool HAS_BIAS>
__global__ __launch_bounds__(256) void k_conv3x3_q(
    const float* __restrict__ in, const void* __restrict__ w,
    const void* __restrict__ bias, float* __restrict__ out,
    const int* __restrict__ flag, int Cin, int Cout)
{
  const int HW = 1024;
  __shared__ float sW[4608];           // 4 co x Cin x 9, Cin<=128
  int fl = flag[0];
  int nq = Cout >> 2;
  int bid = blockIdx.x;
  int qc = bid % nq, n = bid / nq;
  int co0 = qc * 4;
  int tid = threadIdx.x;
  int tot = 4 * Cin * 9;
  for (int i = tid; i < tot; i += 256) {
    int cl = i / (Cin * 9), rem = i % (Cin * 9);
    int ci = rem / 9, k = rem % 9;
    int src = TRANS_W ? ((ci * Cout + co0 + cl) * 9 + (8 - k))
                      : (((co0 + cl) * Cin + ci) * 9 + k);
    sW[i] = ldg_in(w, src, fl);
  }
  __syncthreads();
  int half = tid >> 7;                 // 0/1 (uniform per wave)
  int tt = tid & 127;
  int r2 = tt >> 3, c4 = tt & 7;
  int oy0 = r2 * 2, ox0 = c4 * 4;
  int coA = co0 + half * 2;            // thread computes coA and coA+1
  const float* WA = sW + (half * 2) * Cin * 9;
  const float* WB = WA + Cin * 9;
  float bvA = HAS_BIAS ? ldg_in(bias, coA, fl) : 0.f;
  float bvB = HAS_BIAS ? ldg_in(bias, coA + 1, fl) : 0.f;
  float acc[2][2][4];                  // [coSel][row][col] all compile-time indexed
  #pragma unroll
  for (int r = 0; r < 2; ++r)
    #pragma unroll
    for (int q = 0; q < 4; ++q) { acc[0][r][q] = bvA; acc[1][r][q] = bvB; }
  const float* ip = in + (size_t)n * Cin * HW;
  for (int ci = 0; ci < Cin; ++ci) {
    const float* p = ip + ci * HW;
    const float* wa = WA + ci * 9;
    const float* wb = WB + ci * 9;
    #pragma unroll
    for (int r = 0; r < 4; ++r) {
      int iy = oy0 - 1 + r;
      if ((unsigned)iy < 32u) {
        const float* rp = p + iy * 32;
        float x0, x5;
        {
          int ix = ox0 - 1;
          x0 = ((unsigned)ix < 32u) ? rp[ix] : 0.f;
          ix = ox0 + 4;
          x5 = ((unsigned)ix < 32u) ? rp[ix] : 0.f;
        }
        float x1 = rp[ox0], x2 = rp[ox0 + 1], x3 = rp[ox0 + 2], x4 = rp[ox0 + 3];
        if (IN_RELU) {
          x0 = fmaxf(x0, 0.f); x1 = fmaxf(x1, 0.f); x2 = fmaxf(x2, 0.f);
          x3 = fmaxf(x3, 0.f); x4 = fmaxf(x4, 0.f); x5 = fmaxf(x5, 0.f);
        }
        #pragma unroll
        for (int t = 0; t < 2; ++t) {
          int ky = r - t;              // compile-time after unroll
          if (ky >= 0 && ky <= 2) {
            float wA0 = wa[ky * 3], wA1 = wa[ky * 3 + 1], wA2 = wa[ky * 3 + 2];
            acc[0][t][0] = fmaf(x0, wA0, fmaf(x1, wA1, fmaf(x2, wA2, acc[0][t][0])));
            acc[0][t][1] = fmaf(x1, wA0, fmaf(x2, wA1, fmaf(x3, wA2, acc[0][t][1])));
            acc[0][t][2] = fmaf(x2, wA0, fmaf(x3, wA1, fmaf(x4, wA2, acc[0][t][2])));
            acc[0][t][3] = fmaf(x3, wA0, fmaf(x4, wA1, fmaf(x5, wA2, acc[0][t][3])));
            float wB0 = wb[ky * 3], wB1 = wb[ky * 3 + 1], wB2 = wb[ky * 3 + 2];
            acc[1][t][0] = fmaf(x0, wB0, fmaf(x1, wB1, fmaf(x2, wB2, acc[1][t][0])));
            acc[1][t][1] = fmaf(x1, wB0, fmaf(x2, wB1, fmaf(x3, wB2, acc[1][t][1])));
            acc[1][t][2] = fmaf(x2, wB0, fmaf(x3, wB1, fmaf(x4, wB2, acc[1][t][2])));
            acc[1][t][3] = fmaf(x3, wB0, fmaf(x4, wB1, fmaf(x5, wB2, acc[1][t][3])));
          }
        }
      }
    }
  }
  #pragma unroll
  for (int cl = 0; cl < 2; ++cl) {
    #pragma unroll
    for (int r = 0; r < 2; ++r) {
      float* op = out + (size_t)(n * Cout + coA + cl) * HW + (oy0 + r) * 32 + ox0;
      #pragma unroll
      for (int q = 0; q < 4; ++q) {
        float v = acc[cl][r][q];
        if (OUT_RELU) v = fmaxf(v, 0.f);
        op[q] = v;
      }
    }
  }
}

// ---------------- 1x1 conv @32x32: 4co x 4p register tile ----------------
template<bool ACCUM, bool HAS_BIAS, bool OUT_RELU>
__global__ __launch_bounds__(256) void k_conv1x1_t4(
    const float* __restrict__ in, const void* __restrict__ w,
    const void* __restrict__ bias, float* __restrict__ out,
    const int* __restrict__ flag, int Cin, int Cout)
{
  const int HW = 1024;
  __shared__ float sW[512];
  int fl = flag[0];
  int nq = Cout >> 2;
  int bid = blockIdx.x;
  int qc = bid % nq, n = bid / nq;
  int co0 = qc * 4;
  int tid = threadIdx.x;
  for (int i = tid; i < 4 * Cin; i += 256)
    sW[i] = ldg_in(w, co0 * Cin + i, fl);
  __syncthreads();
  float acc[4][4];
  #pragma unroll
  for (int c = 0; c < 4; ++c) {
    float bv = HAS_BIAS ? ldg_in(bias, co0 + c, fl) : 0.f;
    #pragma unroll
    for (int k = 0; k < 4; ++k) acc[c][k] = bv;
  }
  const float* ip = in + (size_t)n * Cin * HW + tid;
  for (int ci = 0; ci < Cin; ++ci) {
    const float* p = ip + ci * HW;
    float x0 = p[0], x1 = p[256], x2 = p[512], x3 = p[768];
    #pragma unroll
    for (int c = 0; c < 4; ++c) {
      float wv = sW[c * Cin + ci];
      acc[c][0] = fmaf(wv, x0, acc[c][0]);
      acc[c][1] = fmaf(wv, x1, acc[c][1]);
      acc[c][2] = fmaf(wv, x2, acc[c][2]);
      acc[c][3] = fmaf(wv, x3, acc[c][3]);
    }
  }
  #pragma unroll
  for (int c = 0; c < 4; ++c) {
    float* op = out + (size_t)(n * Cout + co0 + c) * HW + tid;
    #pragma unroll
    for (int k = 0; k < 4; ++k) {
      float v = acc[c][k];
      if (ACCUM) v += op[k * 256];
      if (OUT_RELU) v = fmaxf(v, 0.f);
      op[k * 256] = v;
    }
  }
}

// ---------------- ConvTranspose s2 k4 p1, parity-quad, 2 co/thread (up1) ----------------
template<bool OUT_RELU, int HQ>
__global__ __launch_bounds__(256) void k_convT_quad2(
    const float* __restrict__ in, const void* __restrict__ w,
    const void* __restrict__ bias, float* __restrict__ out,
    const int* __restrict__ flag, int Cin, int Cout)
{
  constexpr int HO = HQ * 2;
  constexpr int QPB = (HQ * HQ) / 1024;
  constexpr int LPR = HQ / 4;
  __shared__ float sW[4096];           // 2 co x Cin x 16, Cin<=128
  int fl = flag[0];
  int bid = blockIdx.x;
  int s = bid % QPB;
  int t2 = bid / QPB;
  int cp = t2 % (Cout >> 1);
  int n = t2 / (Cout >> 1);
  int co0 = cp * 2;
  int tid = threadIdx.x;
  for (int i = tid; i < 2 * Cin * 16; i += 256) {
    int cl = i / (Cin * 16), rem = i % (Cin * 16);
    int ci = rem >> 4, k = rem & 15;
    sW[i] = ldg_in(w, (ci * Cout + co0 + cl) * 16 + k, fl);
  }
  __syncthreads();
  int qa = s * (256 / LPR) + tid / LPR;
  int qb0 = (tid % LPR) * 4;
  float bv0 = ldg_in(bias, co0, fl), bv1 = ldg_in(bias, co0 + 1, fl);
  float A[2][4][4];                    // [co][pos 00,01,10,11][j]
  #pragma unroll
  for (int j = 0; j < 4; ++j) {
    A[0][0][j] = bv0; A[0][1][j] = bv0; A[0][2][j] = bv0; A[0][3][j] = bv0;
    A[1][0][j] = bv1; A[1][1][j] = bv1; A[1][2][j] = bv1; A[1][3][j] = bv1;
  }
  const float* ip = in + (size_t)n * Cin * HQ * HQ;
  bool v0 = qa >= 1, v2 = qa + 1 < HQ;
  for (int ci = 0; ci < Cin; ++ci) {
    const float* p = ip + ci * HQ * HQ;
    const float* r0 = p + (qa - 1) * HQ;
    const float* r1 = p + qa * HQ;
    const float* r2 = p + (qa + 1) * HQ;
    float x0[6], x1[6], x2[6];
    #pragma unroll
    for (int c = 0; c < 6; ++c) {
      int ix = qb0 - 1 + c;
      bool vc = (unsigned)ix < (unsigned)HQ;
      x0[c] = (v0 && vc) ? r0[ix] : 0.f;
      x1[c] = vc ? r1[ix] : 0.f;
      x2[c] = (v2 && vc) ? r2[ix] : 0.f;
    }
    #pragma unroll
    for (int cl = 0; cl < 2; ++cl) {
      const float* W = sW + cl * (Cin * 16) + ci * 16;
      float w00 = W[0], w01 = W[1], w02 = W[2], w03 = W[3];
      float w10 = W[4], w11 = W[5], w12 = W[6], w13 = W[7];
      float w20 = W[8], w21 = W[9], w22 = W[10], w23 = W[11];
      float w30 = W[12], w31 = W[13], w32 = W[14], w33 = W[15];
      #pragma unroll
      for (int j = 0; j < 4; ++j) {
        A[cl][0][j] = fmaf(w11, x1[j+1], fmaf(w13, x1[j],   fmaf(w31, x0[j+1], fmaf(w33, x0[j],   A[cl][0][j]))));
        A[cl][1][j] = fmaf(w10, x1[j+2], fmaf(w12, x1[j+1], fmaf(w30, x0[j+2], fmaf(w32, x0[j+1], A[cl][1][j]))));
        A[cl][2][j] = fmaf(w01, x2[j+1], fmaf(w03, x2[j],   fmaf(w21, x1[j+1], fmaf(w23, x1[j],   A[cl][2][j]))));
        A[cl][3][j] = fmaf(w00, x2[j+2], fmaf(w02, x2[j+1], fmaf(w20, x1[j+2], fmaf(w22, x1[j+1], A[cl][3][j]))));
      }
    }
  }
  #pragma unroll
  for (int cl = 0; cl < 2; ++cl) {
    float* op = out + ((size_t)(n * Cout + co0 + cl) * HO + 2 * qa) * HO + 2 * qb0;
    #pragma unroll
    for (int j = 0; j < 4; ++j) {
      float y00 = A[cl][0][j], y01 = A[cl][1][j], y10 = A[cl][2][j], y11 = A[cl][3][j];
      if (OUT_RELU) {
        y00 = fmaxf(y00, 0.f); y01 = fmaxf(y01, 0.f);
        y10 = fmaxf(y10, 0.f); y11 = fmaxf(y11, 0.f);
      }
      op[2*j] = y00; op[2*j + 1] = y01;
      op[HO + 2*j] = y10; op[HO + 2*j + 1] = y11;
    }
  }
}

// ---------------- ConvTranspose parity-quad, 1 co (up2, Cout=3) ----------------
template<bool OUT_RELU, int HQ>
__global__ __launch_bounds__(256) void k_convT_quad(
    const float* __restrict__ in, const void* __restrict__ w,
    const void* __restrict__ bias, float* __restrict__ out,
    const int* __restrict__ flag, int Cin, int Cout)
{
  constexpr int HO = HQ * 2;
  constexpr int QPB = (HQ * HQ) / 1024;
  constexpr int LPR = HQ / 4;
  __shared__ float sW[2048];
  int fl = flag[0];
  int bid = blockIdx.x;
  int s = bid % QPB;
  int t2 = bid / QPB;
  int co = t2 % Cout;
  int n = t2 / Cout;
  int tid = threadIdx.x;
  for (int i = tid; i < Cin * 16; i += 256)
    sW[i] = ldg_in(w, ((i >> 4) * Cout + co) * 16 + (i & 15), fl);
  __syncthreads();
  int qa = s * (256 / LPR) + tid / LPR;
  int qb0 = (tid % LPR) * 4;
  float bv = ldg_in(bias, co, fl);
  float a00[4], a01[4], a10[4], a11[4];
  #pragma unroll
  for (int j = 0; j < 4; ++j) { a00[j] = bv; a01[j] = bv; a10[j] = bv; a11[j] = bv; }
  const float* ip = in + (size_t)n * Cin * HQ * HQ;
  bool v0 = qa >= 1, v2 = qa + 1 < HQ;
  for (int ci = 0; ci < Cin; ++ci) {
    const float* p = ip + ci * HQ * HQ;
    const float* r0 = p + (qa - 1) * HQ;
    const float* r1 = p + qa * HQ;
    const float* r2 = p + (qa + 1) * HQ;
    float x0[6], x1[6], x2[6];
    #pragma unroll
    for (int c = 0; c < 6; ++c) {
      int ix = qb0 - 1 + c;
      bool vc = (unsigned)ix < (unsigned)HQ;
      x0[c] = (v0 && vc) ? r0[ix] : 0.f;
      x1[c] = vc ? r1[ix] : 0.f;
      x2[c] = (v2 && vc) ? r2[ix] : 0.f;
    }
    const float* W = sW + ci * 16;
    float w00 = W[0], w01 = W[1], w02 = W[2], w03 = W[3];
    float w10 = W[4], w11 = W[5], w12 = W[6], w13 = W[7];
    float w20 = W[8], w21 = W[9], w22 = W[10], w23 = W[11];
    float w30 = W[12], w31 = W[13], w32 = W[14], w33 = W[15];
    #pragma unroll
    for (int j = 0; j < 4; ++j) {
      a00[j] = fmaf(w11, x1[j+1], fmaf(w13, x1[j],   fmaf(w31, x0[j+1], fmaf(w33, x0[j],   a00[j]))));
      a01[j] = fmaf(w10, x1[j+2], fmaf(w12, x1[j+1], fmaf(w30, x0[j+2], fmaf(w32, x0[j+1], a01[j]))));
      a10[j] = fmaf(w01, x2[j+1], fmaf(w03, x2[j],   fmaf(w21, x1[j+1], fmaf(w23, x1[j],   a10[j]))));
      a11[j] = fmaf(w00, x2[j+2], fmaf(w02, x2[j+1], fmaf(w20, x1[j+2], fmaf(w22, x1[j+1], a11[j]))));
    }
  }
  float* op = out + ((size_t)(n * Cout + co) * HO + 2 * qa) * HO + 2 * qb0;
  #pragma unroll
  for (int j = 0; j < 4; ++j) {
    float y00 = a00[j], y01 = a01[j], y10 = a10[j], y11 = a11[j];
    if (OUT_RELU) {
      y00 = fmaxf(y00, 0.f); y01 = fmaxf(y01, 0.f);
      y10 = fmaxf(y10, 0.f); y11 = fmaxf(y11, 0.f);
    }
    op[2*j] = y00; op[2*j + 1] = y01;
    op[HO + 2*j] = y10; op[HO + 2*j + 1] = y11;
  }
}

// ---------------- VQ: argmin (first-min), zq in-place, idx (fp32) to d_out ----------------
__global__ __launch_bounds__(256) void k_vq(
    const float* __restrict__ z, const void* __restrict__ emb,
    float* __restrict__ zq, float* __restrict__ idx_out,
    const int* __restrict__ flag, float* __restrict__ lossp, int lossbase)
{
  __shared__ float sE[8192];
  __shared__ float sEE[128];
  __shared__ float wsum[4];
  int fl = flag[0];
  int tid = threadIdx.x;
  int n = blockIdx.x * 256 + tid;
  int nb = n >> 10, p = n & 1023;
  const float* zp = z + nb * 65536 + p;
  float zv[64];
  float zz = 0.f;
  #pragma unroll
  for (int d = 0; d < 64; ++d) { zv[d] = zp[d * 1024]; zz = fmaf(zv[d], zv[d], zz); }
  float best = 3.4e38f; int bidx = 0;
  for (int kb = 0; kb < 8; ++kb) {
    __syncthreads();
    for (int i = tid; i < 8192; i += 256) sE[i] = ldg_in(emb, kb * 8192 + i, fl);
    __syncthreads();
    if (tid < 128) {
      float s = 0.f;
      #pragma unroll
      for (int d = 0; d < 64; ++d) s = fmaf(sE[tid * 64 + d], sE[tid * 64 + d], s);
      sEE[tid] = s;
    }
    __syncthreads();
    for (int k = 0; k < 128; ++k) {
      const float* ep = sE + k * 64;
      float dot = 0.f;
      #pragma unroll
      for (int d = 0; d < 64; ++d) dot = fmaf(zv[d], ep[d], dot);
      float dist = zz + sEE[k] - 2.f * dot;
      if (dist < best) { best = dist; bidx = kb * 128 + k; }  // strict <: first min wins
    }
  }
  idx_out[n] = (float)bidx;
  float ls = 0.f;
  float* qp = zq + nb * 65536 + p;
  #pragma unroll
  for (int d = 0; d < 64; ++d) {
    float e = ldg_in(emb, bidx * 64 + d, fl);
    qp[d * 1024] = e;                  // in-place over z: thread owns its column
    float df = e - zv[d];
    ls = fmaf(df, df, ls);
  }
  #pragma unroll
  for (int off = 32; off > 0; off >>= 1) ls += __shfl_down(ls, off);
  if ((tid & 63) == 0) wsum[tid >> 6] = ls;
  __syncthreads();
  if (tid == 0) lossp[lossbase + blockIdx.x] = wsum[0] + wsum[1] + wsum[2] + wsum[3];
}

__global__ void k_loss_final(const float* __restrict__ lossp, float* __restrict__ out) {
  if (threadIdx.x == 0 && blockIdx.x == 0) {
    float s = 0.f;
    for (int i = 0; i < 256; ++i) s += lossp[i];
    float L = s * (1.f / 4194304.f);   // mean over 64*32*32*64
    out[R_RECON + 0] = L;
    out[R_RECON + 1] = L;
  }
}

extern "C" void kernel_launch(void* const* d_in, const int* in_sizes, int n_in,
                              void* d_out, int out_size, void* d_ws, size_t ws_size,
                              hipStream_t stream)
{
  float* out = (float*)d_out;          // output is fp32 (established R8-R10)

  float* F = (float*)d_ws;
  float* LOSSP = F;
  int* FLAG = (int*)(F + 256);
  float* A = F + 272;

  int Bc = 64;
  while (Bc > 1 && 4ull * (272ull + (size_t)Bc * 393216ull) > ws_size) Bc >>= 1;
  float* H1 = A;
  float* H2 = A + (size_t)Bc * 262144;
  float* H3 = A;
  float* T  = A + (size_t)Bc * 131072;
  float* Z  = A + (size_t)Bc * 163840;
  float* D1 = H2;
  float* D2 = A;

  const void* patch = d_in[0];
  const void* ew1 = d_in[1];  const void* eb1 = d_in[2];
  const void* ew2 = d_in[3];  const void* eb2 = d_in[4];
  const void* ew3 = d_in[5];  const void* eb3 = d_in[6];
  const void* er1a = d_in[7]; const void* er1b = d_in[8];
  const void* er2a = d_in[9]; const void* er2b = d_in[10];
  const void* pqw = d_in[11]; const void* pqb = d_in[12];
  const void* emb = d_in[13];
  const void* dw1 = d_in[14]; const void* db1 = d_in[15];
  const void* dr1a = d_in[16]; const void* dr1b = d_in[17];
  const void* dr2a = d_in[18]; const void* dr2b = d_in[19];
  const void* dw2 = d_in[20]; const void* db2 = d_in[21];
  const void* dw3 = d_in[22]; const void* db3 = d_in[23];

  k_detect<<<1, 256, 0, stream>>>((const u16*)patch, FLAG);

  int NC = 64 / Bc;
  for (int c = 0; c < NC; ++c) {
    int b0 = c * Bc;

    // ---- encoder ----
    k_conv_s2k4<true><<<Bc * 1024, 256, 0, stream>>>(patch, ew1, eb1, H1, FLAG,
                                                     b0 * 49152, 3, 128, 64, 64);
    k_enc2<<<Bc * 64, 256, 0, stream>>>(H1, ew2, eb2, H2, FLAG);
    k_conv3x3_q<false, false, false, true><<<Bc * 32, 256, 0, stream>>>(H2, ew3, eb3, H3, FLAG, 128, 128);
    // res1: T = relu(conv3x3(relu(x))); x += conv1x1(T)
    k_conv3x3_q<true, false, true, false><<<Bc * 8, 256, 0, stream>>>(H3, er1a, nullptr, T, FLAG, 128, 32);
    k_conv1x1_t4<true, false, false><<<Bc * 32, 256, 0, stream>>>(T, er1b, nullptr, H3, FLAG, 32, 128);
    // res2: final relu fused into the accumulate write
    k_conv3x3_q<true, false, true, false><<<Bc * 8, 256, 0, stream>>>(H3, er2a, nullptr, T, FLAG, 128, 32);
    k_conv1x1_t4<true, false, true><<<Bc * 32, 256, 0, stream>>>(T, er2b, nullptr, H3, FLAG, 32, 128);
    // pre-quant 1x1 (input already relu'd at res2 write)
    k_conv1x1_t4<false, true, false><<<Bc * 16, 256, 0, stream>>>(H3, pqw, pqb, Z, FLAG, 128, 64);

    // ---- VQ ----
    k_vq<<<Bc * 4, 256, 0, stream>>>(Z, emb, Z, out + R_RECON + 2 + (size_t)b0 * 1024,
                                     FLAG, LOSSP, b0 * 4);

    // ---- decoder ----
    k_conv3x3_q<false, true, false, true><<<Bc * 32, 256, 0, stream>>>(Z, dw1, db1, D1, FLAG, 64, 128);
    k_conv3x3_q<true, false, true, false><<<Bc * 8, 256, 0, stream>>>(D1, dr1a, nullptr, T, FLAG, 128, 32);
    k_conv1x1_t4<true, false, false><<<Bc * 32, 256, 0, stream>>>(T, dr1b, nullptr, D1, FLAG, 32, 128);
    k_conv3x3_q<true, false, true, false><<<Bc * 8, 256, 0, stream>>>(D1, dr2a, nullptr, T, FLAG, 128, 32);
    k_conv1x1_t4<true, false, true><<<Bc * 32, 256, 0, stream>>>(T, dr2b, nullptr, D1, FLAG, 32, 128);
    // up1: 2 co per thread
    k_convT_quad2<true, 32><<<Bc * 32, 256, 0, stream>>>(D1, dw2, db2, D2, FLAG, 128, 64);
    // up2 -> recon (Cout=3, single-co kernel)
    k_convT_quad<false, 64><<<Bc * 12, 256, 0, stream>>>(D2, dw3, db3,
                                     out + (size_t)b0 * 49152, FLAG, 64, 3);
  }

  k_loss_final<<<1, 64, 0, stream>>>(LOSSP, out);
}

// Round 14
// 4341.419 us; speedup vs baseline: 3.7878x; 1.1494x over previous
//
#include <hip/hip_runtime.h>
#include <hip/hip_bf16.h>

typedef __hip_bfloat16 bf16;
typedef unsigned short u16;

#define R_RECON 3145728
#define N_IDX   65536

// dual-dtype input load: fl=1 -> fp32 (expected), fl=0 -> bf16
__device__ __forceinline__ float ldg_in(const void* p, int i, int fl) {
  return fl ? ((const float*)p)[i] : __bfloat162float(((const bf16*)p)[i]);
}

__global__ __launch_bounds__(256) void k_detect(const u16* __restrict__ p, int* __restrict__ flag) {
  __shared__ int s;
  if (threadIdx.x == 0) s = 0;
  __syncthreads();
  for (int i = threadIdx.x; i < 4096; i += 256) {
    float f = __uint_as_float(((unsigned)p[i]) << 16);
    if (!(fabsf(f) < 16384.f)) atomicOr(&s, 1);
  }
  __syncthreads();
  if (threadIdx.x == 0) flag[0] = s;
}

// ---------------- enc1: stride-2 4x4 conv from global input (Cin=3) ----------------
template<bool GIN>
__global__ __launch_bounds__(256) void k_conv_s2k4(
    const void* __restrict__ inp, const void* __restrict__ w,
    const void* __restrict__ bias, float* __restrict__ out,
    const int* __restrict__ flag, int in_off,
    int Cin, int Hin, int Cout, int Hout)
{
  __shared__ float sW[1024];
  int fl = flag[0];
  int tid = threadIdx.x;
  int idx = blockIdx.x * 256 + tid;
  int hw = Hout * Hout;
  int co = (idx / hw) % Cout;
  for (int i = tid; i < Cin * 16; i += 256)
    sW[i] = ldg_in(w, co * Cin * 16 + i, fl);
  __syncthreads();
  int ox = idx % Hout; int t = idx / Hout;
  int oy = t % Hout;
  int n = idx / (hw * Cout);
  float acc = ldg_in(bias, co, fl);
  int iy0 = 2 * oy - 1, ix0 = 2 * ox - 1;
  const float* inf = (const float*)inp;
  for (int ci = 0; ci < Cin; ++ci) {
    int base_in = (n * Cin + ci) * Hin * Hin;
    const float* wp = sW + ci * 16;
    #pragma unroll
    for (int ky = 0; ky < 4; ++ky) {
      int iy = iy0 + ky;
      if ((unsigned)iy >= (unsigned)Hin) continue;
      int rb = base_in + iy * Hin;
      #pragma unroll
      for (int kx = 0; kx < 4; ++kx) {
        int ix = ix0 + kx;
        if ((unsigned)ix >= (unsigned)Hin) continue;
        float v = GIN ? ldg_in(inp, in_off + rb + ix, fl) : inf[rb + ix];
        acc = fmaf(v, wp[ky * 4 + kx], acc);
      }
    }
  }
  out[idx] = fmaxf(acc, 0.f);
}

// ---------------- enc2: s2 k4, 64ch 64x64 -> 128ch 32x32; 4 co per thread ----------------
__global__ __launch_bounds__(256) void k_enc2(
    const float* __restrict__ in, const void* __restrict__ w,
    const void* __restrict__ bias, float* __restrict__ out,
    const int* __restrict__ flag)
{
  const int Cin = 64, Cout = 128;
  __shared__ float sW[4096];           // 4 co x 64ci x 16, co-major
  int fl = flag[0];
  int bid = blockIdx.x;
  int cp = bid & 31, n = bid >> 5;     // 32 co-quads
  int co0 = cp * 4;
  int tid = threadIdx.x;
  for (int i = tid; i < 4096; i += 256)
    sW[i] = ldg_in(w, co0 * 1024 + i, fl);   // 4 co contiguous (1024 = Cin*16)
  __syncthreads();
  int oy = tid >> 3, ox0 = (tid & 7) << 2;
  float bvA = ldg_in(bias, co0, fl), bvB = ldg_in(bias, co0 + 1, fl);
  float bvC = ldg_in(bias, co0 + 2, fl), bvD = ldg_in(bias, co0 + 3, fl);
  float a0 = bvA, a1 = bvA, a2 = bvA, a3 = bvA;
  float b0 = bvB, b1 = bvB, b2 = bvB, b3 = bvB;
  float c0 = bvC, c1 = bvC, c2 = bvC, c3 = bvC;
  float d0 = bvD, d1 = bvD, d2 = bvD, d3 = bvD;
  int ry0 = 2 * oy - 1;
  int cx0 = 2 * ox0 - 1;
  const float* ip = in + (size_t)n * Cin * 4096;
  for (int ci = 0; ci < Cin; ++ci) {
    const float* p = ip + ci * 4096;
    #pragma unroll
    for (int ky = 0; ky < 4; ++ky) {
      int iy = ry0 + ky;
      if ((unsigned)iy < 64u) {
        const float* rp = p + iy * 64;
        float x0 = (cx0 >= 0) ? rp[cx0] : 0.f;
        float x1 = rp[cx0 + 1], x2 = rp[cx0 + 2], x3 = rp[cx0 + 3], x4 = rp[cx0 + 4];
        float x5 = rp[cx0 + 5], x6 = rp[cx0 + 6], x7 = rp[cx0 + 7], x8 = rp[cx0 + 8];
        float x9 = (cx0 + 9 < 64) ? rp[cx0 + 9] : 0.f;
        int wb = ci * 16 + ky * 4;
        {
          float wa0 = sW[wb], wa1 = sW[wb + 1], wa2 = sW[wb + 2], wa3 = sW[wb + 3];
          a0 = fmaf(x0, wa0, fmaf(x1, wa1, fmaf(x2, wa2, fmaf(x3, wa3, a0))));
          a1 = fmaf(x2, wa0, fmaf(x3, wa1, fmaf(x4, wa2, fmaf(x5, wa3, a1))));
          a2 = fmaf(x4, wa0, fmaf(x5, wa1, fmaf(x6, wa2, fmaf(x7, wa3, a2))));
          a3 = fmaf(x6, wa0, fmaf(x7, wa1, fmaf(x8, wa2, fmaf(x9, wa3, a3))));
          float wb0 = sW[wb + 1024], wb1 = sW[wb + 1025], wb2 = sW[wb + 1026], wb3 = sW[wb + 1027];
          b0 = fmaf(x0, wb0, fmaf(x1, wb1, fmaf(x2, wb2, fmaf(x3, wb3, b0))));
          b1 = fmaf(x2, wb0, fmaf(x3, wb1, fmaf(x4, wb2, fmaf(x5, wb3, b1))));
          b2 = fmaf(x4, wb0, fmaf(x5, wb1, fmaf(x6, wb2, fmaf(x7, wb3, b2))));
          b3 = fmaf(x6, wb0, fmaf(x7, wb1, fmaf(x8, wb2, fmaf(x9, wb3, b3))));
        }
        {
          float wc0 = sW[wb + 2048], wc1 = sW[wb + 2049], wc2 = sW[wb + 2050], wc3 = sW[wb + 2051];
          c0 = fmaf(x0, wc0, fmaf(x1, wc1, fmaf(x2, wc2, fmaf(x3, wc3, c0))));
          c1 = fmaf(x2, wc0, fmaf(x3, wc1, fmaf(x4, wc2, fmaf(x5, wc3, c1))));
          c2 = fmaf(x4, wc0, fmaf(x5, wc1, fmaf(x6, wc2, fmaf(x7, wc3, c2))));
          c3 = fmaf(x6, wc0, fmaf(x7, wc1, fmaf(x8, wc2, fmaf(x9, wc3, c3))));
          float wd0 = sW[wb + 3072], wd1 = sW[wb + 3073], wd2 = sW[wb + 3074], wd3 = sW[wb + 3075];
          d0 = fmaf(x0, wd0, fmaf(x1, wd1, fmaf(x2, wd2, fmaf(x3, wd3, d0))));
          d1 = fmaf(x2, wd0, fmaf(x3, wd1, fmaf(x4, wd2, fmaf(x5, wd3, d1))));
          d2 = fmaf(x4, wd0, fmaf(x5, wd1, fmaf(x6, wd2, fmaf(x7, wd3, d2))));
          d3 = fmaf(x6, wd0, fmaf(x7, wd1, fmaf(x8, wd2, fmaf(x9, wd3, d3))));
        }
      }
    }
  }
  float* op = out + (size_t)(n * Cout + co0) * 1024 + oy * 32 + ox0;
  op[0] = fmaxf(a0, 0.f); op[1] = fmaxf(a1, 0.f); op[2] = fmaxf(a2, 0.f); op[3] = fmaxf(a3, 0.f);
  op += 1024;
  op[0] = fmaxf(b0, 0.f); op[1] = fmaxf(b1, 0.f); op[2] = fmaxf(b2, 0.f); op[3] = fmaxf(b3, 0.f);
  op += 1024;
  op[0] = fmaxf(c0, 0.f); op[1] = fmaxf(c1, 0.f); op[2] = fmaxf(c2, 0.f); op[3] = fmaxf(c3, 0.f);
  op += 1024;
  op[0] = fmaxf(d0, 0.f); op[1] = fmaxf(d1, 0.f); op[2] = fmaxf(d2, 0.f); op[3] = fmaxf(d3, 0.f);
}

// ---- 3x3 conv s1 p1 @32x32: 4 co/block, 2 co/thread, 2x4 px tile, SCALAR acc ----
#define C33(A0, A1, A2, A3, W0, W1, W2) \
  A0 = fmaf(x0, W0, fmaf(x1, W1, fmaf(x2, W2, A0))); \
  A1 = fmaf(x1, W0, fmaf(x2, W1, fmaf(x3, W2, A1))); \
  A2 = fmaf(x2, W0, fmaf(x3, W1, fmaf(x4, W2, A2))); \
  A3 = fmaf(x3, W0, fmaf(x4, W1, fmaf(x5, W2, A3)));

#define C33_LOAD(RP) \
  x0 = (ox0 > 0) ? (RP)[ox0 - 1] : 0.f; \
  x1 = (RP)[ox0]; x2 = (RP)[ox0 + 1]; x3 = (RP)[ox0 + 2]; x4 = (RP)[ox0 + 3]; \
  x5 = (ox0 < 28) ? (RP)[ox0 + 4] : 0.f; \
  if (IN_RELU) { \
    x0 = fmaxf(x0, 0.f); x1 = fmaxf(x1, 0.f); x2 = fmaxf(x2, 0.f); \
    x3 = fmaxf(x3, 0.f); x4 = fmaxf(x4, 0.f); x5 = fmaxf(x5, 0.f); \
  }

template<bool IN_RELU, bool TRANS_W, bool OUT_RELU, bool HAS_BIAS>
__global__ __launch_bounds__(256) void k_conv3x3_s(
    const float* __restrict__ in, const void* __restrict__ w,
    const void* __restrict__ bias, float* __restrict__ out,
    const int* __restrict__ flag, int Cin, int Cout)
{
  const int HW = 1024;
  __shared__ float sW[4608];           // 4 co x Cin x 9, Cin<=128
  int fl = flag[0];
  int nq = Cout >> 2;
  int bid = blockIdx.x;
  int qc = bid % nq, n = bid / nq;
  int co0 = qc * 4;
  int tid = threadIdx.x;
  int tot = 4 * Cin * 9;
  for (int i = tid; i < tot; i += 256) {
    int cl = i / (Cin * 9), rem = i % (Cin * 9);
    int ci = rem / 9, k = rem % 9;
    int src = TRANS_W ? ((ci * Cout + co0 + cl) * 9 + (8 - k))
                      : (((co0 + cl) * Cin + ci) * 9 + k);
    sW[i] = ldg_in(w, src, fl);
  }
  __syncthreads();
  int half = tid >> 7;
  int tt = tid & 127;
  int r2 = tt >> 3, c4 = tt & 7;
  int oy0 = r2 * 2, ox0 = c4 * 4;
  int coA = co0 + half * 2;
  const float* WA = sW + (half * 2) * Cin * 9;
  const float* WB = WA + Cin * 9;
  float bvA = HAS_BIAS ? ldg_in(bias, coA, fl) : 0.f;
  float bvB = HAS_BIAS ? ldg_in(bias, coA + 1, fl) : 0.f;
  float A00 = bvA, A01 = bvA, A02 = bvA, A03 = bvA;
  float A10 = bvA, A11 = bvA, A12 = bvA, A13 = bvA;
  float B00 = bvB, B01 = bvB, B02 = bvB, B03 = bvB;
  float B10 = bvB, B11 = bvB, B12 = bvB, B13 = bvB;
  const float* ip = in + (size_t)n * Cin * HW;
  for (int ci = 0; ci < Cin; ++ci) {
    const float* p = ip + ci * HW;
    const float* wa = WA + ci * 9;
    const float* wb = WB + ci * 9;
    float x0, x1, x2, x3, x4, x5;
    if (oy0 > 0) {                     // r=0: iy=oy0-1, feeds out-row0 ky0
      C33_LOAD(p + (oy0 - 1) * 32)
      C33(A00, A01, A02, A03, wa[0], wa[1], wa[2])
      C33(B00, B01, B02, B03, wb[0], wb[1], wb[2])
    }
    {                                  // r=1: iy=oy0, row0 ky1 + row1 ky0
      C33_LOAD(p + oy0 * 32)
      C33(A00, A01, A02, A03, wa[3], wa[4], wa[5])
      C33(A10, A11, A12, A13, wa[0], wa[1], wa[2])
      C33(B00, B01, B02, B03, wb[3], wb[4], wb[5])
      C33(B10, B11, B12, B13, wb[0], wb[1], wb[2])
    }
    {                                  // r=2: iy=oy0+1, row0 ky2 + row1 ky1
      C33_LOAD(p + (oy0 + 1) * 32)
      C33(A00, A01, A02, A03, wa[6], wa[7], wa[8])
      C33(A10, A11, A12, A13, wa[3], wa[4], wa[5])
      C33(B00, B01, B02, B03, wb[6], wb[7], wb[8])
      C33(B10, B11, B12, B13, wb[3], wb[4], wb[5])
    }
    if (oy0 < 30) {                    // r=3: iy=oy0+2, row1 ky2
      C33_LOAD(p + (oy0 + 2) * 32)
      C33(A10, A11, A12, A13, wa[6], wa[7], wa[8])
      C33(B10, B11, B12, B13, wb[6], wb[7], wb[8])
    }
  }
  float* op = out + (size_t)(n * Cout + coA) * HW + oy0 * 32 + ox0;
  if (OUT_RELU) {
    op[0] = fmaxf(A00, 0.f); op[1] = fmaxf(A01, 0.f); op[2] = fmaxf(A02, 0.f); op[3] = fmaxf(A03, 0.f);
    op[32] = fmaxf(A10, 0.f); op[33] = fmaxf(A11, 0.f); op[34] = fmaxf(A12, 0.f); op[35] = fmaxf(A13, 0.f);
    op += HW;
    op[0] = fmaxf(B00, 0.f); op[1] = fmaxf(B01, 0.f); op[2] = fmaxf(B02, 0.f); op[3] = fmaxf(B03, 0.f);
    op[32] = fmaxf(B10, 0.f); op[33] = fmaxf(B11, 0.f); op[34] = fmaxf(B12, 0.f); op[35] = fmaxf(B13, 0.f);
  } else {
    op[0] = A00; op[1] = A01; op[2] = A02; op[3] = A03;
    op[32] = A10; op[33] = A11; op[34] = A12; op[35] = A13;
    op += HW;
    op[0] = B00; op[1] = B01; op[2] = B02; op[3] = B03;
    op[32] = B10; op[33] = B11; op[34] = B12; op[35] = B13;
  }
}

// ---------------- 1x1 conv @32x32: 4co x 4p register tile ----------------
template<bool ACCUM, bool HAS_BIAS, bool OUT_RELU>
__global__ __launch_bounds__(256) void k_conv1x1_t4(
    const float* __restrict__ in, const void* __restrict__ w,
    const void* __restrict__ bias, float* __restrict__ out,
    const int* __restrict__ flag, int Cin, int Cout)
{
  const int HW = 1024;
  __shared__ float sW[512];
  int fl = flag[0];
  int nq = Cout >> 2;
  int bid = blockIdx.x;
  int qc = bid % nq, n = bid / nq;
  int co0 = qc * 4;
  int tid = threadIdx.x;
  for (int i = tid; i < 4 * Cin; i += 256)
    sW[i] = ldg_in(w, co0 * Cin + i, fl);
  __syncthreads();
  float acc[4][4];
  #pragma unroll
  for (int c = 0; c < 4; ++c) {
    float bv = HAS_BIAS ? ldg_in(bias, co0 + c, fl) : 0.f;
    #pragma unroll
    for (int k = 0; k < 4; ++k) acc[c][k] = bv;
  }
  const float* ip = in + (size_t)n * Cin * HW + tid;
  for (int ci = 0; ci < Cin; ++ci) {
    const float* p = ip + ci * HW;
    float x0 = p[0], x1 = p[256], x2 = p[512], x3 = p[768];
    #pragma unroll
    for (int c = 0; c < 4; ++c) {
      float wv = sW[c * Cin + ci];
      acc[c][0] = fmaf(wv, x0, acc[c][0]);
      acc[c][1] = fmaf(wv, x1, acc[c][1]);
      acc[c][2] = fmaf(wv, x2, acc[c][2]);
      acc[c][3] = fmaf(wv, x3, acc[c][3]);
    }
  }
  #pragma unroll
  for (int c = 0; c < 4; ++c) {
    float* op = out + (size_t)(n * Cout + co0 + c) * HW + tid;
    #pragma unroll
    for (int k = 0; k < 4; ++k) {
      float v = acc[c][k];
      if (ACCUM) v += op[k * 256];
      if (OUT_RELU) v = fmaxf(v, 0.f);
      op[k * 256] = v;
    }
  }
}

// ---- ConvTranspose s2 k4 p1 parity-quad macros (scalar form) ----
// quad output from 3 input rows (m=qa-1, c=qa, d=qa+1), cols j..j+2:
#define LOADW16(BASE) \
  w00 = (BASE)[0];  w01 = (BASE)[1];  w02 = (BASE)[2];  w03 = (BASE)[3];  \
  w10 = (BASE)[4];  w11 = (BASE)[5];  w12 = (BASE)[6];  w13 = (BASE)[7];  \
  w20 = (BASE)[8];  w21 = (BASE)[9];  w22 = (BASE)[10]; w23 = (BASE)[11]; \
  w30 = (BASE)[12]; w31 = (BASE)[13]; w32 = (BASE)[14]; w33 = (BASE)[15];

#define CT_J(P00, P01, P10, P11, M0, M1, M2, C0, C1, C2, D0, D1, D2) \
  P00 = fmaf(w11, C1, fmaf(w13, C0, fmaf(w31, M1, fmaf(w33, M0, P00)))); \
  P01 = fmaf(w10, C2, fmaf(w12, C1, fmaf(w30, M2, fmaf(w32, M1, P01)))); \
  P10 = fmaf(w01, D1, fmaf(w03, D0, fmaf(w21, C1, fmaf(w23, C0, P10)))); \
  P11 = fmaf(w00, D2, fmaf(w02, D1, fmaf(w20, C2, fmaf(w22, C1, P11))));

// ---------------- up1: convT s2 k4, 128ch 32x32 -> 64ch 64x64, 2 co/thread ----------------
__global__ __launch_bounds__(256) void k_convT_up1(
    const float* __restrict__ in, const void* __restrict__ w,
    const void* __restrict__ bias, float* __restrict__ out,
    const int* __restrict__ flag)
{
  const int Cin = 128, Cout = 64;
  __shared__ float sW[4096];           // 2 co x 128ci x 16
  int fl = flag[0];
  int bid = blockIdx.x;
  int cp = bid & 31, n = bid >> 5;
  int co0 = cp * 2;
  int tid = threadIdx.x;
  for (int i = tid; i < 4096; i += 256) {
    int cl = i >> 11, rem = i & 2047;
    int ci = rem >> 4, k = rem & 15;
    sW[i] = ldg_in(w, (ci * Cout + co0 + cl) * 16 + k, fl);
  }
  __syncthreads();
  int qa = tid >> 3;                   // 0..31
  int qb0 = (tid & 7) * 4;             // 0..28
  float bv0 = ldg_in(bias, co0, fl), bv1 = ldg_in(bias, co0 + 1, fl);
  float uA0 = bv0, uA1 = bv0, uA2 = bv0, uA3 = bv0;   // pos00 j0..3
  float uB0 = bv0, uB1 = bv0, uB2 = bv0, uB3 = bv0;   // pos01
  float uC0 = bv0, uC1 = bv0, uC2 = bv0, uC3 = bv0;   // pos10
  float uD0 = bv0, uD1 = bv0, uD2 = bv0, uD3 = bv0;   // pos11
  float vA0 = bv1, vA1 = bv1, vA2 = bv1, vA3 = bv1;
  float vB0 = bv1, vB1 = bv1, vB2 = bv1, vB3 = bv1;
  float vC0 = bv1, vC1 = bv1, vC2 = bv1, vC3 = bv1;
  float vD0 = bv1, vD1 = bv1, vD2 = bv1, vD3 = bv1;
  const float* ip = in + (size_t)n * Cin * 1024;
  bool vm = qa >= 1, vd = qa + 1 < 32;
  bool vl = qb0 > 0, vr = qb0 < 28;
  for (int ci = 0; ci < Cin; ++ci) {
    const float* p = ip + ci * 1024;
    const float* rm = p + (qa - 1) * 32;
    const float* rc = p + qa * 32;
    const float* rd = p + (qa + 1) * 32;
    float m0 = (vm && vl) ? rm[qb0 - 1] : 0.f;
    float m1 = vm ? rm[qb0] : 0.f, m2 = vm ? rm[qb0 + 1] : 0.f;
    float m3 = vm ? rm[qb0 + 2] : 0.f, m4 = vm ? rm[qb0 + 3] : 0.f;
    float m5 = (vm && vr) ? rm[qb0 + 4] : 0.f;
    float c0 = vl ? rc[qb0 - 1] : 0.f;
    float c1 = rc[qb0], c2 = rc[qb0 + 1], c3 = rc[qb0 + 2], c4 = rc[qb0 + 3];
    float c5 = vr ? rc[qb0 + 4] : 0.f;
    float d0 = (vd && vl) ? rd[qb0 - 1] : 0.f;
    float d1 = vd ? rd[qb0] : 0.f, d2 = vd ? rd[qb0 + 1] : 0.f;
    float d3 = vd ? rd[qb0 + 2] : 0.f, d4 = vd ? rd[qb0 + 3] : 0.f;
    float d5 = (vd && vr) ? rd[qb0 + 4] : 0.f;
    float w00, w01, w02, w03, w10, w11, w12, w13, w20, w21, w22, w23, w30, w31, w32, w33;
    {
      LOADW16(sW + ci * 16)
      CT_J(uA0, uB0, uC0, uD0, m0, m1, m2, c0, c1, c2, d0, d1, d2)
      CT_J(uA1, uB1, uC1, uD1, m1, m2, m3, c1, c2, c3, d1, d2, d3)
      CT_J(uA2, uB2, uC2, uD2, m2, m3, m4, c2, c3, c4, d2, d3, d4)
      CT_J(uA3, uB3, uC3, uD3, m3, m4, m5, c3, c4, c5, d3, d4, d5)
    }
    {
      LOADW16(sW + 2048 + ci * 16)
      CT_J(vA0, vB0, vC0, vD0, m0, m1, m2, c0, c1, c2, d0, d1, d2)
      CT_J(vA1, vB1, vC1, vD1, m1, m2, m3, c1, c2, c3, d1, d2, d3)
      CT_J(vA2, vB2, vC2, vD2, m2, m3, m4, c2, c3, c4, d2, d3, d4)
      CT_J(vA3, vB3, vC3, vD3, m3, m4, m5, c3, c4, c5, d3, d4, d5)
    }
  }
  float* op = out + ((size_t)(n * Cout + co0) * 64 + 2 * qa) * 64 + 2 * qb0;
  op[0] = fmaxf(uA0, 0.f); op[1] = fmaxf(uB0, 0.f);
  op[2] = fmaxf(uA1, 0.f); op[3] = fmaxf(uB1, 0.f);
  op[4] = fmaxf(uA2, 0.f); op[5] = fmaxf(uB2, 0.f);
  op[6] = fmaxf(uA3, 0.f); op[7] = fmaxf(uB3, 0.f);
  op[64] = fmaxf(uC0, 0.f); op[65] = fmaxf(uD0, 0.f);
  op[66] = fmaxf(uC1, 0.f); op[67] = fmaxf(uD1, 0.f);
  op[68] = fmaxf(uC2, 0.f); op[69] = fmaxf(uD2, 0.f);
  op[70] = fmaxf(uC3, 0.f); op[71] = fmaxf(uD3, 0.f);
  op += (size_t)64 * 64;
  op[0] = fmaxf(vA0, 0.f); op[1] = fmaxf(vB0, 0.f);
  op[2] = fmaxf(vA1, 0.f); op[3] = fmaxf(vB1, 0.f);
  op[4] = fmaxf(vA2, 0.f); op[5] = fmaxf(vB2, 0.f);
  op[6] = fmaxf(vA3, 0.f); op[7] = fmaxf(vB3, 0.f);
  op[64] = fmaxf(vC0, 0.f); op[65] = fmaxf(vD0, 0.f);
  op[66] = fmaxf(vC1, 0.f); op[67] = fmaxf(vD1, 0.f);
  op[68] = fmaxf(vC2, 0.f); op[69] = fmaxf(vD2, 0.f);
  op[70] = fmaxf(vC3, 0.f); op[71] = fmaxf(vD3, 0.f);
}

// ---------------- up2: convT s2 k4, 64ch 64x64 -> 3ch 128x128, all 3 co/thread ----------------
__global__ __launch_bounds__(256) void k_convT_up2(
    const float* __restrict__ in, const void* __restrict__ w,
    const void* __restrict__ bias, float* __restrict__ out,
    const int* __restrict__ flag)
{
  const int Cin = 64;
  __shared__ float sW[3072];           // 64ci x 3co x 16, native layout
  int fl = flag[0];
  int bid = blockIdx.x;
  int s = bid & 7, n = bid >> 3;
  int tid = threadIdx.x;
  for (int i = tid; i < 3072; i += 256)
    sW[i] = ldg_in(w, i, fl);
  __syncthreads();
  int qa = s * 8 + (tid >> 5);         // 0..63
  int qb0 = (tid & 31) * 2;            // 0..62
  float bp = ldg_in(bias, 0, fl), bq = ldg_in(bias, 1, fl), br = ldg_in(bias, 2, fl);
  float pA0 = bp, pA1 = bp, pB0 = bp, pB1 = bp, pC0 = bp, pC1 = bp, pD0 = bp, pD1 = bp;
  float qA0 = bq, qA1 = bq, qB0_ = bq, qB1 = bq, qC0 = bq, qC1 = bq, qD0 = bq, qD1 = bq;
  float rA0 = br, rA1 = br, rB0 = br, rB1 = br, rC0 = br, rC1 = br, rD0 = br, rD1 = br;
  const float* ip = in + (size_t)n * Cin * 4096;
  bool vm = qa >= 1, vd = qa + 1 < 64;
  bool vl = qb0 > 0, vr = qb0 < 62;
  for (int ci = 0; ci < Cin; ++ci) {
    const float* p = ip + ci * 4096;
    const float* rm = p + (qa - 1) * 64;
    const float* rc = p + qa * 64;
    const float* rd = p + (qa + 1) * 64;
    float m0 = (vm && vl) ? rm[qb0 - 1] : 0.f;
    float m1 = vm ? rm[qb0] : 0.f, m2 = vm ? rm[qb0 + 1] : 0.f;
    float m3 = (vm && vr) ? rm[qb0 + 2] : 0.f;
    float c0 = vl ? rc[qb0 - 1] : 0.f;
    float c1 = rc[qb0], c2 = rc[qb0 + 1];
    float c3 = vr ? rc[qb0 + 2] : 0.f;
    float d0 = (vd && vl) ? rd[qb0 - 1] : 0.f;
    float d1 = vd ? rd[qb0] : 0.f, d2 = vd ? rd[qb0 + 1] : 0.f;
    float d3 = (vd && vr) ? rd[qb0 + 2] : 0.f;
    float w00, w01, w02, w03, w10, w11, w12, w13, w20, w21, w22, w23, w30, w31, w32, w33;
    {
      LOADW16(sW + ci * 48)
      CT_J(pA0, pB0, pC0, pD0, m0, m1, m2, c0, c1, c2, d0, d1, d2)
      CT_J(pA1, pB1, pC1, pD1, m1, m2, m3, c1, c2, c3, d1, d2, d3)
    }
    {
      LOADW16(sW + ci * 48 + 16)
      CT_J(qA0, qB0_, qC0, qD0, m0, m1, m2, c0, c1, c2, d0, d1, d2)
      CT_J(qA1, qB1, qC1, qD1, m1, m2, m3, c1, c2, c3, d1, d2, d3)
    }
    {
      LOADW16(sW + ci * 48 + 32)
      CT_J(rA0, rB0, rC0, rD0, m0, m1, m2, c0, c1, c2, d0, d1, d2)
      CT_J(rA1, rB1, rC1, rD1, m1, m2, m3, c1, c2, c3, d1, d2, d3)
    }
  }
  float* op = out + ((size_t)(n * 3 + 0) * 128 + 2 * qa) * 128 + 2 * qb0;
  op[0] = pA0; op[1] = pB0; op[2] = pA1; op[3] = pB1;
  op[128] = pC0; op[129] = pD0; op[130] = pC1; op[131] = pD1;
  op += (size_t)128 * 128;
  op[0] = qA0; op[1] = qB0_; op[2] = qA1; op[3] = qB1;
  op[128] = qC0; op[129] = qD0; op[130] = qC1; op[131] = qD1;
  op += (size_t)128 * 128;
  op[0] = rA0; op[1] = rB0; op[2] = rA1; op[3] = rB1;
  op[128] = rC0; op[129] = rD0; op[130] = rC1; op[131] = rD1;
}

// ---------------- VQ: argmin (first-min), zq in-place, idx (fp32) to d_out ----------------
__global__ __launch_bounds__(256) void k_vq(
    const float* __restrict__ z, const void* __restrict__ emb,
    float* __restrict__ zq, float* __restrict__ idx_out,
    const int* __restrict__ flag, float* __restrict__ lossp, int lossbase)
{
  __shared__ float sE[8192];
  __shared__ float sEE[128];
  __shared__ float wsum[4];
  int fl = flag[0];
  int tid = threadIdx.x;
  int n = blockIdx.x * 256 + tid;
  int nb = n >> 10, p = n & 1023;
  const float* zp = z + nb * 65536 + p;
  float zv[64];
  float zz = 0.f;
  #pragma unroll
  for (int d = 0; d < 64; ++d) { zv[d] = zp[d * 1024]; zz = fmaf(zv[d], zv[d], zz); }
  float best = 3.4e38f; int bidx = 0;
  for (int kb = 0; kb < 8; ++kb) {
    __syncthreads();
    for (int i = tid; i < 8192; i += 256) sE[i] = ldg_in(emb, kb * 8192 + i, fl);
    __syncthreads();
    if (tid < 128) {
      float s = 0.f;
      #pragma unroll
      for (int d = 0; d < 64; ++d) s = fmaf(sE[tid * 64 + d], sE[tid * 64 + d], s);
      sEE[tid] = s;
    }
    __syncthreads();
    for (int k = 0; k < 128; ++k) {
      const float* ep = sE + k * 64;
      float dot = 0.f;
      #pragma unroll
      for (int d = 0; d < 64; ++d) dot = fmaf(zv[d], ep[d], dot);
      float dist = zz + sEE[k] - 2.f * dot;
      if (dist < best) { best = dist; bidx = kb * 128 + k; }  // strict <: first min wins
    }
  }
  idx_out[n] = (float)bidx;
  float ls = 0.f;
  float* qp = zq + nb * 65536 + p;
  #pragma unroll
  for (int d = 0; d < 64; ++d) {
    float e = ldg_in(emb, bidx * 64 + d, fl);
    qp[d * 1024] = e;
    float df = e - zv[d];
    ls = fmaf(df, df, ls);
  }
  #pragma unroll
  for (int off = 32; off > 0; off >>= 1) ls += __shfl_down(ls, off);
  if ((tid & 63) == 0) wsum[tid >> 6] = ls;
  __syncthreads();
  if (tid == 0) lossp[lossbase + blockIdx.x] = wsum[0] + wsum[1] + wsum[2] + wsum[3];
}

__global__ void k_loss_final(const float* __restrict__ lossp, float* __restrict__ out) {
  if (threadIdx.x == 0 && blockIdx.x == 0) {
    float s = 0.f;
    for (int i = 0; i < 256; ++i) s += lossp[i];
    float L = s * (1.f / 4194304.f);
    out[R_RECON + 0] = L;
    out[R_RECON + 1] = L;
  }
}

extern "C" void kernel_launch(void* const* d_in, const int* in_sizes, int n_in,
                              void* d_out, int out_size, void* d_ws, size_t ws_size,
                              hipStream_t stream)
{
  float* out = (float*)d_out;          // fp32 output (established R8-R10)

  float* F = (float*)d_ws;
  float* LOSSP = F;
  int* FLAG = (int*)(F + 256);
  float* A = F + 272;

  int Bc = 64;
  while (Bc > 1 && 4ull * (272ull + (size_t)Bc * 393216ull) > ws_size) Bc >>= 1;
  float* H1 = A;
  float* H2 = A + (size_t)Bc * 262144;
  float* H3 = A;
  float* T  = A + (size_t)Bc * 131072;
  float* Z  = A + (size_t)Bc * 163840;
  float* D1 = H2;
  float* D2 = A;

  const void* patch = d_in[0];
  const void* ew1 = d_in[1];  const void* eb1 = d_in[2];
  const void* ew2 = d_in[3];  const void* eb2 = d_in[4];
  const void* ew3 = d_in[5];  const void* eb3 = d_in[6];
  const void* er1a = d_in[7]; const void* er1b = d_in[8];
  const void* er2a = d_in[9]; const void* er2b = d_in[10];
  const void* pqw = d_in[11]; const void* pqb = d_in[12];
  const void* emb = d_in[13];
  const void* dw1 = d_in[14]; const void* db1 = d_in[15];
  const void* dr1a = d_in[16]; const void* dr1b = d_in[17];
  const void* dr2a = d_in[18]; const void* dr2b = d_in[19];
  const void* dw2 = d_in[20]; const void* db2 = d_in[21];
  const void* dw3 = d_in[22]; const void* db3 = d_in[23];

  k_detect<<<1, 256, 0, stream>>>((const u16*)patch, FLAG);

  int NC = 64 / Bc;
  for (int c = 0; c < NC; ++c) {
    int b0 = c * Bc;

    // ---- encoder ----
    k_conv_s2k4<true><<<Bc * 1024, 256, 0, stream>>>(patch, ew1, eb1, H1, FLAG,
                                                     b0 * 49152, 3, 128, 64, 64);
    k_enc2<<<Bc * 32, 256, 0, stream>>>(H1, ew2, eb2, H2, FLAG);
    k_conv3x3_s<false, false, false, true><<<Bc * 32, 256, 0, stream>>>(H2, ew3, eb3, H3, FLAG, 128, 128);
    k_conv3x3_s<true, false, true, false><<<Bc * 8, 256, 0, stream>>>(H3, er1a, nullptr, T, FLAG, 128, 32);
    k_conv1x1_t4<true, false, false><<<Bc * 32, 256, 0, stream>>>(T, er1b, nullptr, H3, FLAG, 32, 128);
    k_conv3x3_s<true, false, true, false><<<Bc * 8, 256, 0, stream>>>(H3, er2a, nullptr, T, FLAG, 128, 32);
    k_conv1x1_t4<true, false, true><<<Bc * 32, 256, 0, stream>>>(T, er2b, nullptr, H3, FLAG, 32, 128);
    k_conv1x1_t4<false, true, false><<<Bc * 16, 256, 0, stream>>>(H3, pqw, pqb, Z, FLAG, 128, 64);

    // ---- VQ ----
    k_vq<<<Bc * 4, 256, 0, stream>>>(Z, emb, Z, out + R_RECON + 2 + (size_t)b0 * 1024,
                                     FLAG, LOSSP, b0 * 4);

    // ---- decoder ----
    k_conv3x3_s<false, true, false, true><<<Bc * 32, 256, 0, stream>>>(Z, dw1, db1, D1, FLAG, 64, 128);
    k_conv3x3_s<true, false, true, false><<<Bc * 8, 256, 0, stream>>>(D1, dr1a, nullptr, T, FLAG, 128, 32);
    k_conv1x1_t4<true, false, false><<<Bc * 32, 256, 0, stream>>>(T, dr1b, nullptr, D1, FLAG, 32, 128);
    k_conv3x3_s<true, false, true, false><<<Bc * 8, 256, 0, stream>>>(D1, dr2a, nullptr, T, FLAG, 128, 32);
    k_conv1x1_t4<true, false, true><<<Bc * 32, 256, 0, stream>>>(T, dr2b, nullptr, D1, FLAG, 32, 128);
    k_convT_up1<<<Bc * 32, 256, 0, stream>>>(D1, dw2, db2, D2, FLAG);
    k_convT_up2<<<Bc * 8, 256, 0, stream>>>(D2, dw3, db3, out + (size_t)b0 * 49152, FLAG);
  }

  k_loss_final<<<1, 64, 0, stream>>>(LOSSP, out);
}

// Round 15
// 3943.660 us; speedup vs baseline: 4.1699x; 1.1009x over previous
//
#include <hip/hip_runtime.h>
#include <hip/hip_bf16.h>

typedef __hip_bfloat16 bf16;
typedef unsigned short u16;

#define R_RECON 3145728
#define N_IDX   65536

__device__ __forceinline__ float ldg_in(const void* p, int i, int fl) {
  return fl ? ((const float*)p)[i] : __bfloat162float(((const bf16*)p)[i]);
}

__global__ __launch_bounds__(256) void k_detect(const u16* __restrict__ p, int* __restrict__ flag) {
  __shared__ int s;
  if (threadIdx.x == 0) s = 0;
  __syncthreads();
  for (int i = threadIdx.x; i < 4096; i += 256) {
    float f = __uint_as_float(((unsigned)p[i]) << 16);
    if (!(fabsf(f) < 16384.f)) atomicOr(&s, 1);
  }
  __syncthreads();
  if (threadIdx.x == 0) flag[0] = s;
}

// ---------------- enc1: stride-2 4x4 conv from global input (Cin=3) ----------------
template<bool GIN>
__global__ __launch_bounds__(256) void k_conv_s2k4(
    const void* __restrict__ inp, const void* __restrict__ w,
    const void* __restrict__ bias, float* __restrict__ out,
    const int* __restrict__ flag, int in_off,
    int Cin, int Hin, int Cout, int Hout)
{
  __shared__ float sW[1024];
  int fl = flag[0];
  int tid = threadIdx.x;
  int idx = blockIdx.x * 256 + tid;
  int hw = Hout * Hout;
  int co = (idx / hw) % Cout;
  for (int i = tid; i < Cin * 16; i += 256)
    sW[i] = ldg_in(w, co * Cin * 16 + i, fl);
  __syncthreads();
  int ox = idx % Hout; int t = idx / Hout;
  int oy = t % Hout;
  int n = idx / (hw * Cout);
  float acc = ldg_in(bias, co, fl);
  int iy0 = 2 * oy - 1, ix0 = 2 * ox - 1;
  const float* inf = (const float*)inp;
  for (int ci = 0; ci < Cin; ++ci) {
    int base_in = (n * Cin + ci) * Hin * Hin;
    const float* wp = sW + ci * 16;
    #pragma unroll
    for (int ky = 0; ky < 4; ++ky) {
      int iy = iy0 + ky;
      if ((unsigned)iy >= (unsigned)Hin) continue;
      int rb = base_in + iy * Hin;
      #pragma unroll
      for (int kx = 0; kx < 4; ++kx) {
        int ix = ix0 + kx;
        if ((unsigned)ix >= (unsigned)Hin) continue;
        float v = GIN ? ldg_in(inp, in_off + rb + ix, fl) : inf[rb + ix];
        acc = fmaf(v, wp[ky * 4 + kx], acc);
      }
    }
  }
  out[idx] = fmaxf(acc, 0.f);
}

// ---------------- enc2: s2 k4, 64ch 64x64 -> 128ch 32x32; 4 co per thread ----------------
__global__ __launch_bounds__(256) void k_enc2(
    const float* __restrict__ in, const void* __restrict__ w,
    const void* __restrict__ bias, float* __restrict__ out,
    const int* __restrict__ flag)
{
  const int Cin = 64, Cout = 128;
  __shared__ float sW[4096];
  int fl = flag[0];
  int bid = blockIdx.x;
  int cp = bid & 31, n = bid >> 5;
  int co0 = cp * 4;
  int tid = threadIdx.x;
  for (int i = tid; i < 4096; i += 256)
    sW[i] = ldg_in(w, co0 * 1024 + i, fl);
  __syncthreads();
  int oy = tid >> 3, ox0 = (tid & 7) << 2;
  float bvA = ldg_in(bias, co0, fl), bvB = ldg_in(bias, co0 + 1, fl);
  float bvC = ldg_in(bias, co0 + 2, fl), bvD = ldg_in(bias, co0 + 3, fl);
  float a0 = bvA, a1 = bvA, a2 = bvA, a3 = bvA;
  float b0 = bvB, b1 = bvB, b2 = bvB, b3 = bvB;
  float c0 = bvC, c1 = bvC, c2 = bvC, c3 = bvC;
  float d0 = bvD, d1 = bvD, d2 = bvD, d3 = bvD;
  int ry0 = 2 * oy - 1;
  int cx0 = 2 * ox0 - 1;
  const float* ip = in + (size_t)n * Cin * 4096;
  for (int ci = 0; ci < Cin; ++ci) {
    const float* p = ip + ci * 4096;
    #pragma unroll
    for (int ky = 0; ky < 4; ++ky) {
      int iy = ry0 + ky;
      if ((unsigned)iy < 64u) {
        const float* rp = p + iy * 64;
        float x0 = (cx0 >= 0) ? rp[cx0] : 0.f;
        float x1 = rp[cx0 + 1], x2 = rp[cx0 + 2], x3 = rp[cx0 + 3], x4 = rp[cx0 + 4];
        float x5 = rp[cx0 + 5], x6 = rp[cx0 + 6], x7 = rp[cx0 + 7], x8 = rp[cx0 + 8];
        float x9 = (cx0 + 9 < 64) ? rp[cx0 + 9] : 0.f;
        int wb = ci * 16 + ky * 4;
        {
          float wa0 = sW[wb], wa1 = sW[wb + 1], wa2 = sW[wb + 2], wa3 = sW[wb + 3];
          a0 = fmaf(x0, wa0, fmaf(x1, wa1, fmaf(x2, wa2, fmaf(x3, wa3, a0))));
          a1 = fmaf(x2, wa0, fmaf(x3, wa1, fmaf(x4, wa2, fmaf(x5, wa3, a1))));
          a2 = fmaf(x4, wa0, fmaf(x5, wa1, fmaf(x6, wa2, fmaf(x7, wa3, a2))));
          a3 = fmaf(x6, wa0, fmaf(x7, wa1, fmaf(x8, wa2, fmaf(x9, wa3, a3))));
          float wb0 = sW[wb + 1024], wb1 = sW[wb + 1025], wb2 = sW[wb + 1026], wb3 = sW[wb + 1027];
          b0 = fmaf(x0, wb0, fmaf(x1, wb1, fmaf(x2, wb2, fmaf(x3, wb3, b0))));
          b1 = fmaf(x2, wb0, fmaf(x3, wb1, fmaf(x4, wb2, fmaf(x5, wb3, b1))));
          b2 = fmaf(x4, wb0, fmaf(x5, wb1, fmaf(x6, wb2, fmaf(x7, wb3, b2))));
          b3 = fmaf(x6, wb0, fmaf(x7, wb1, fmaf(x8, wb2, fmaf(x9, wb3, b3))));
        }
        {
          float wc0 = sW[wb + 2048], wc1 = sW[wb + 2049], wc2 = sW[wb + 2050], wc3 = sW[wb + 2051];
          c0 = fmaf(x0, wc0, fmaf(x1, wc1, fmaf(x2, wc2, fmaf(x3, wc3, c0))));
          c1 = fmaf(x2, wc0, fmaf(x3, wc1, fmaf(x4, wc2, fmaf(x5, wc3, c1))));
          c2 = fmaf(x4, wc0, fmaf(x5, wc1, fmaf(x6, wc2, fmaf(x7, wc3, c2))));
          c3 = fmaf(x6, wc0, fmaf(x7, wc1, fmaf(x8, wc2, fmaf(x9, wc3, c3))));
          float wd0 = sW[wb + 3072], wd1 = sW[wb + 3073], wd2 = sW[wb + 3074], wd3 = sW[wb + 3075];
          d0 = fmaf(x0, wd0, fmaf(x1, wd1, fmaf(x2, wd2, fmaf(x3, wd3, d0))));
          d1 = fmaf(x2, wd0, fmaf(x3, wd1, fmaf(x4, wd2, fmaf(x5, wd3, d1))));
          d2 = fmaf(x4, wd0, fmaf(x5, wd1, fmaf(x6, wd2, fmaf(x7, wd3, d2))));
          d3 = fmaf(x6, wd0, fmaf(x7, wd1, fmaf(x8, wd2, fmaf(x9, wd3, d3))));
        }
      }
    }
  }
  float* op = out + (size_t)(n * Cout + co0) * 1024 + oy * 32 + ox0;
  op[0] = fmaxf(a0, 0.f); op[1] = fmaxf(a1, 0.f); op[2] = fmaxf(a2, 0.f); op[3] = fmaxf(a3, 0.f);
  op += 1024;
  op[0] = fmaxf(b0, 0.f); op[1] = fmaxf(b1, 0.f); op[2] = fmaxf(b2, 0.f); op[3] = fmaxf(b3, 0.f);
  op += 1024;
  op[0] = fmaxf(c0, 0.f); op[1] = fmaxf(c1, 0.f); op[2] = fmaxf(c2, 0.f); op[3] = fmaxf(c3, 0.f);
  op += 1024;
  op[0] = fmaxf(d0, 0.f); op[1] = fmaxf(d1, 0.f); op[2] = fmaxf(d2, 0.f); op[3] = fmaxf(d3, 0.f);
}

// ---- 3x3 conv s1 p1 @32x32: 4x4 px tile, 2 co/thread, 4 co/block, 128 threads ----
#define C4(P0, P1, P2, P3, W0, W1, W2) \
  P0 = fmaf(x0, W0, fmaf(x1, W1, fmaf(x2, W2, P0))); \
  P1 = fmaf(x1, W0, fmaf(x2, W1, fmaf(x3, W2, P1))); \
  P2 = fmaf(x2, W0, fmaf(x3, W1, fmaf(x4, W2, P2))); \
  P3 = fmaf(x3, W0, fmaf(x4, W1, fmaf(x5, W2, P3)));

#define ROW_AB(T, KY) \
  C4(A##T##0, A##T##1, A##T##2, A##T##3, wa[3*KY], wa[3*KY+1], wa[3*KY+2]) \
  C4(B##T##0, B##T##1, B##T##2, B##T##3, wb[3*KY], wb[3*KY+1], wb[3*KY+2])

#define C33_LOAD(RP) \
  x0 = (ox0 > 0) ? (RP)[ox0 - 1] : 0.f; \
  x1 = (RP)[ox0]; x2 = (RP)[ox0 + 1]; x3 = (RP)[ox0 + 2]; x4 = (RP)[ox0 + 3]; \
  x5 = (ox0 < 28) ? (RP)[ox0 + 4] : 0.f; \
  if (IN_RELU) { \
    x0 = fmaxf(x0, 0.f); x1 = fmaxf(x1, 0.f); x2 = fmaxf(x2, 0.f); \
    x3 = fmaxf(x3, 0.f); x4 = fmaxf(x4, 0.f); x5 = fmaxf(x5, 0.f); \
  }

#define ST_ROW4(PTR, P0, P1, P2, P3) \
  if (OUT_RELU) { (PTR)[0] = fmaxf(P0, 0.f); (PTR)[1] = fmaxf(P1, 0.f); \
                  (PTR)[2] = fmaxf(P2, 0.f); (PTR)[3] = fmaxf(P3, 0.f); } \
  else { (PTR)[0] = P0; (PTR)[1] = P1; (PTR)[2] = P2; (PTR)[3] = P3; }

template<bool IN_RELU, bool TRANS_W, bool OUT_RELU, bool HAS_BIAS>
__global__ __launch_bounds__(128) void k_conv3x3_v2(
    const float* __restrict__ in, const void* __restrict__ w,
    const void* __restrict__ bias, float* __restrict__ out,
    const int* __restrict__ flag, int Cin, int Cout)
{
  const int HW = 1024;
  __shared__ float sW[4608];           // 4 co x Cin x 9, Cin<=128
  int fl = flag[0];
  int nq = Cout >> 2;
  int bid = blockIdx.x;
  int qc = bid % nq, n = bid / nq;
  int co0 = qc * 4;
  int tid = threadIdx.x;
  int tot = 4 * Cin * 9;
  for (int i = tid; i < tot; i += 128) {
    int cl = i / (Cin * 9), rem = i % (Cin * 9);
    int ci = rem / 9, k = rem % 9;
    int src = TRANS_W ? ((ci * Cout + co0 + cl) * 9 + (8 - k))
                      : (((co0 + cl) * Cin + ci) * 9 + k);
    sW[i] = ldg_in(w, src, fl);
  }
  __syncthreads();
  int cp = tid >> 6;                   // co-pair sel (uniform per wave)
  int tt = tid & 63;
  int ty = tt >> 3, tx = tt & 7;
  int oy0 = ty * 4, ox0 = tx * 4;
  int coA = co0 + cp * 2;
  const float* WA = sW + (cp * 2) * Cin * 9;
  const float* WB = WA + Cin * 9;
  float bvA = HAS_BIAS ? ldg_in(bias, coA, fl) : 0.f;
  float bvB = HAS_BIAS ? ldg_in(bias, coA + 1, fl) : 0.f;
  float A00=bvA,A01=bvA,A02=bvA,A03=bvA, A10=bvA,A11=bvA,A12=bvA,A13=bvA;
  float A20=bvA,A21=bvA,A22=bvA,A23=bvA, A30=bvA,A31=bvA,A32=bvA,A33=bvA;
  float B00=bvB,B01=bvB,B02=bvB,B03=bvB, B10=bvB,B11=bvB,B12=bvB,B13=bvB;
  float B20=bvB,B21=bvB,B22=bvB,B23=bvB, B30=bvB,B31=bvB,B32=bvB,B33=bvB;
  const float* ip = in + (size_t)n * Cin * HW;
  for (int ci = 0; ci < Cin; ++ci) {
    const float* p = ip + ci * HW;
    const float* wa = WA + ci * 9;
    const float* wb = WB + ci * 9;
    float x0, x1, x2, x3, x4, x5;
    if (oy0 > 0) {                     // iy = oy0-1 -> row0 ky0
      C33_LOAD(p + (oy0 - 1) * 32)
      ROW_AB(0, 0)
    }
    { C33_LOAD(p + oy0 * 32)           // iy = oy0 -> row0 ky1, row1 ky0
      ROW_AB(0, 1) ROW_AB(1, 0) }
    { C33_LOAD(p + (oy0 + 1) * 32)     // row0 ky2, row1 ky1, row2 ky0
      ROW_AB(0, 2) ROW_AB(1, 1) ROW_AB(2, 0) }
    { C33_LOAD(p + (oy0 + 2) * 32)     // row1 ky2, row2 ky1, row3 ky0
      ROW_AB(1, 2) ROW_AB(2, 1) ROW_AB(3, 0) }
    { C33_LOAD(p + (oy0 + 3) * 32)     // row2 ky2, row3 ky1
      ROW_AB(2, 2) ROW_AB(3, 1) }
    if (oy0 < 28) {                    // iy = oy0+4 -> row3 ky2
      C33_LOAD(p + (oy0 + 4) * 32)
      ROW_AB(3, 2)
    }
  }
  float* op = out + (size_t)(n * Cout + coA) * HW + oy0 * 32 + ox0;
  ST_ROW4(op,      A00, A01, A02, A03)
  ST_ROW4(op + 32, A10, A11, A12, A13)
  ST_ROW4(op + 64, A20, A21, A22, A23)
  ST_ROW4(op + 96, A30, A31, A32, A33)
  op += HW;
  ST_ROW4(op,      B00, B01, B02, B03)
  ST_ROW4(op + 32, B10, B11, B12, B13)
  ST_ROW4(op + 64, B20, B21, B22, B23)
  ST_ROW4(op + 96, B30, B31, B32, B33)
}

// ---------------- 1x1 conv @32x32: 4co x 4p register tile ----------------
template<bool ACCUM, bool HAS_BIAS, bool OUT_RELU>
__global__ __launch_bounds__(256) void k_conv1x1_t4(
    const float* __restrict__ in, const void* __restrict__ w,
    const void* __restrict__ bias, float* __restrict__ out,
    const int* __restrict__ flag, int Cin, int Cout)
{
  const int HW = 1024;
  __shared__ float sW[512];
  int fl = flag[0];
  int nq = Cout >> 2;
  int bid = blockIdx.x;
  int qc = bid % nq, n = bid / nq;
  int co0 = qc * 4;
  int tid = threadIdx.x;
  for (int i = tid; i < 4 * Cin; i += 256)
    sW[i] = ldg_in(w, co0 * Cin + i, fl);
  __syncthreads();
  float acc[4][4];
  #pragma unroll
  for (int c = 0; c < 4; ++c) {
    float bv = HAS_BIAS ? ldg_in(bias, co0 + c, fl) : 0.f;
    #pragma unroll
    for (int k = 0; k < 4; ++k) acc[c][k] = bv;
  }
  const float* ip = in + (size_t)n * Cin * HW + tid;
  for (int ci = 0; ci < Cin; ++ci) {
    const float* p = ip + ci * HW;
    float x0 = p[0], x1 = p[256], x2 = p[512], x3 = p[768];
    #pragma unroll
    for (int c = 0; c < 4; ++c) {
      float wv = sW[c * Cin + ci];
      acc[c][0] = fmaf(wv, x0, acc[c][0]);
      acc[c][1] = fmaf(wv, x1, acc[c][1]);
      acc[c][2] = fmaf(wv, x2, acc[c][2]);
      acc[c][3] = fmaf(wv, x3, acc[c][3]);
    }
  }
  #pragma unroll
  for (int c = 0; c < 4; ++c) {
    float* op = out + (size_t)(n * Cout + co0 + c) * HW + tid;
    #pragma unroll
    for (int k = 0; k < 4; ++k) {
      float v = acc[c][k];
      if (ACCUM) v += op[k * 256];
      if (OUT_RELU) v = fmaxf(v, 0.f);
      op[k * 256] = v;
    }
  }
}

// ---- ConvTranspose s2 k4 p1 parity-quad macros ----
#define LOADW16(BASE) \
  w00 = (BASE)[0];  w01 = (BASE)[1];  w02 = (BASE)[2];  w03 = (BASE)[3];  \
  w10 = (BASE)[4];  w11 = (BASE)[5];  w12 = (BASE)[6];  w13 = (BASE)[7];  \
  w20 = (BASE)[8];  w21 = (BASE)[9];  w22 = (BASE)[10]; w23 = (BASE)[11]; \
  w30 = (BASE)[12]; w31 = (BASE)[13]; w32 = (BASE)[14]; w33 = (BASE)[15];

#define CT_J(P00, P01, P10, P11, M0, M1, M2, C0, C1, C2, D0, D1, D2) \
  P00 = fmaf(w11, C1, fmaf(w13, C0, fmaf(w31, M1, fmaf(w33, M0, P00)))); \
  P01 = fmaf(w10, C2, fmaf(w12, C1, fmaf(w30, M2, fmaf(w32, M1, P01)))); \
  P10 = fmaf(w01, D1, fmaf(w03, D0, fmaf(w21, C1, fmaf(w23, C0, P10)))); \
  P11 = fmaf(w00, D2, fmaf(w02, D1, fmaf(w20, C2, fmaf(w22, C1, P11))));

#define DECL16(PX, BV) \
  float PX##A0=BV, PX##A1=BV, PX##A2=BV, PX##A3=BV, \
        PX##B0=BV, PX##B1=BV, PX##B2=BV, PX##B3=BV, \
        PX##C0=BV, PX##C1=BV, PX##C2=BV, PX##C3=BV, \
        PX##D0=BV, PX##D1=BV, PX##D2=BV, PX##D3=BV;

#define CT_CO(PX) \
  CT_J(PX##A0, PX##B0, PX##C0, PX##D0, m0, m1, m2, c0, c1, c2, d0, d1, d2) \
  CT_J(PX##A1, PX##B1, PX##C1, PX##D1, m1, m2, m3, c1, c2, c3, d1, d2, d3) \
  CT_J(PX##A2, PX##B2, PX##C2, PX##D2, m2, m3, m4, c2, c3, c4, d2, d3, d4) \
  CT_J(PX##A3, PX##B3, PX##C3, PX##D3, m3, m4, m5, c3, c4, c5, d3, d4, d5)

#define CT_STORE(PX, PTR, HO) \
  (PTR)[0] = fmaxf(PX##A0, 0.f); (PTR)[1] = fmaxf(PX##B0, 0.f); \
  (PTR)[2] = fmaxf(PX##A1, 0.f); (PTR)[3] = fmaxf(PX##B1, 0.f); \
  (PTR)[4] = fmaxf(PX##A2, 0.f); (PTR)[5] = fmaxf(PX##B2, 0.f); \
  (PTR)[6] = fmaxf(PX##A3, 0.f); (PTR)[7] = fmaxf(PX##B3, 0.f); \
  (PTR)[HO]     = fmaxf(PX##C0, 0.f); (PTR)[HO + 1] = fmaxf(PX##D0, 0.f); \
  (PTR)[HO + 2] = fmaxf(PX##C1, 0.f); (PTR)[HO + 3] = fmaxf(PX##D1, 0.f); \
  (PTR)[HO + 4] = fmaxf(PX##C2, 0.f); (PTR)[HO + 5] = fmaxf(PX##D2, 0.f); \
  (PTR)[HO + 6] = fmaxf(PX##C3, 0.f); (PTR)[HO + 7] = fmaxf(PX##D3, 0.f);

// ---------------- up1: convT s2 k4, 128ch 32x32 -> 64ch 64x64, 4 co/thread ----------------
__global__ __launch_bounds__(256) void k_convT_up1(
    const float* __restrict__ in, const void* __restrict__ w,
    const void* __restrict__ bias, float* __restrict__ out,
    const int* __restrict__ flag)
{
  const int Cin = 128, Cout = 64;
  __shared__ float sW[8192];           // 4 co x 128ci x 16 (32 KB)
  int fl = flag[0];
  int bid = blockIdx.x;
  int cp = bid & 15, n = bid >> 4;
  int co0 = cp * 4;
  int tid = threadIdx.x;
  for (int i = tid; i < 8192; i += 256) {
    int cl = i >> 11, rem = i & 2047;
    int ci = rem >> 4, k = rem & 15;
    sW[i] = ldg_in(w, (ci * Cout + co0 + cl) * 16 + k, fl);
  }
  __syncthreads();
  int qa = tid >> 3;
  int qb0 = (tid & 7) * 4;
  float bv0 = ldg_in(bias, co0, fl), bv1 = ldg_in(bias, co0 + 1, fl);
  float bv2 = ldg_in(bias, co0 + 2, fl), bv3 = ldg_in(bias, co0 + 3, fl);
  DECL16(u, bv0) DECL16(v, bv1) DECL16(y, bv2) DECL16(z, bv3)
  const float* ip = in + (size_t)n * Cin * 1024;
  bool vm = qa >= 1, vd = qa + 1 < 32;
  bool vl = qb0 > 0, vr = qb0 < 28;
  for (int ci = 0; ci < Cin; ++ci) {
    const float* p = ip + ci * 1024;
    const float* rm = p + (qa - 1) * 32;
    const float* rc = p + qa * 32;
    const float* rd = p + (qa + 1) * 32;
    float m0 = (vm && vl) ? rm[qb0 - 1] : 0.f;
    float m1 = vm ? rm[qb0] : 0.f, m2 = vm ? rm[qb0 + 1] : 0.f;
    float m3 = vm ? rm[qb0 + 2] : 0.f, m4 = vm ? rm[qb0 + 3] : 0.f;
    float m5 = (vm && vr) ? rm[qb0 + 4] : 0.f;
    float c0 = vl ? rc[qb0 - 1] : 0.f;
    float c1 = rc[qb0], c2 = rc[qb0 + 1], c3 = rc[qb0 + 2], c4 = rc[qb0 + 3];
    float c5 = vr ? rc[qb0 + 4] : 0.f;
    float d0 = (vd && vl) ? rd[qb0 - 1] : 0.f;
    float d1 = vd ? rd[qb0] : 0.f, d2 = vd ? rd[qb0 + 1] : 0.f;
    float d3 = vd ? rd[qb0 + 2] : 0.f, d4 = vd ? rd[qb0 + 3] : 0.f;
    float d5 = (vd && vr) ? rd[qb0 + 4] : 0.f;
    float w00, w01, w02, w03, w10, w11, w12, w13, w20, w21, w22, w23, w30, w31, w32, w33;
    { LOADW16(sW + ci * 16)        CT_CO(u) }
    { LOADW16(sW + 2048 + ci * 16) CT_CO(v) }
    { LOADW16(sW + 4096 + ci * 16) CT_CO(y) }
    { LOADW16(sW + 6144 + ci * 16) CT_CO(z) }
  }
  float* op = out + ((size_t)(n * Cout + co0) * 64 + 2 * qa) * 64 + 2 * qb0;
  CT_STORE(u, op, 64) op += (size_t)64 * 64;
  CT_STORE(v, op, 64) op += (size_t)64 * 64;
  CT_STORE(y, op, 64) op += (size_t)64 * 64;
  CT_STORE(z, op, 64)
}

// ---------------- up2: convT s2 k4, 64ch 64x64 -> 3ch 128x128, all 3 co/thread ----------------
__global__ __launch_bounds__(256) void k_convT_up2(
    const float* __restrict__ in, const void* __restrict__ w,
    const void* __restrict__ bias, float* __restrict__ out,
    const int* __restrict__ flag)
{
  const int Cin = 64;
  __shared__ float sW[3072];
  int fl = flag[0];
  int bid = blockIdx.x;
  int s = bid & 7, n = bid >> 3;
  int tid = threadIdx.x;
  for (int i = tid; i < 3072; i += 256)
    sW[i] = ldg_in(w, i, fl);
  __syncthreads();
  int qa = s * 8 + (tid >> 5);
  int qb0 = (tid & 31) * 2;
  float bp = ldg_in(bias, 0, fl), bq = ldg_in(bias, 1, fl), br = ldg_in(bias, 2, fl);
  float pA0 = bp, pA1 = bp, pB0 = bp, pB1 = bp, pC0 = bp, pC1 = bp, pD0 = bp, pD1 = bp;
  float qA0 = bq, qA1 = bq, qB0_ = bq, qB1 = bq, qC0 = bq, qC1 = bq, qD0 = bq, qD1 = bq;
  float rA0 = br, rA1 = br, rB0 = br, rB1 = br, rC0 = br, rC1 = br, rD0 = br, rD1 = br;
  const float* ip = in + (size_t)n * Cin * 4096;
  bool vm = qa >= 1, vd = qa + 1 < 64;
  bool vl = qb0 > 0, vr = qb0 < 62;
  for (int ci = 0; ci < Cin; ++ci) {
    const float* p = ip + ci * 4096;
    const float* rm = p + (qa - 1) * 64;
    const float* rc = p + qa * 64;
    const float* rd = p + (qa + 1) * 64;
    float m0 = (vm && vl) ? rm[qb0 - 1] : 0.f;
    float m1 = vm ? rm[qb0] : 0.f, m2 = vm ? rm[qb0 + 1] : 0.f;
    float m3 = (vm && vr) ? rm[qb0 + 2] : 0.f;
    float c0 = vl ? rc[qb0 - 1] : 0.f;
    float c1 = rc[qb0], c2 = rc[qb0 + 1];
    float c3 = vr ? rc[qb0 + 2] : 0.f;
    float d0 = (vd && vl) ? rd[qb0 - 1] : 0.f;
    float d1 = vd ? rd[qb0] : 0.f, d2 = vd ? rd[qb0 + 1] : 0.f;
    float d3 = (vd && vr) ? rd[qb0 + 2] : 0.f;
    float w00, w01, w02, w03, w10, w11, w12, w13, w20, w21, w22, w23, w30, w31, w32, w33;
    {
      LOADW16(sW + ci * 48)
      CT_J(pA0, pB0, pC0, pD0, m0, m1, m2, c0, c1, c2, d0, d1, d2)
      CT_J(pA1, pB1, pC1, pD1, m1, m2, m3, c1, c2, c3, d1, d2, d3)
    }
    {
      LOADW16(sW + ci * 48 + 16)
      CT_J(qA0, qB0_, qC0, qD0, m0, m1, m2, c0, c1, c2, d0, d1, d2)
      CT_J(qA1, qB1, qC1, qD1, m1, m2, m3, c1, c2, c3, d1, d2, d3)
    }
    {
      LOADW16(sW + ci * 48 + 32)
      CT_J(rA0, rB0, rC0, rD0, m0, m1, m2, c0, c1, c2, d0, d1, d2)
      CT_J(rA1, rB1, rC1, rD1, m1, m2, m3, c1, c2, c3, d1, d2, d3)
    }
  }
  float* op = out + ((size_t)(n * 3 + 0) * 128 + 2 * qa) * 128 + 2 * qb0;
  op[0] = pA0; op[1] = pB0; op[2] = pA1; op[3] = pB1;
  op[128] = pC0; op[129] = pD0; op[130] = pC1; op[131] = pD1;
  op += (size_t)128 * 128;
  op[0] = qA0; op[1] = qB0_; op[2] = qA1; op[3] = qB1;
  op[128] = qC0; op[129] = qD0; op[130] = qC1; op[131] = qD1;
  op += (size_t)128 * 128;
  op[0] = rA0; op[1] = rB0; op[2] = rA1; op[3] = rB1;
  op[128] = rC0; op[129] = rD0; op[130] = rC1; op[131] = rD1;
}

// ---------------- VQ: argmin (first-min), zq in-place, idx (fp32) to d_out ----------------
__global__ __launch_bounds__(256) void k_vq(
    const float* __restrict__ z, const void* __restrict__ emb,
    float* __restrict__ zq, float* __restrict__ idx_out,
    const int* __restrict__ flag, float* __restrict__ lossp, int lossbase)
{
  __shared__ float sE[8192];
  __shared__ float sEE[128];
  __shared__ float wsum[4];
  int fl = flag[0];
  int tid = threadIdx.x;
  int n = blockIdx.x * 256 + tid;
  int nb = n >> 10, p = n & 1023;
  const float* zp = z + nb * 65536 + p;
  float zv[64];
  float zz = 0.f;
  #pragma unroll
  for (int d = 0; d < 64; ++d) { zv[d] = zp[d * 1024]; zz = fmaf(zv[d], zv[d], zz); }
  float best = 3.4e38f; int bidx = 0;
  for (int kb = 0; kb < 8; ++kb) {
    __syncthreads();
    for (int i = tid; i < 8192; i += 256) sE[i] = ldg_in(emb, kb * 8192 + i, fl);
    __syncthreads();
    if (tid < 128) {
      float s = 0.f;
      #pragma unroll
      for (int d = 0; d < 64; ++d) s = fmaf(sE[tid * 64 + d], sE[tid * 64 + d], s);
      sEE[tid] = s;
    }
    __syncthreads();
    for (int k = 0; k < 128; ++k) {
      const float* ep = sE + k * 64;
      float dot = 0.f;
      #pragma unroll
      for (int d = 0; d < 64; ++d) dot = fmaf(zv[d], ep[d], dot);
      float dist = zz + sEE[k] - 2.f * dot;
      if (dist < best) { best = dist; bidx = kb * 128 + k; }  // strict <: first min wins
    }
  }
  idx_out[n] = (float)bidx;
  float ls = 0.f;
  float* qp = zq + nb * 65536 + p;
  #pragma unroll
  for (int d = 0; d < 64; ++d) {
    float e = ldg_in(emb, bidx * 64 + d, fl);
    qp[d * 1024] = e;
    float df = e - zv[d];
    ls = fmaf(df, df, ls);
  }
  #pragma unroll
  for (int off = 32; off > 0; off >>= 1) ls += __shfl_down(ls, off);
  if ((tid & 63) == 0) wsum[tid >> 6] = ls;
  __syncthreads();
  if (tid == 0) lossp[lossbase + blockIdx.x] = wsum[0] + wsum[1] + wsum[2] + wsum[3];
}

__global__ void k_loss_final(const float* __restrict__ lossp, float* __restrict__ out) {
  if (threadIdx.x == 0 && blockIdx.x == 0) {
    float s = 0.f;
    for (int i = 0; i < 256; ++i) s += lossp[i];
    float L = s * (1.f / 4194304.f);
    out[R_RECON + 0] = L;
    out[R_RECON + 1] = L;
  }
}

extern "C" void kernel_launch(void* const* d_in, const int* in_sizes, int n_in,
                              void* d_out, int out_size, void* d_ws, size_t ws_size,
                              hipStream_t stream)
{
  float* out = (float*)d_out;          // fp32 output (established R8-R10)

  float* F = (float*)d_ws;
  float* LOSSP = F;
  int* FLAG = (int*)(F + 256);
  float* A = F + 272;

  int Bc = 64;
  while (Bc > 1 && 4ull * (272ull + (size_t)Bc * 393216ull) > ws_size) Bc >>= 1;
  float* H1 = A;
  float* H2 = A + (size_t)Bc * 262144;
  float* H3 = A;
  float* T  = A + (size_t)Bc * 131072;
  float* Z  = A + (size_t)Bc * 163840;
  float* D1 = H2;
  float* D2 = A;

  const void* patch = d_in[0];
  const void* ew1 = d_in[1];  const void* eb1 = d_in[2];
  const void* ew2 = d_in[3];  const void* eb2 = d_in[4];
  const void* ew3 = d_in[5];  const void* eb3 = d_in[6];
  const void* er1a = d_in[7]; const void* er1b = d_in[8];
  const void* er2a = d_in[9]; const void* er2b = d_in[10];
  const void* pqw = d_in[11]; const void* pqb = d_in[12];
  const void* emb = d_in[13];
  const void* dw1 = d_in[14]; const void* db1 = d_in[15];
  const void* dr1a = d_in[16]; const void* dr1b = d_in[17];
  const void* dr2a = d_in[18]; const void* dr2b = d_in[19];
  const void* dw2 = d_in[20]; const void* db2 = d_in[21];
  const void* dw3 = d_in[22]; const void* db3 = d_in[23];

  k_detect<<<1, 256, 0, stream>>>((const u16*)patch, FLAG);

  int NC = 64 / Bc;
  for (int c = 0; c < NC; ++c) {
    int b0 = c * Bc;

    // ---- encoder ----
    k_conv_s2k4<true><<<Bc * 1024, 256, 0, stream>>>(patch, ew1, eb1, H1, FLAG,
                                                     b0 * 49152, 3, 128, 64, 64);
    k_enc2<<<Bc * 32, 256, 0, stream>>>(H1, ew2, eb2, H2, FLAG);
    k_conv3x3_v2<false, false, false, true><<<Bc * 32, 128, 0, stream>>>(H2, ew3, eb3, H3, FLAG, 128, 128);
    k_conv3x3_v2<true, false, true, false><<<Bc * 8, 128, 0, stream>>>(H3, er1a, nullptr, T, FLAG, 128, 32);
    k_conv1x1_t4<true, false, false><<<Bc * 32, 256, 0, stream>>>(T, er1b, nullptr, H3, FLAG, 32, 128);
    k_conv3x3_v2<true, false, true, false><<<Bc * 8, 128, 0, stream>>>(H3, er2a, nullptr, T, FLAG, 128, 32);
    k_conv1x1_t4<true, false, true><<<Bc * 32, 256, 0, stream>>>(T, er2b, nullptr, H3, FLAG, 32, 128);
    k_conv1x1_t4<false, true, false><<<Bc * 16, 256, 0, stream>>>(H3, pqw, pqb, Z, FLAG, 128, 64);

    // ---- VQ ----
    k_vq<<<Bc * 4, 256, 0, stream>>>(Z, emb, Z, out + R_RECON + 2 + (size_t)b0 * 1024,
                                     FLAG, LOSSP, b0 * 4);

    // ---- decoder ----
    k_conv3x3_v2<false, true, false, true><<<Bc * 32, 128, 0, stream>>>(Z, dw1, db1, D1, FLAG, 64, 128);
    k_conv3x3_v2<true, false, true, false><<<Bc * 8, 128, 0, stream>>>(D1, dr1a, nullptr, T, FLAG, 128, 32);
    k_conv1x1_t4<true, false, false><<<Bc * 32, 256, 0, stream>>>(T, dr1b, nullptr, D1, FLAG, 32, 128);
    k_conv3x3_v2<true, false, true, false><<<Bc * 8, 128, 0, stream>>>(D1, dr2a, nullptr, T, FLAG, 128, 32);
    k_conv1x1_t4<true, false, true><<<Bc * 32, 256, 0, stream>>>(T, dr2b, nullptr, D1, FLAG, 32, 128);
    k_convT_up1<<<Bc * 16, 256, 0, stream>>>(D1, dw2, db2, D2, FLAG);
    k_convT_up2<<<Bc * 8, 256, 0, stream>>>(D2, dw3, db3, out + (size_t)b0 * 49152, FLAG);
  }

  k_loss_final<<<1, 64, 0, stream>>>(LOSSP, out);
}

// Round 16
// 2998.470 us; speedup vs baseline: 5.4843x; 1.3152x over previous
//
#include <hip/hip_runtime.h>
#include <hip/hip_bf16.h>

typedef __hip_bfloat16 bf16;
typedef unsigned short u16;

#define R_RECON 3145728
#define N_IDX   65536

__device__ __forceinline__ float ldg_in(const void* p, int i, int fl) {
  return fl ? ((const float*)p)[i] : __bfloat162float(((const bf16*)p)[i]);
}

__global__ __launch_bounds__(256) void k_detect(const u16* __restrict__ p, int* __restrict__ flag) {
  __shared__ int s;
  if (threadIdx.x == 0) s = 0;
  __syncthreads();
  for (int i = threadIdx.x; i < 4096; i += 256) {
    float f = __uint_as_float(((unsigned)p[i]) << 16);
    if (!(fabsf(f) < 16384.f)) atomicOr(&s, 1);
  }
  __syncthreads();
  if (threadIdx.x == 0) flag[0] = s;
}

// ---------------- enc1: stride-2 4x4 conv from global input (Cin=3) ----------------
template<bool GIN>
__global__ __launch_bounds__(256) void k_conv_s2k4(
    const void* __restrict__ inp, const void* __restrict__ w,
    const void* __restrict__ bias, float* __restrict__ out,
    const int* __restrict__ flag, int in_off,
    int Cin, int Hin, int Cout, int Hout)
{
  __shared__ float sW[1024];
  int fl = flag[0];
  int tid = threadIdx.x;
  int idx = blockIdx.x * 256 + tid;
  int hw = Hout * Hout;
  int co = (idx / hw) % Cout;
  for (int i = tid; i < Cin * 16; i += 256)
    sW[i] = ldg_in(w, co * Cin * 16 + i, fl);
  __syncthreads();
  int ox = idx % Hout; int t = idx / Hout;
  int oy = t % Hout;
  int n = idx / (hw * Cout);
  float acc = ldg_in(bias, co, fl);
  int iy0 = 2 * oy - 1, ix0 = 2 * ox - 1;
  const float* inf = (const float*)inp;
  for (int ci = 0; ci < Cin; ++ci) {
    int base_in = (n * Cin + ci) * Hin * Hin;
    const float* wp = sW + ci * 16;
    #pragma unroll
    for (int ky = 0; ky < 4; ++ky) {
      int iy = iy0 + ky;
      if ((unsigned)iy >= (unsigned)Hin) continue;
      int rb = base_in + iy * Hin;
      #pragma unroll
      for (int kx = 0; kx < 4; ++kx) {
        int ix = ix0 + kx;
        if ((unsigned)ix >= (unsigned)Hin) continue;
        float v = GIN ? ldg_in(inp, in_off + rb + ix, fl) : inf[rb + ix];
        acc = fmaf(v, wp[ky * 4 + kx], acc);
      }
    }
  }
  out[idx] = fmaxf(acc, 0.f);
}

// ---------------- enc2: s2 k4, 64ch 64x64 -> 128ch 32x32; 4 co/thread, LDS-staged ----------------
__global__ __launch_bounds__(256) void k_enc2(
    const float* __restrict__ in, const void* __restrict__ w,
    const void* __restrict__ bias, float* __restrict__ out,
    const int* __restrict__ flag)
{
  const int Cin = 64, Cout = 128;
  __shared__ float sW[4096];                 // 4 co x 64ci x 16
  __shared__ __align__(16) float sIn[4096];  // one 64x64 plane
  int fl = flag[0];
  int bid = blockIdx.x;
  int cp = bid & 31, n = bid >> 5;
  int co0 = cp * 4;
  int tid = threadIdx.x;
  for (int i = tid; i < 4096; i += 256)
    sW[i] = ldg_in(w, co0 * 1024 + i, fl);
  int oy = tid >> 3, ox0 = (tid & 7) << 2;
  float bvA = ldg_in(bias, co0, fl), bvB = ldg_in(bias, co0 + 1, fl);
  float bvC = ldg_in(bias, co0 + 2, fl), bvD = ldg_in(bias, co0 + 3, fl);
  float a0 = bvA, a1 = bvA, a2 = bvA, a3 = bvA;
  float b0 = bvB, b1 = bvB, b2 = bvB, b3 = bvB;
  float c0 = bvC, c1 = bvC, c2 = bvC, c3 = bvC;
  float d0 = bvD, d1 = bvD, d2 = bvD, d3 = bvD;
  int ry0 = 2 * oy - 1;
  int cx0 = 2 * ox0 - 1;
  const float* ip = in + (size_t)n * Cin * 4096;
  for (int ci = 0; ci < Cin; ++ci) {
    __syncthreads();
    {
      const float4* s4 = (const float4*)(ip + ci * 4096);
      float4* d4 = (float4*)sIn;
      d4[tid] = s4[tid]; d4[tid + 256] = s4[tid + 256];
      d4[tid + 512] = s4[tid + 512]; d4[tid + 768] = s4[tid + 768];
    }
    __syncthreads();
    #pragma unroll
    for (int ky = 0; ky < 4; ++ky) {
      int iy = ry0 + ky;
      if ((unsigned)iy < 64u) {
        const float* rp = sIn + iy * 64;
        float x0 = (cx0 >= 0) ? rp[cx0] : 0.f;
        float x1 = rp[cx0 + 1], x2 = rp[cx0 + 2], x3 = rp[cx0 + 3], x4 = rp[cx0 + 4];
        float x5 = rp[cx0 + 5], x6 = rp[cx0 + 6], x7 = rp[cx0 + 7], x8 = rp[cx0 + 8];
        float x9 = (cx0 + 9 < 64) ? rp[cx0 + 9] : 0.f;
        int wb = ci * 16 + ky * 4;
        {
          float wa0 = sW[wb], wa1 = sW[wb + 1], wa2 = sW[wb + 2], wa3 = sW[wb + 3];
          a0 = fmaf(x0, wa0, fmaf(x1, wa1, fmaf(x2, wa2, fmaf(x3, wa3, a0))));
          a1 = fmaf(x2, wa0, fmaf(x3, wa1, fmaf(x4, wa2, fmaf(x5, wa3, a1))));
          a2 = fmaf(x4, wa0, fmaf(x5, wa1, fmaf(x6, wa2, fmaf(x7, wa3, a2))));
          a3 = fmaf(x6, wa0, fmaf(x7, wa1, fmaf(x8, wa2, fmaf(x9, wa3, a3))));
          float wb0 = sW[wb + 1024], wb1 = sW[wb + 1025], wb2 = sW[wb + 1026], wb3 = sW[wb + 1027];
          b0 = fmaf(x0, wb0, fmaf(x1, wb1, fmaf(x2, wb2, fmaf(x3, wb3, b0))));
          b1 = fmaf(x2, wb0, fmaf(x3, wb1, fmaf(x4, wb2, fmaf(x5, wb3, b1))));
          b2 = fmaf(x4, wb0, fmaf(x5, wb1, fmaf(x6, wb2, fmaf(x7, wb3, b2))));
          b3 = fmaf(x6, wb0, fmaf(x7, wb1, fmaf(x8, wb2, fmaf(x9, wb3, b3))));
        }
        {
          float wc0 = sW[wb + 2048], wc1 = sW[wb + 2049], wc2 = sW[wb + 2050], wc3 = sW[wb + 2051];
          c0 = fmaf(x0, wc0, fmaf(x1, wc1, fmaf(x2, wc2, fmaf(x3, wc3, c0))));
          c1 = fmaf(x2, wc0, fmaf(x3, wc1, fmaf(x4, wc2, fmaf(x5, wc3, c1))));
          c2 = fmaf(x4, wc0, fmaf(x5, wc1, fmaf(x6, wc2, fmaf(x7, wc3, c2))));
          c3 = fmaf(x6, wc0, fmaf(x7, wc1, fmaf(x8, wc2, fmaf(x9, wc3, c3))));
          float wd0 = sW[wb + 3072], wd1 = sW[wb + 3073], wd2 = sW[wb + 3074], wd3 = sW[wb + 3075];
          d0 = fmaf(x0, wd0, fmaf(x1, wd1, fmaf(x2, wd2, fmaf(x3, wd3, d0))));
          d1 = fmaf(x2, wd0, fmaf(x3, wd1, fmaf(x4, wd2, fmaf(x5, wd3, d1))));
          d2 = fmaf(x4, wd0, fmaf(x5, wd1, fmaf(x6, wd2, fmaf(x7, wd3, d2))));
          d3 = fmaf(x6, wd0, fmaf(x7, wd1, fmaf(x8, wd2, fmaf(x9, wd3, d3))));
        }
      }
    }
  }
  float* op = out + (size_t)(n * Cout + co0) * 1024 + oy * 32 + ox0;
  op[0] = fmaxf(a0, 0.f); op[1] = fmaxf(a1, 0.f); op[2] = fmaxf(a2, 0.f); op[3] = fmaxf(a3, 0.f);
  op += 1024;
  op[0] = fmaxf(b0, 0.f); op[1] = fmaxf(b1, 0.f); op[2] = fmaxf(b2, 0.f); op[3] = fmaxf(b3, 0.f);
  op += 1024;
  op[0] = fmaxf(c0, 0.f); op[1] = fmaxf(c1, 0.f); op[2] = fmaxf(c2, 0.f); op[3] = fmaxf(c3, 0.f);
  op += 1024;
  op[0] = fmaxf(d0, 0.f); op[1] = fmaxf(d1, 0.f); op[2] = fmaxf(d2, 0.f); op[3] = fmaxf(d3, 0.f);
}

// ---- 3x3 conv s1 p1 @32x32 v3: 256 thr, 4 co/block, 2 co/thread, 4x2 px, LDS-staged input ----
#define C4(P0, P1, P2, P3, W0, W1, W2) \
  P0 = fmaf(x0, W0, fmaf(x1, W1, fmaf(x2, W2, P0))); \
  P1 = fmaf(x1, W0, fmaf(x2, W1, fmaf(x3, W2, P1))); \
  P2 = fmaf(x2, W0, fmaf(x3, W1, fmaf(x4, W2, P2))); \
  P3 = fmaf(x3, W0, fmaf(x4, W1, fmaf(x5, W2, P3)));

#define ROW_AB(T, KY) \
  C4(A##T##0, A##T##1, A##T##2, A##T##3, wa[3*KY], wa[3*KY+1], wa[3*KY+2]) \
  C4(B##T##0, B##T##1, B##T##2, B##T##3, wb[3*KY], wb[3*KY+1], wb[3*KY+2])

#define C33_LOAD(RP) \
  x0 = (ox0 > 0) ? (RP)[ox0 - 1] : 0.f; \
  x1 = (RP)[ox0]; x2 = (RP)[ox0 + 1]; x3 = (RP)[ox0 + 2]; x4 = (RP)[ox0 + 3]; \
  x5 = (ox0 < 28) ? (RP)[ox0 + 4] : 0.f; \
  if (IN_RELU) { \
    x0 = fmaxf(x0, 0.f); x1 = fmaxf(x1, 0.f); x2 = fmaxf(x2, 0.f); \
    x3 = fmaxf(x3, 0.f); x4 = fmaxf(x4, 0.f); x5 = fmaxf(x5, 0.f); \
  }

#define ST_ROW4(PTR, P0, P1, P2, P3) \
  if (OUT_RELU) { (PTR)[0] = fmaxf(P0, 0.f); (PTR)[1] = fmaxf(P1, 0.f); \
                  (PTR)[2] = fmaxf(P2, 0.f); (PTR)[3] = fmaxf(P3, 0.f); } \
  else { (PTR)[0] = P0; (PTR)[1] = P1; (PTR)[2] = P2; (PTR)[3] = P3; }

template<bool IN_RELU, bool TRANS_W, bool OUT_RELU, bool HAS_BIAS>
__global__ __launch_bounds__(256) void k_conv3x3_v3(
    const float* __restrict__ in, const void* __restrict__ w,
    const void* __restrict__ bias, float* __restrict__ out,
    const int* __restrict__ flag, int Cin, int Cout)
{
  const int HW = 1024;
  __shared__ float sW[4608];                 // 4 co x Cin x 9, Cin<=128
  __shared__ __align__(16) float sIn[2048];  // two 32x32 planes
  int fl = flag[0];
  int nq = Cout >> 2;
  int bid = blockIdx.x;
  int qc = bid % nq, n = bid / nq;
  int co0 = qc * 4;
  int tid = threadIdx.x;
  int tot = 4 * Cin * 9;
  for (int i = tid; i < tot; i += 256) {
    int cl = i / (Cin * 9), rem = i % (Cin * 9);
    int ci = rem / 9, k = rem % 9;
    int src = TRANS_W ? ((ci * Cout + co0 + cl) * 9 + (8 - k))
                      : (((co0 + cl) * Cin + ci) * 9 + k);
    sW[i] = ldg_in(w, src, fl);
  }
  int cp = tid >> 7;                   // co-pair sel (uniform per wave)
  int tt = tid & 127;
  int ty = tt >> 3, tx = tt & 7;       // 16 x 8
  int oy0 = ty * 2, ox0 = tx * 4;
  int coA = co0 + cp * 2;
  const float* WA = sW + (cp * 2) * Cin * 9;
  const float* WB = WA + Cin * 9;
  float bvA = HAS_BIAS ? ldg_in(bias, coA, fl) : 0.f;
  float bvB = HAS_BIAS ? ldg_in(bias, coA + 1, fl) : 0.f;
  float A00=bvA,A01=bvA,A02=bvA,A03=bvA, A10=bvA,A11=bvA,A12=bvA,A13=bvA;
  float B00=bvB,B01=bvB,B02=bvB,B03=bvB, B10=bvB,B11=bvB,B12=bvB,B13=bvB;
  const float* ip = in + (size_t)n * Cin * HW;
  for (int cb = 0; cb < Cin; cb += 2) {
    __syncthreads();
    {
      const float4* s4 = (const float4*)(ip + cb * HW);
      float4* d4 = (float4*)sIn;
      d4[tid] = s4[tid];               // plane cb + cb+1 contiguous: 512 float4
      d4[tid + 256] = s4[tid + 256];
    }
    __syncthreads();
    #pragma unroll
    for (int u = 0; u < 2; ++u) {
      int ci = cb + u;
      const float* sP = sIn + u * 1024;
      const float* wa = WA + ci * 9;
      const float* wb = WB + ci * 9;
      float x0, x1, x2, x3, x4, x5;
      if (oy0 > 0) {                   // iy = oy0-1 -> row0 ky0
        C33_LOAD(sP + (oy0 - 1) * 32)
        ROW_AB(0, 0)
      }
      { C33_LOAD(sP + oy0 * 32)        // row0 ky1, row1 ky0
        ROW_AB(0, 1) ROW_AB(1, 0) }
      { C33_LOAD(sP + (oy0 + 1) * 32)  // row0 ky2, row1 ky1
        ROW_AB(0, 2) ROW_AB(1, 1) }
      if (oy0 < 30) {                  // iy = oy0+2 -> row1 ky2
        C33_LOAD(sP + (oy0 + 2) * 32)
        ROW_AB(1, 2)
      }
    }
  }
  float* op = out + (size_t)(n * Cout + coA) * HW + oy0 * 32 + ox0;
  ST_ROW4(op,      A00, A01, A02, A03)
  ST_ROW4(op + 32, A10, A11, A12, A13)
  op += HW;
  ST_ROW4(op,      B00, B01, B02, B03)
  ST_ROW4(op + 32, B10, B11, B12, B13)
}

// ---------------- 1x1 conv @32x32: 4co x 4p register tile ----------------
template<bool ACCUM, bool HAS_BIAS, bool OUT_RELU>
__global__ __launch_bounds__(256) void k_conv1x1_t4(
    const float* __restrict__ in, const void* __restrict__ w,
    const void* __restrict__ bias, float* __restrict__ out,
    const int* __restrict__ flag, int Cin, int Cout)
{
  const int HW = 1024;
  __shared__ float sW[512];
  int fl = flag[0];
  int nq = Cout >> 2;
  int bid = blockIdx.x;
  int qc = bid % nq, n = bid / nq;
  int co0 = qc * 4;
  int tid = threadIdx.x;
  for (int i = tid; i < 4 * Cin; i += 256)
    sW[i] = ldg_in(w, co0 * Cin + i, fl);
  __syncthreads();
  float acc[4][4];
  #pragma unroll
  for (int c = 0; c < 4; ++c) {
    float bv = HAS_BIAS ? ldg_in(bias, co0 + c, fl) : 0.f;
    #pragma unroll
    for (int k = 0; k < 4; ++k) acc[c][k] = bv;
  }
  const float* ip = in + (size_t)n * Cin * HW + tid;
  for (int ci = 0; ci < Cin; ++ci) {
    const float* p = ip + ci * HW;
    float x0 = p[0], x1 = p[256], x2 = p[512], x3 = p[768];
    #pragma unroll
    for (int c = 0; c < 4; ++c) {
      float wv = sW[c * Cin + ci];
      acc[c][0] = fmaf(wv, x0, acc[c][0]);
      acc[c][1] = fmaf(wv, x1, acc[c][1]);
      acc[c][2] = fmaf(wv, x2, acc[c][2]);
      acc[c][3] = fmaf(wv, x3, acc[c][3]);
    }
  }
  #pragma unroll
  for (int c = 0; c < 4; ++c) {
    float* op = out + (size_t)(n * Cout + co0 + c) * HW + tid;
    #pragma unroll
    for (int k = 0; k < 4; ++k) {
      float v = acc[c][k];
      if (ACCUM) v += op[k * 256];
      if (OUT_RELU) v = fmaxf(v, 0.f);
      op[k * 256] = v;
    }
  }
}

// ---- ConvTranspose s2 k4 p1 parity-quad macros ----
#define LOADW16(BASE) \
  w00 = (BASE)[0];  w01 = (BASE)[1];  w02 = (BASE)[2];  w03 = (BASE)[3];  \
  w10 = (BASE)[4];  w11 = (BASE)[5];  w12 = (BASE)[6];  w13 = (BASE)[7];  \
  w20 = (BASE)[8];  w21 = (BASE)[9];  w22 = (BASE)[10]; w23 = (BASE)[11]; \
  w30 = (BASE)[12]; w31 = (BASE)[13]; w32 = (BASE)[14]; w33 = (BASE)[15];

#define CT_J(P00, P01, P10, P11, M0, M1, M2, C0, C1, C2, D0, D1, D2) \
  P00 = fmaf(w11, C1, fmaf(w13, C0, fmaf(w31, M1, fmaf(w33, M0, P00)))); \
  P01 = fmaf(w10, C2, fmaf(w12, C1, fmaf(w30, M2, fmaf(w32, M1, P01)))); \
  P10 = fmaf(w01, D1, fmaf(w03, D0, fmaf(w21, C1, fmaf(w23, C0, P10)))); \
  P11 = fmaf(w00, D2, fmaf(w02, D1, fmaf(w20, C2, fmaf(w22, C1, P11))));

#define DECL16(PX, BV) \
  float PX##A0=BV, PX##A1=BV, PX##A2=BV, PX##A3=BV, \
        PX##B0=BV, PX##B1=BV, PX##B2=BV, PX##B3=BV, \
        PX##C0=BV, PX##C1=BV, PX##C2=BV, PX##C3=BV, \
        PX##D0=BV, PX##D1=BV, PX##D2=BV, PX##D3=BV;

#define CT_CO(PX) \
  CT_J(PX##A0, PX##B0, PX##C0, PX##D0, m0, m1, m2, c0, c1, c2, d0, d1, d2) \
  CT_J(PX##A1, PX##B1, PX##C1, PX##D1, m1, m2, m3, c1, c2, c3, d1, d2, d3) \
  CT_J(PX##A2, PX##B2, PX##C2, PX##D2, m2, m3, m4, c2, c3, c4, d2, d3, d4) \
  CT_J(PX##A3, PX##B3, PX##C3, PX##D3, m3, m4, m5, c3, c4, c5, d3, d4, d5)

#define CT_STORE(PX, PTR, HO) \
  (PTR)[0] = fmaxf(PX##A0, 0.f); (PTR)[1] = fmaxf(PX##B0, 0.f); \
  (PTR)[2] = fmaxf(PX##A1, 0.f); (PTR)[3] = fmaxf(PX##B1, 0.f); \
  (PTR)[4] = fmaxf(PX##A2, 0.f); (PTR)[5] = fmaxf(PX##B2, 0.f); \
  (PTR)[6] = fmaxf(PX##A3, 0.f); (PTR)[7] = fmaxf(PX##B3, 0.f); \
  (PTR)[HO]     = fmaxf(PX##C0, 0.f); (PTR)[HO + 1] = fmaxf(PX##D0, 0.f); \
  (PTR)[HO + 2] = fmaxf(PX##C1, 0.f); (PTR)[HO + 3] = fmaxf(PX##D1, 0.f); \
  (PTR)[HO + 4] = fmaxf(PX##C2, 0.f); (PTR)[HO + 5] = fmaxf(PX##D2, 0.f); \
  (PTR)[HO + 6] = fmaxf(PX##C3, 0.f); (PTR)[HO + 7] = fmaxf(PX##D3, 0.f);

// ---------------- up1: convT s2 k4, 128ch 32x32 -> 64ch 64x64, 4 co/thread ----------------
__global__ __launch_bounds__(256) void k_convT_up1(
    const float* __restrict__ in, const void* __restrict__ w,
    const void* __restrict__ bias, float* __restrict__ out,
    const int* __restrict__ flag)
{
  const int Cin = 128, Cout = 64;
  __shared__ float sW[8192];           // 4 co x 128ci x 16 (32 KB)
  int fl = flag[0];
  int bid = blockIdx.x;
  int cp = bid & 15, n = bid >> 4;
  int co0 = cp * 4;
  int tid = threadIdx.x;
  for (int i = tid; i < 8192; i += 256) {
    int cl = i >> 11, rem = i & 2047;
    int ci = rem >> 4, k = rem & 15;
    sW[i] = ldg_in(w, (ci * Cout + co0 + cl) * 16 + k, fl);
  }
  __syncthreads();
  int qa = tid >> 3;
  int qb0 = (tid & 7) * 4;
  float bv0 = ldg_in(bias, co0, fl), bv1 = ldg_in(bias, co0 + 1, fl);
  float bv2 = ldg_in(bias, co0 + 2, fl), bv3 = ldg_in(bias, co0 + 3, fl);
  DECL16(u, bv0) DECL16(v, bv1) DECL16(y, bv2) DECL16(z, bv3)
  const float* ip = in + (size_t)n * Cin * 1024;
  bool vm = qa >= 1, vd = qa + 1 < 32;
  bool vl = qb0 > 0, vr = qb0 < 28;
  for (int ci = 0; ci < Cin; ++ci) {
    const float* p = ip + ci * 1024;
    const float* rm = p + (qa - 1) * 32;
    const float* rc = p + qa * 32;
    const float* rd = p + (qa + 1) * 32;
    float m0 = (vm && vl) ? rm[qb0 - 1] : 0.f;
    float m1 = vm ? rm[qb0] : 0.f, m2 = vm ? rm[qb0 + 1] : 0.f;
    float m3 = vm ? rm[qb0 + 2] : 0.f, m4 = vm ? rm[qb0 + 3] : 0.f;
    float m5 = (vm && vr) ? rm[qb0 + 4] : 0.f;
    float c0 = vl ? rc[qb0 - 1] : 0.f;
    float c1 = rc[qb0], c2 = rc[qb0 + 1], c3 = rc[qb0 + 2], c4 = rc[qb0 + 3];
    float c5 = vr ? rc[qb0 + 4] : 0.f;
    float d0 = (vd && vl) ? rd[qb0 - 1] : 0.f;
    float d1 = vd ? rd[qb0] : 0.f, d2 = vd ? rd[qb0 + 1] : 0.f;
    float d3 = vd ? rd[qb0 + 2] : 0.f, d4 = vd ? rd[qb0 + 3] : 0.f;
    float d5 = (vd && vr) ? rd[qb0 + 4] : 0.f;
    float w00, w01, w02, w03, w10, w11, w12, w13, w20, w21, w22, w23, w30, w31, w32, w33;
    { LOADW16(sW + ci * 16)        CT_CO(u) }
    { LOADW16(sW + 2048 + ci * 16) CT_CO(v) }
    { LOADW16(sW + 4096 + ci * 16) CT_CO(y) }
    { LOADW16(sW + 6144 + ci * 16) CT_CO(z) }
  }
  float* op = out + ((size_t)(n * Cout + co0) * 64 + 2 * qa) * 64 + 2 * qb0;
  CT_STORE(u, op, 64) op += (size_t)64 * 64;
  CT_STORE(v, op, 64) op += (size_t)64 * 64;
  CT_STORE(y, op, 64) op += (size_t)64 * 64;
  CT_STORE(z, op, 64)
}

// ---------------- up2: convT s2 k4, 64ch 64x64 -> 3ch 128x128, all 3 co/thread ----------------
__global__ __launch_bounds__(256) void k_convT_up2(
    const float* __restrict__ in, const void* __restrict__ w,
    const void* __restrict__ bias, float* __restrict__ out,
    const int* __restrict__ flag)
{
  const int Cin = 64;
  __shared__ float sW[3072];
  int fl = flag[0];
  int bid = blockIdx.x;
  int s = bid & 7, n = bid >> 3;
  int tid = threadIdx.x;
  for (int i = tid; i < 3072; i += 256)
    sW[i] = ldg_in(w, i, fl);
  __syncthreads();
  int qa = s * 8 + (tid >> 5);
  int qb0 = (tid & 31) * 2;
  float bp = ldg_in(bias, 0, fl), bq = ldg_in(bias, 1, fl), br = ldg_in(bias, 2, fl);
  float pA0 = bp, pA1 = bp, pB0 = bp, pB1 = bp, pC0 = bp, pC1 = bp, pD0 = bp, pD1 = bp;
  float qA0 = bq, qA1 = bq, qB0_ = bq, qB1 = bq, qC0 = bq, qC1 = bq, qD0 = bq, qD1 = bq;
  float rA0 = br, rA1 = br, rB0 = br, rB1 = br, rC0 = br, rC1 = br, rD0 = br, rD1 = br;
  const float* ip = in + (size_t)n * Cin * 4096;
  bool vm = qa >= 1, vd = qa + 1 < 64;
  bool vl = qb0 > 0, vr = qb0 < 62;
  for (int ci = 0; ci < Cin; ++ci) {
    const float* p = ip + ci * 4096;
    const float* rm = p + (qa - 1) * 64;
    const float* rc = p + qa * 64;
    const float* rd = p + (qa + 1) * 64;
    float m0 = (vm && vl) ? rm[qb0 - 1] : 0.f;
    float m1 = vm ? rm[qb0] : 0.f, m2 = vm ? rm[qb0 + 1] : 0.f;
    float m3 = (vm && vr) ? rm[qb0 + 2] : 0.f;
    float c0 = vl ? rc[qb0 - 1] : 0.f;
    float c1 = rc[qb0], c2 = rc[qb0 + 1];
    float c3 = vr ? rc[qb0 + 2] : 0.f;
    float d0 = (vd && vl) ? rd[qb0 - 1] : 0.f;
    float d1 = vd ? rd[qb0] : 0.f, d2 = vd ? rd[qb0 + 1] : 0.f;
    float d3 = (vd && vr) ? rd[qb0 + 2] : 0.f;
    float w00, w01, w02, w03, w10, w11, w12, w13, w20, w21, w22, w23, w30, w31, w32, w33;
    {
      LOADW16(sW + ci * 48)
      CT_J(pA0, pB0, pC0, pD0, m0, m1, m2, c0, c1, c2, d0, d1, d2)
      CT_J(pA1, pB1, pC1, pD1, m1, m2, m3, c1, c2, c3, d1, d2, d3)
    }
    {
      LOADW16(sW + ci * 48 + 16)
      CT_J(qA0, qB0_, qC0, qD0, m0, m1, m2, c0, c1, c2, d0, d1, d2)
      CT_J(qA1, qB1, qC1, qD1, m1, m2, m3, c1, c2, c3, d1, d2, d3)
    }
    {
      LOADW16(sW + ci * 48 + 32)
      CT_J(rA0, rB0, rC0, rD0, m0, m1, m2, c0, c1, c2, d0, d1, d2)
      CT_J(rA1, rB1, rC1, rD1, m1, m2, m3, c1, c2, c3, d1, d2, d3)
    }
  }
  float* op = out + ((size_t)(n * 3 + 0) * 128 + 2 * qa) * 128 + 2 * qb0;
  op[0] = pA0; op[1] = pB0; op[2] = pA1; op[3] = pB1;
  op[128] = pC0; op[129] = pD0; op[130] = pC1; op[131] = pD1;
  op += (size_t)128 * 128;
  op[0] = qA0; op[1] = qB0_; op[2] = qA1; op[3] = qB1;
  op[128] = qC0; op[129] = qD0; op[130] = qC1; op[131] = qD1;
  op += (size_t)128 * 128;
  op[0] = rA0; op[1] = rB0; op[2] = rA1; op[3] = rB1;
  op[128] = rC0; op[129] = rD0; op[130] = rC1; op[131] = rD1;
}

// ---------------- VQ: argmin (first-min), zq in-place, idx (fp32) to d_out ----------------
__global__ __launch_bounds__(256) void k_vq(
    const float* __restrict__ z, const void* __restrict__ emb,
    float* __restrict__ zq, float* __restrict__ idx_out,
    const int* __restrict__ flag, float* __restrict__ lossp, int lossbase)
{
  __shared__ __align__(16) float sE[8192];
  __shared__ float sEE[128];
  __shared__ float wsum[4];
  int fl = flag[0];
  int tid = threadIdx.x;
  int n = blockIdx.x * 256 + tid;
  int nb = n >> 10, p = n & 1023;
  const float* zp = z + nb * 65536 + p;
  float zv[64];
  float zz = 0.f;
  #pragma unroll
  for (int d = 0; d < 64; ++d) { zv[d] = zp[d * 1024]; zz = fmaf(zv[d], zv[d], zz); }
  float best = 3.4e38f; int bidx = 0;
  for (int kb = 0; kb < 8; ++kb) {
    __syncthreads();
    for (int i = tid; i < 8192; i += 256) sE[i] = ldg_in(emb, kb * 8192 + i, fl);
    __syncthreads();
    if (tid < 128) {
      float s = 0.f;
      #pragma unroll
      for (int d = 0; d < 64; ++d) s = fmaf(sE[tid * 64 + d], sE[tid * 64 + d], s);
      sEE[tid] = s;
    }
    __syncthreads();
    for (int k = 0; k < 128; ++k) {
      const float4* ep4 = (const float4*)(sE + k * 64);
      float dot = 0.f;
      #pragma unroll
      for (int i = 0; i < 16; ++i) {
        float4 v = ep4[i];             // wave-uniform k: LDS broadcast, conflict-free
        dot = fmaf(zv[4*i], v.x, dot);
        dot = fmaf(zv[4*i + 1], v.y, dot);
        dot = fmaf(zv[4*i + 2], v.z, dot);
        dot = fmaf(zv[4*i + 3], v.w, dot);
      }
      float dist = zz + sEE[k] - 2.f * dot;
      if (dist < best) { best = dist; bidx = kb * 128 + k; }  // strict <: first min wins
    }
  }
  idx_out[n] = (float)bidx;
  float ls = 0.f;
  float* qp = zq + nb * 65536 + p;
  #pragma unroll
  for (int d = 0; d < 64; ++d) {
    float e = ldg_in(emb, bidx * 64 + d, fl);
    qp[d * 1024] = e;
    float df = e - zv[d];
    ls = fmaf(df, df, ls);
  }
  #pragma unroll
  for (int off = 32; off > 0; off >>= 1) ls += __shfl_down(ls, off);
  if ((tid & 63) == 0) wsum[tid >> 6] = ls;
  __syncthreads();
  if (tid == 0) lossp[lossbase + blockIdx.x] = wsum[0] + wsum[1] + wsum[2] + wsum[3];
}

__global__ void k_loss_final(const float* __restrict__ lossp, float* __restrict__ out) {
  if (threadIdx.x == 0 && blockIdx.x == 0) {
    float s = 0.f;
    for (int i = 0; i < 256; ++i) s += lossp[i];
    float L = s * (1.f / 4194304.f);
    out[R_RECON + 0] = L;
    out[R_RECON + 1] = L;
  }
}

extern "C" void kernel_launch(void* const* d_in, const int* in_sizes, int n_in,
                              void* d_out, int out_size, void* d_ws, size_t ws_size,
                              hipStream_t stream)
{
  float* out = (float*)d_out;          // fp32 output (established R8-R10)

  float* F = (float*)d_ws;
  float* LOSSP = F;
  int* FLAG = (int*)(F + 256);
  float* A = F + 272;

  int Bc = 64;
  while (Bc > 1 && 4ull * (272ull + (size_t)Bc * 393216ull) > ws_size) Bc >>= 1;
  float* H1 = A;
  float* H2 = A + (size_t)Bc * 262144;
  float* H3 = A;
  float* T  = A + (size_t)Bc * 131072;
  float* Z  = A + (size_t)Bc * 163840;
  float* D1 = H2;
  float* D2 = A;

  const void* patch = d_in[0];
  const void* ew1 = d_in[1];  const void* eb1 = d_in[2];
  const void* ew2 = d_in[3];  const void* eb2 = d_in[4];
  const void* ew3 = d_in[5];  const void* eb3 = d_in[6];
  const void* er1a = d_in[7]; const void* er1b = d_in[8];
  const void* er2a = d_in[9]; const void* er2b = d_in[10];
  const void* pqw = d_in[11]; const void* pqb = d_in[12];
  const void* emb = d_in[13];
  const void* dw1 = d_in[14]; const void* db1 = d_in[15];
  const void* dr1a = d_in[16]; const void* dr1b = d_in[17];
  const void* dr2a = d_in[18]; const void* dr2b = d_in[19];
  const void* dw2 = d_in[20]; const void* db2 = d_in[21];
  const void* dw3 = d_in[22]; const void* db3 = d_in[23];

  k_detect<<<1, 256, 0, stream>>>((const u16*)patch, FLAG);

  int NC = 64 / Bc;
  for (int c = 0; c < NC; ++c) {
    int b0 = c * Bc;

    // ---- encoder ----
    k_conv_s2k4<true><<<Bc * 1024, 256, 0, stream>>>(patch, ew1, eb1, H1, FLAG,
                                                     b0 * 49152, 3, 128, 64, 64);
    k_enc2<<<Bc * 32, 256, 0, stream>>>(H1, ew2, eb2, H2, FLAG);
    k_conv3x3_v3<false, false, false, true><<<Bc * 32, 256, 0, stream>>>(H2, ew3, eb3, H3, FLAG, 128, 128);
    k_conv3x3_v3<true, false, true, false><<<Bc * 8, 256, 0, stream>>>(H3, er1a, nullptr, T, FLAG, 128, 32);
    k_conv1x1_t4<true, false, false><<<Bc * 32, 256, 0, stream>>>(T, er1b, nullptr, H3, FLAG, 32, 128);
    k_conv3x3_v3<true, false, true, false><<<Bc * 8, 256, 0, stream>>>(H3, er2a, nullptr, T, FLAG, 128, 32);
    k_conv1x1_t4<true, false, true><<<Bc * 32, 256, 0, stream>>>(T, er2b, nullptr, H3, FLAG, 32, 128);
    k_conv1x1_t4<false, true, false><<<Bc * 16, 256, 0, stream>>>(H3, pqw, pqb, Z, FLAG, 128, 64);

    // ---- VQ ----
    k_vq<<<Bc * 4, 256, 0, stream>>>(Z, emb, Z, out + R_RECON + 2 + (size_t)b0 * 1024,
                                     FLAG, LOSSP, b0 * 4);

    // ---- decoder ----
    k_conv3x3_v3<false, true, false, true><<<Bc * 32, 256, 0, stream>>>(Z, dw1, db1, D1, FLAG, 64, 128);
    k_conv3x3_v3<true, false, true, false><<<Bc * 8, 256, 0, stream>>>(D1, dr1a, nullptr, T, FLAG, 128, 32);
    k_conv1x1_t4<true, false, false><<<Bc * 32, 256, 0, stream>>>(T, dr1b, nullptr, D1, FLAG, 32, 128);
    k_conv3x3_v3<true, false, true, false><<<Bc * 8, 256, 0, stream>>>(D1, dr2a, nullptr, T, FLAG, 128, 32);
    k_conv1x1_t4<true, false, true><<<Bc * 32, 256, 0, stream>>>(T, dr2b, nullptr, D1, FLAG, 32, 128);
    k_convT_up1<<<Bc * 16, 256, 0, stream>>>(D1, dw2, db2, D2, FLAG);
    k_convT_up2<<<Bc * 8, 256, 0, stream>>>(D2, dw3, db3, out + (size_t)b0 * 49152, FLAG);
  }

  k_loss_final<<<1, 64, 0, stream>>>(LOSSP, out);
}

// Round 17
// 2827.368 us; speedup vs baseline: 5.8162x; 1.0605x over previous
//
#include <hip/hip_runtime.h>
#include <hip/hip_bf16.h>

typedef __hip_bfloat16 bf16;
typedef unsigned short u16;

#define R_RECON 3145728
#define N_IDX   65536

__device__ __forceinline__ float ldg_in(const void* p, int i, int fl) {
  return fl ? ((const float*)p)[i] : __bfloat162float(((const bf16*)p)[i]);
}

__global__ __launch_bounds__(256) void k_detect(const u16* __restrict__ p, int* __restrict__ flag) {
  __shared__ int s;
  if (threadIdx.x == 0) s = 0;
  __syncthreads();
  for (int i = threadIdx.x; i < 4096; i += 256) {
    float f = __uint_as_float(((unsigned)p[i]) << 16);
    if (!(fabsf(f) < 16384.f)) atomicOr(&s, 1);
  }
  __syncthreads();
  if (threadIdx.x == 0) flag[0] = s;
}

// ---------------- enc1: stride-2 4x4 conv from global input (Cin=3) ----------------
template<bool GIN>
__global__ __launch_bounds__(256) void k_conv_s2k4(
    const void* __restrict__ inp, const void* __restrict__ w,
    const void* __restrict__ bias, float* __restrict__ out,
    const int* __restrict__ flag, int in_off,
    int Cin, int Hin, int Cout, int Hout)
{
  __shared__ float sW[1024];
  int fl = flag[0];
  int tid = threadIdx.x;
  int idx = blockIdx.x * 256 + tid;
  int hw = Hout * Hout;
  int co = (idx / hw) % Cout;
  for (int i = tid; i < Cin * 16; i += 256)
    sW[i] = ldg_in(w, co * Cin * 16 + i, fl);
  __syncthreads();
  int ox = idx % Hout; int t = idx / Hout;
  int oy = t % Hout;
  int n = idx / (hw * Cout);
  float acc = ldg_in(bias, co, fl);
  int iy0 = 2 * oy - 1, ix0 = 2 * ox - 1;
  const float* inf = (const float*)inp;
  for (int ci = 0; ci < Cin; ++ci) {
    int base_in = (n * Cin + ci) * Hin * Hin;
    const float* wp = sW + ci * 16;
    #pragma unroll
    for (int ky = 0; ky < 4; ++ky) {
      int iy = iy0 + ky;
      if ((unsigned)iy >= (unsigned)Hin) continue;
      int rb = base_in + iy * Hin;
      #pragma unroll
      for (int kx = 0; kx < 4; ++kx) {
        int ix = ix0 + kx;
        if ((unsigned)ix >= (unsigned)Hin) continue;
        float v = GIN ? ldg_in(inp, in_off + rb + ix, fl) : inf[rb + ix];
        acc = fmaf(v, wp[ky * 4 + kx], acc);
      }
    }
  }
  out[idx] = fmaxf(acc, 0.f);
}

// ---------------- enc2: s2 k4, 64ch 64x64 -> 128ch 32x32; 4 co/thread, padded LDS ----------------
__global__ __launch_bounds__(256) void k_enc2(
    const float* __restrict__ in, const void* __restrict__ w,
    const void* __restrict__ bias, float* __restrict__ out,
    const int* __restrict__ flag)
{
  const int Cin = 64, Cout = 128;
  const int P = 65;                          // padded row stride (bank-conflict fix)
  __shared__ float sW[4096];                 // 4 co x 64ci x 16
  __shared__ float sIn[64 * P];              // one 64x64 plane, padded
  int fl = flag[0];
  int bid = blockIdx.x;
  int cp = bid & 31, n = bid >> 5;
  int co0 = cp * 4;
  int tid = threadIdx.x;
  for (int i = tid; i < 4096; i += 256)
    sW[i] = ldg_in(w, co0 * 1024 + i, fl);
  int oy = tid >> 3, ox0 = (tid & 7) << 2;
  float bvA = ldg_in(bias, co0, fl), bvB = ldg_in(bias, co0 + 1, fl);
  float bvC = ldg_in(bias, co0 + 2, fl), bvD = ldg_in(bias, co0 + 3, fl);
  float a0 = bvA, a1 = bvA, a2 = bvA, a3 = bvA;
  float b0 = bvB, b1 = bvB, b2 = bvB, b3 = bvB;
  float c0 = bvC, c1 = bvC, c2 = bvC, c3 = bvC;
  float d0 = bvD, d1 = bvD, d2 = bvD, d3 = bvD;
  int ry0 = 2 * oy - 1;
  int cx0 = 2 * ox0 - 1;
  const float* ip = in + (size_t)n * Cin * 4096;
  for (int ci = 0; ci < Cin; ++ci) {
    __syncthreads();
    {
      const float* g = ip + ci * 4096;
      #pragma unroll
      for (int j = 0; j < 16; ++j) {
        int i = tid + j * 256;
        sIn[(i >> 6) * P + (i & 63)] = g[i];
      }
    }
    __syncthreads();
    #pragma unroll
    for (int ky = 0; ky < 4; ++ky) {
      int iy = ry0 + ky;
      if ((unsigned)iy < 64u) {
        const float* rp = sIn + iy * P;
        float x0 = (cx0 >= 0) ? rp[cx0] : 0.f;
        float x1 = rp[cx0 + 1], x2 = rp[cx0 + 2], x3 = rp[cx0 + 3], x4 = rp[cx0 + 4];
        float x5 = rp[cx0 + 5], x6 = rp[cx0 + 6], x7 = rp[cx0 + 7], x8 = rp[cx0 + 8];
        float x9 = (cx0 + 9 < 64) ? rp[cx0 + 9] : 0.f;
        int wb = ci * 16 + ky * 4;
        {
          float wa0 = sW[wb], wa1 = sW[wb + 1], wa2 = sW[wb + 2], wa3 = sW[wb + 3];
          a0 = fmaf(x0, wa0, fmaf(x1, wa1, fmaf(x2, wa2, fmaf(x3, wa3, a0))));
          a1 = fmaf(x2, wa0, fmaf(x3, wa1, fmaf(x4, wa2, fmaf(x5, wa3, a1))));
          a2 = fmaf(x4, wa0, fmaf(x5, wa1, fmaf(x6, wa2, fmaf(x7, wa3, a2))));
          a3 = fmaf(x6, wa0, fmaf(x7, wa1, fmaf(x8, wa2, fmaf(x9, wa3, a3))));
          float wb0 = sW[wb + 1024], wb1 = sW[wb + 1025], wb2 = sW[wb + 1026], wb3 = sW[wb + 1027];
          b0 = fmaf(x0, wb0, fmaf(x1, wb1, fmaf(x2, wb2, fmaf(x3, wb3, b0))));
          b1 = fmaf(x2, wb0, fmaf(x3, wb1, fmaf(x4, wb2, fmaf(x5, wb3, b1))));
          b2 = fmaf(x4, wb0, fmaf(x5, wb1, fmaf(x6, wb2, fmaf(x7, wb3, b2))));
          b3 = fmaf(x6, wb0, fmaf(x7, wb1, fmaf(x8, wb2, fmaf(x9, wb3, b3))));
        }
        {
          float wc0 = sW[wb + 2048], wc1 = sW[wb + 2049], wc2 = sW[wb + 2050], wc3 = sW[wb + 2051];
          c0 = fmaf(x0, wc0, fmaf(x1, wc1, fmaf(x2, wc2, fmaf(x3, wc3, c0))));
          c1 = fmaf(x2, wc0, fmaf(x3, wc1, fmaf(x4, wc2, fmaf(x5, wc3, c1))));
          c2 = fmaf(x4, wc0, fmaf(x5, wc1, fmaf(x6, wc2, fmaf(x7, wc3, c2))));
          c3 = fmaf(x6, wc0, fmaf(x7, wc1, fmaf(x8, wc2, fmaf(x9, wc3, c3))));
          float wd0 = sW[wb + 3072], wd1 = sW[wb + 3073], wd2 = sW[wb + 3074], wd3 = sW[wb + 3075];
          d0 = fmaf(x0, wd0, fmaf(x1, wd1, fmaf(x2, wd2, fmaf(x3, wd3, d0))));
          d1 = fmaf(x2, wd0, fmaf(x3, wd1, fmaf(x4, wd2, fmaf(x5, wd3, d1))));
          d2 = fmaf(x4, wd0, fmaf(x5, wd1, fmaf(x6, wd2, fmaf(x7, wd3, d2))));
          d3 = fmaf(x6, wd0, fmaf(x7, wd1, fmaf(x8, wd2, fmaf(x9, wd3, d3))));
        }
      }
    }
  }
  float* op = out + (size_t)(n * Cout + co0) * 1024 + oy * 32 + ox0;
  op[0] = fmaxf(a0, 0.f); op[1] = fmaxf(a1, 0.f); op[2] = fmaxf(a2, 0.f); op[3] = fmaxf(a3, 0.f);
  op += 1024;
  op[0] = fmaxf(b0, 0.f); op[1] = fmaxf(b1, 0.f); op[2] = fmaxf(b2, 0.f); op[3] = fmaxf(b3, 0.f);
  op += 1024;
  op[0] = fmaxf(c0, 0.f); op[1] = fmaxf(c1, 0.f); op[2] = fmaxf(c2, 0.f); op[3] = fmaxf(c3, 0.f);
  op += 1024;
  op[0] = fmaxf(d0, 0.f); op[1] = fmaxf(d1, 0.f); op[2] = fmaxf(d2, 0.f); op[3] = fmaxf(d3, 0.f);
}

// ---- 3x3 conv s1 p1 @32x32 v3: 256 thr, 4 co/block, 2 co/thread, 4x2 px, padded LDS ----
#define C4(P0, P1, P2, P3, W0, W1, W2) \
  P0 = fmaf(x0, W0, fmaf(x1, W1, fmaf(x2, W2, P0))); \
  P1 = fmaf(x1, W0, fmaf(x2, W1, fmaf(x3, W2, P1))); \
  P2 = fmaf(x2, W0, fmaf(x3, W1, fmaf(x4, W2, P2))); \
  P3 = fmaf(x3, W0, fmaf(x4, W1, fmaf(x5, W2, P3)));

#define ROW_AB(T, KY) \
  C4(A##T##0, A##T##1, A##T##2, A##T##3, wa[3*KY], wa[3*KY+1], wa[3*KY+2]) \
  C4(B##T##0, B##T##1, B##T##2, B##T##3, wb[3*KY], wb[3*KY+1], wb[3*KY+2])

#define C33_LOAD(RP) \
  x0 = (ox0 > 0) ? (RP)[ox0 - 1] : 0.f; \
  x1 = (RP)[ox0]; x2 = (RP)[ox0 + 1]; x3 = (RP)[ox0 + 2]; x4 = (RP)[ox0 + 3]; \
  x5 = (ox0 < 28) ? (RP)[ox0 + 4] : 0.f; \
  if (IN_RELU) { \
    x0 = fmaxf(x0, 0.f); x1 = fmaxf(x1, 0.f); x2 = fmaxf(x2, 0.f); \
    x3 = fmaxf(x3, 0.f); x4 = fmaxf(x4, 0.f); x5 = fmaxf(x5, 0.f); \
  }

#define ST_ROW4(PTR, P0, P1, P2, P3) \
  if (OUT_RELU) { (PTR)[0] = fmaxf(P0, 0.f); (PTR)[1] = fmaxf(P1, 0.f); \
                  (PTR)[2] = fmaxf(P2, 0.f); (PTR)[3] = fmaxf(P3, 0.f); } \
  else { (PTR)[0] = P0; (PTR)[1] = P1; (PTR)[2] = P2; (PTR)[3] = P3; }

template<bool IN_RELU, bool TRANS_W, bool OUT_RELU, bool HAS_BIAS>
__global__ __launch_bounds__(256) void k_conv3x3_v3(
    const float* __restrict__ in, const void* __restrict__ w,
    const void* __restrict__ bias, float* __restrict__ out,
    const int* __restrict__ flag, int Cin, int Cout)
{
  const int HW = 1024;
  const int PP = 33;                   // padded row stride
  const int PLANE = 32 * PP;           // 1056
  __shared__ float sW[4608];           // 4 co x Cin x 9, Cin<=128
  __shared__ float sIn[2 * 1056];      // two padded 32x32 planes
  int fl = flag[0];
  int nq = Cout >> 2;
  int bid = blockIdx.x;
  int qc = bid % nq, n = bid / nq;
  int co0 = qc * 4;
  int tid = threadIdx.x;
  int tot = 4 * Cin * 9;
  for (int i = tid; i < tot; i += 256) {
    int cl = i / (Cin * 9), rem = i % (Cin * 9);
    int ci = rem / 9, k = rem % 9;
    int src = TRANS_W ? ((ci * Cout + co0 + cl) * 9 + (8 - k))
                      : (((co0 + cl) * Cin + ci) * 9 + k);
    sW[i] = ldg_in(w, src, fl);
  }
  int cp = tid >> 7;                   // co-pair sel (uniform per wave)
  int tt = tid & 127;
  int ty = tt >> 3, tx = tt & 7;       // 16 x 8
  int oy0 = ty * 2, ox0 = tx * 4;
  int coA = co0 + cp * 2;
  const float* WA = sW + (cp * 2) * Cin * 9;
  const float* WB = WA + Cin * 9;
  float bvA = HAS_BIAS ? ldg_in(bias, coA, fl) : 0.f;
  float bvB = HAS_BIAS ? ldg_in(bias, coA + 1, fl) : 0.f;
  float A00=bvA,A01=bvA,A02=bvA,A03=bvA, A10=bvA,A11=bvA,A12=bvA,A13=bvA;
  float B00=bvB,B01=bvB,B02=bvB,B03=bvB, B10=bvB,B11=bvB,B12=bvB,B13=bvB;
  const float* ip = in + (size_t)n * Cin * HW;
  for (int cb = 0; cb < Cin; cb += 2) {
    __syncthreads();
    {
      const float* g = ip + cb * HW;
      #pragma unroll
      for (int j = 0; j < 8; ++j) {
        int i = tid + j * 256;         // 0..2047 over 2 planes
        int pl = i >> 10, rem = i & 1023;
        sIn[pl * PLANE + (rem >> 5) * PP + (rem & 31)] = g[i];
      }
    }
    __syncthreads();
    #pragma unroll
    for (int u = 0; u < 2; ++u) {
      int ci = cb + u;
      const float* sP = sIn + u * PLANE;
      const float* wa = WA + ci * 9;
      const float* wb = WB + ci * 9;
      float x0, x1, x2, x3, x4, x5;
      if (oy0 > 0) {                   // iy = oy0-1 -> row0 ky0
        C33_LOAD(sP + (oy0 - 1) * PP)
        ROW_AB(0, 0)
      }
      { C33_LOAD(sP + oy0 * PP)        // row0 ky1, row1 ky0
        ROW_AB(0, 1) ROW_AB(1, 0) }
      { C33_LOAD(sP + (oy0 + 1) * PP)  // row0 ky2, row1 ky1
        ROW_AB(0, 2) ROW_AB(1, 1) }
      if (oy0 < 30) {                  // iy = oy0+2 -> row1 ky2
        C33_LOAD(sP + (oy0 + 2) * PP)
        ROW_AB(1, 2)
      }
    }
  }
  float* op = out + (size_t)(n * Cout + coA) * HW + oy0 * 32 + ox0;
  ST_ROW4(op,      A00, A01, A02, A03)
  ST_ROW4(op + 32, A10, A11, A12, A13)
  op += HW;
  ST_ROW4(op,      B00, B01, B02, B03)
  ST_ROW4(op + 32, B10, B11, B12, B13)
}

// ---------------- 1x1 conv @32x32: 4co x 4p register tile ----------------
template<bool ACCUM, bool HAS_BIAS, bool OUT_RELU>
__global__ __launch_bounds__(256) void k_conv1x1_t4(
    const float* __restrict__ in, const void* __restrict__ w,
    const void* __restrict__ bias, float* __restrict__ out,
    const int* __restrict__ flag, int Cin, int Cout)
{
  const int HW = 1024;
  __shared__ float sW[512];
  int fl = flag[0];
  int nq = Cout >> 2;
  int bid = blockIdx.x;
  int qc = bid % nq, n = bid / nq;
  int co0 = qc * 4;
  int tid = threadIdx.x;
  for (int i = tid; i < 4 * Cin; i += 256)
    sW[i] = ldg_in(w, co0 * Cin + i, fl);
  __syncthreads();
  float acc[4][4];
  #pragma unroll
  for (int c = 0; c < 4; ++c) {
    float bv = HAS_BIAS ? ldg_in(bias, co0 + c, fl) : 0.f;
    #pragma unroll
    for (int k = 0; k < 4; ++k) acc[c][k] = bv;
  }
  const float* ip = in + (size_t)n * Cin * HW + tid;
  for (int ci = 0; ci < Cin; ++ci) {
    const float* p = ip + ci * HW;
    float x0 = p[0], x1 = p[256], x2 = p[512], x3 = p[768];
    #pragma unroll
    for (int c = 0; c < 4; ++c) {
      float wv = sW[c * Cin + ci];
      acc[c][0] = fmaf(wv, x0, acc[c][0]);
      acc[c][1] = fmaf(wv, x1, acc[c][1]);
      acc[c][2] = fmaf(wv, x2, acc[c][2]);
      acc[c][3] = fmaf(wv, x3, acc[c][3]);
    }
  }
  #pragma unroll
  for (int c = 0; c < 4; ++c) {
    float* op = out + (size_t)(n * Cout + co0 + c) * HW + tid;
    #pragma unroll
    for (int k = 0; k < 4; ++k) {
      float v = acc[c][k];
      if (ACCUM) v += op[k * 256];
      if (OUT_RELU) v = fmaxf(v, 0.f);
      op[k * 256] = v;
    }
  }
}

// ---- ConvTranspose s2 k4 p1 parity-quad macros ----
#define LOADW16(BASE) \
  w00 = (BASE)[0];  w01 = (BASE)[1];  w02 = (BASE)[2];  w03 = (BASE)[3];  \
  w10 = (BASE)[4];  w11 = (BASE)[5];  w12 = (BASE)[6];  w13 = (BASE)[7];  \
  w20 = (BASE)[8];  w21 = (BASE)[9];  w22 = (BASE)[10]; w23 = (BASE)[11]; \
  w30 = (BASE)[12]; w31 = (BASE)[13]; w32 = (BASE)[14]; w33 = (BASE)[15];

#define CT_J(P00, P01, P10, P11, M0, M1, M2, C0, C1, C2, D0, D1, D2) \
  P00 = fmaf(w11, C1, fmaf(w13, C0, fmaf(w31, M1, fmaf(w33, M0, P00)))); \
  P01 = fmaf(w10, C2, fmaf(w12, C1, fmaf(w30, M2, fmaf(w32, M1, P01)))); \
  P10 = fmaf(w01, D1, fmaf(w03, D0, fmaf(w21, C1, fmaf(w23, C0, P10)))); \
  P11 = fmaf(w00, D2, fmaf(w02, D1, fmaf(w20, C2, fmaf(w22, C1, P11))));

#define DECL16(PX, BV) \
  float PX##A0=BV, PX##A1=BV, PX##A2=BV, PX##A3=BV, \
        PX##B0=BV, PX##B1=BV, PX##B2=BV, PX##B3=BV, \
        PX##C0=BV, PX##C1=BV, PX##C2=BV, PX##C3=BV, \
        PX##D0=BV, PX##D1=BV, PX##D2=BV, PX##D3=BV;

#define CT_CO(PX) \
  CT_J(PX##A0, PX##B0, PX##C0, PX##D0, m0, m1, m2, c0, c1, c2, d0, d1, d2) \
  CT_J(PX##A1, PX##B1, PX##C1, PX##D1, m1, m2, m3, c1, c2, c3, d1, d2, d3) \
  CT_J(PX##A2, PX##B2, PX##C2, PX##D2, m2, m3, m4, c2, c3, c4, d2, d3, d4) \
  CT_J(PX##A3, PX##B3, PX##C3, PX##D3, m3, m4, m5, c3, c4, c5, d3, d4, d5)

#define CT_STORE(PX, PTR, HO) \
  (PTR)[0] = fmaxf(PX##A0, 0.f); (PTR)[1] = fmaxf(PX##B0, 0.f); \
  (PTR)[2] = fmaxf(PX##A1, 0.f); (PTR)[3] = fmaxf(PX##B1, 0.f); \
  (PTR)[4] = fmaxf(PX##A2, 0.f); (PTR)[5] = fmaxf(PX##B2, 0.f); \
  (PTR)[6] = fmaxf(PX##A3, 0.f); (PTR)[7] = fmaxf(PX##B3, 0.f); \
  (PTR)[HO]     = fmaxf(PX##C0, 0.f); (PTR)[HO + 1] = fmaxf(PX##D0, 0.f); \
  (PTR)[HO + 2] = fmaxf(PX##C1, 0.f); (PTR)[HO + 3] = fmaxf(PX##D1, 0.f); \
  (PTR)[HO + 4] = fmaxf(PX##C2, 0.f); (PTR)[HO + 5] = fmaxf(PX##D2, 0.f); \
  (PTR)[HO + 6] = fmaxf(PX##C3, 0.f); (PTR)[HO + 7] = fmaxf(PX##D3, 0.f);

// ---------------- up1: convT s2 k4, 128ch 32x32 -> 64ch 64x64, 4 co/thread ----------------
__global__ __launch_bounds__(256) void k_convT_up1(
    const float* __restrict__ in, const void* __restrict__ w,
    const void* __restrict__ bias, float* __restrict__ out,
    const int* __restrict__ flag)
{
  const int Cin = 128, Cout = 64;
  __shared__ float sW[8192];           // 4 co x 128ci x 16 (32 KB)
  int fl = flag[0];
  int bid = blockIdx.x;
  int cp = bid & 15, n = bid >> 4;
  int co0 = cp * 4;
  int tid = threadIdx.x;
  for (int i = tid; i < 8192; i += 256) {
    int cl = i >> 11, rem = i & 2047;
    int ci = rem >> 4, k = rem & 15;
    sW[i] = ldg_in(w, (ci * Cout + co0 + cl) * 16 + k, fl);
  }
  __syncthreads();
  int qa = tid >> 3;
  int qb0 = (tid & 7) * 4;
  float bv0 = ldg_in(bias, co0, fl), bv1 = ldg_in(bias, co0 + 1, fl);
  float bv2 = ldg_in(bias, co0 + 2, fl), bv3 = ldg_in(bias, co0 + 3, fl);
  DECL16(u, bv0) DECL16(v, bv1) DECL16(y, bv2) DECL16(z, bv3)
  const float* ip = in + (size_t)n * Cin * 1024;
  bool vm = qa >= 1, vd = qa + 1 < 32;
  bool vl = qb0 > 0, vr = qb0 < 28;
  for (int ci = 0; ci < Cin; ++ci) {
    const float* p = ip + ci * 1024;
    const float* rm = p + (qa - 1) * 32;
    const float* rc = p + qa * 32;
    const float* rd = p + (qa + 1) * 32;
    float m0 = (vm && vl) ? rm[qb0 - 1] : 0.f;
    float m1 = vm ? rm[qb0] : 0.f, m2 = vm ? rm[qb0 + 1] : 0.f;
    float m3 = vm ? rm[qb0 + 2] : 0.f, m4 = vm ? rm[qb0 + 3] : 0.f;
    float m5 = (vm && vr) ? rm[qb0 + 4] : 0.f;
    float c0 = vl ? rc[qb0 - 1] : 0.f;
    float c1 = rc[qb0], c2 = rc[qb0 + 1], c3 = rc[qb0 + 2], c4 = rc[qb0 + 3];
    float c5 = vr ? rc[qb0 + 4] : 0.f;
    float d0 = (vd && vl) ? rd[qb0 - 1] : 0.f;
    float d1 = vd ? rd[qb0] : 0.f, d2 = vd ? rd[qb0 + 1] : 0.f;
    float d3 = vd ? rd[qb0 + 2] : 0.f, d4 = vd ? rd[qb0 + 3] : 0.f;
    float d5 = (vd && vr) ? rd[qb0 + 4] : 0.f;
    float w00, w01, w02, w03, w10, w11, w12, w13, w20, w21, w22, w23, w30, w31, w32, w33;
    { LOADW16(sW + ci * 16)        CT_CO(u) }
    { LOADW16(sW + 2048 + ci * 16) CT_CO(v) }
    { LOADW16(sW + 4096 + ci * 16) CT_CO(y) }
    { LOADW16(sW + 6144 + ci * 16) CT_CO(z) }
  }
  float* op = out + ((size_t)(n * Cout + co0) * 64 + 2 * qa) * 64 + 2 * qb0;
  CT_STORE(u, op, 64) op += (size_t)64 * 64;
  CT_STORE(v, op, 64) op += (size_t)64 * 64;
  CT_STORE(y, op, 64) op += (size_t)64 * 64;
  CT_STORE(z, op, 64)
}

// ---------------- up2: convT s2 k4, 64ch 64x64 -> 3ch 128x128, all 3 co/thread ----------------
__global__ __launch_bounds__(256) void k_convT_up2(
    const float* __restrict__ in, const void* __restrict__ w,
    const void* __restrict__ bias, float* __restrict__ out,
    const int* __restrict__ flag)
{
  const int Cin = 64;
  __shared__ float sW[3072];
  int fl = flag[0];
  int bid = blockIdx.x;
  int s = bid & 7, n = bid >> 3;
  int tid = threadIdx.x;
  for (int i = tid; i < 3072; i += 256)
    sW[i] = ldg_in(w, i, fl);
  __syncthreads();
  int qa = s * 8 + (tid >> 5);
  int qb0 = (tid & 31) * 2;
  float bp = ldg_in(bias, 0, fl), bq = ldg_in(bias, 1, fl), br = ldg_in(bias, 2, fl);
  float pA0 = bp, pA1 = bp, pB0 = bp, pB1 = bp, pC0 = bp, pC1 = bp, pD0 = bp, pD1 = bp;
  float qA0 = bq, qA1 = bq, qB0_ = bq, qB1 = bq, qC0 = bq, qC1 = bq, qD0 = bq, qD1 = bq;
  float rA0 = br, rA1 = br, rB0 = br, rB1 = br, rC0 = br, rC1 = br, rD0 = br, rD1 = br;
  const float* ip = in + (size_t)n * Cin * 4096;
  bool vm = qa >= 1, vd = qa + 1 < 64;
  bool vl = qb0 > 0, vr = qb0 < 62;
  for (int ci = 0; ci < Cin; ++ci) {
    const float* p = ip + ci * 4096;
    const float* rm = p + (qa - 1) * 64;
    const float* rc = p + qa * 64;
    const float* rd = p + (qa + 1) * 64;
    float m0 = (vm && vl) ? rm[qb0 - 1] : 0.f;
    float m1 = vm ? rm[qb0] : 0.f, m2 = vm ? rm[qb0 + 1] : 0.f;
    float m3 = (vm && vr) ? rm[qb0 + 2] : 0.f;
    float c0 = vl ? rc[qb0 - 1] : 0.f;
    float c1 = rc[qb0], c2 = rc[qb0 + 1];
    float c3 = vr ? rc[qb0 + 2] : 0.f;
    float d0 = (vd && vl) ? rd[qb0 - 1] : 0.f;
    float d1 = vd ? rd[qb0] : 0.f, d2 = vd ? rd[qb0 + 1] : 0.f;
    float d3 = (vd && vr) ? rd[qb0 + 2] : 0.f;
    float w00, w01, w02, w03, w10, w11, w12, w13, w20, w21, w22, w23, w30, w31, w32, w33;
    {
      LOADW16(sW + ci * 48)
      CT_J(pA0, pB0, pC0, pD0, m0, m1, m2, c0, c1, c2, d0, d1, d2)
      CT_J(pA1, pB1, pC1, pD1, m1, m2, m3, c1, c2, c3, d1, d2, d3)
    }
    {
      LOADW16(sW + ci * 48 + 16)
      CT_J(qA0, qB0_, qC0, qD0, m0, m1, m2, c0, c1, c2, d0, d1, d2)
      CT_J(qA1, qB1, qC1, qD1, m1, m2, m3, c1, c2, c3, d1, d2, d3)
    }
    {
      LOADW16(sW + ci * 48 + 32)
      CT_J(rA0, rB0, rC0, rD0, m0, m1, m2, c0, c1, c2, d0, d1, d2)
      CT_J(rA1, rB1, rC1, rD1, m1, m2, m3, c1, c2, c3, d1, d2, d3)
    }
  }
  float* op = out + ((size_t)(n * 3 + 0) * 128 + 2 * qa) * 128 + 2 * qb0;
  op[0] = pA0; op[1] = pB0; op[2] = pA1; op[3] = pB1;
  op[128] = pC0; op[129] = pD0; op[130] = pC1; op[131] = pD1;
  op += (size_t)128 * 128;
  op[0] = qA0; op[1] = qB0_; op[2] = qA1; op[3] = qB1;
  op[128] = qC0; op[129] = qD0; op[130] = qC1; op[131] = qD1;
  op += (size_t)128 * 128;
  op[0] = rA0; op[1] = rB0; op[2] = rA1; op[3] = rB1;
  op[128] = rC0; op[129] = rD0; op[130] = rC1; op[131] = rD1;
}

// ---------------- VQ: argmin (first-min), zq in-place, idx (fp32) to d_out ----------------
// sE padded to row stride 65: sEE reads bank=(tid+d)%32 -> conflict-free (was 64-way);
// dot reads are wave-uniform -> LDS broadcast, conflict-free at any stride.
__global__ __launch_bounds__(256) void k_vq(
    const float* __restrict__ z, const void* __restrict__ emb,
    float* __restrict__ zq, float* __restrict__ idx_out,
    const int* __restrict__ flag, float* __restrict__ lossp, int lossbase)
{
  const int PE = 65;
  __shared__ float sE[128 * PE];
  __shared__ float sEE[128];
  __shared__ float wsum[4];
  int fl = flag[0];
  int tid = threadIdx.x;
  int n = blockIdx.x * 256 + tid;
  int nb = n >> 10, p = n & 1023;
  const float* zp = z + nb * 65536 + p;
  float zv[64];
  float zz = 0.f;
  #pragma unroll
  for (int d = 0; d < 64; ++d) { zv[d] = zp[d * 1024]; zz = fmaf(zv[d], zv[d], zz); }
  float best = 3.4e38f; int bidx = 0;
  for (int kb = 0; kb < 8; ++kb) {
    __syncthreads();
    for (int i = tid; i < 8192; i += 256)
      sE[(i >> 6) * PE + (i & 63)] = ldg_in(emb, kb * 8192 + i, fl);
    __syncthreads();
    if (tid < 128) {
      const float* ep = sE + tid * PE;
      float s = 0.f;
      #pragma unroll
      for (int d = 0; d < 64; ++d) s = fmaf(ep[d], ep[d], s);
      sEE[tid] = s;
    }
    __syncthreads();
    for (int k = 0; k < 128; ++k) {
      const float* ep = sE + k * PE;
      float dot = 0.f;
      #pragma unroll
      for (int d = 0; d < 64; ++d) dot = fmaf(zv[d], ep[d], dot);
      float dist = zz + sEE[k] - 2.f * dot;
      if (dist < best) { best = dist; bidx = kb * 128 + k; }  // strict <: first min wins
    }
  }
  idx_out[n] = (float)bidx;
  float ls = 0.f;
  float* qp = zq + nb * 65536 + p;
  #pragma unroll
  for (int d = 0; d < 64; ++d) {
    float e = ldg_in(emb, bidx * 64 + d, fl);
    qp[d * 1024] = e;
    float df = e - zv[d];
    ls = fmaf(df, df, ls);
  }
  #pragma unroll
  for (int off = 32; off > 0; off >>= 1) ls += __shfl_down(ls, off);
  if ((tid & 63) == 0) wsum[tid >> 6] = ls;
  __syncthreads();
  if (tid == 0) lossp[lossbase + blockIdx.x] = wsum[0] + wsum[1] + wsum[2] + wsum[3];
}

__global__ void k_loss_final(const float* __restrict__ lossp, float* __restrict__ out) {
  if (threadIdx.x == 0 && blockIdx.x == 0) {
    float s = 0.f;
    for (int i = 0; i < 256; ++i) s += lossp[i];
    float L = s * (1.f / 4194304.f);
    out[R_RECON + 0] = L;
    out[R_RECON + 1] = L;
  }
}

extern "C" void kernel_launch(void* const* d_in, const int* in_sizes, int n_in,
                              void* d_out, int out_size, void* d_ws, size_t ws_size,
                              hipStream_t stream)
{
  float* out = (float*)d_out;          // fp32 output (established R8-R10)

  float* F = (float*)d_ws;
  float* LOSSP = F;
  int* FLAG = (int*)(F + 256);
  float* A = F + 272;

  int Bc = 64;
  while (Bc > 1 && 4ull * (272ull + (size_t)Bc * 393216ull) > ws_size) Bc >>= 1;
  float* H1 = A;
  float* H2 = A + (size_t)Bc * 262144;
  float* H3 = A;
  float* T  = A + (size_t)Bc * 131072;
  float* Z  = A + (size_t)Bc * 163840;
  float* D1 = H2;
  float* D2 = A;

  const void* patch = d_in[0];
  const void* ew1 = d_in[1];  const void* eb1 = d_in[2];
  const void* ew2 = d_in[3];  const void* eb2 = d_in[4];
  const void* ew3 = d_in[5];  const void* eb3 = d_in[6];
  const void* er1a = d_in[7]; const void* er1b = d_in[8];
  const void* er2a = d_in[9]; const void* er2b = d_in[10];
  const void* pqw = d_in[11]; const void* pqb = d_in[12];
  const void* emb = d_in[13];
  const void* dw1 = d_in[14]; const void* db1 = d_in[15];
  const void* dr1a = d_in[16]; const void* dr1b = d_in[17];
  const void* dr2a = d_in[18]; const void* dr2b = d_in[19];
  const void* dw2 = d_in[20]; const void* db2 = d_in[21];
  const void* dw3 = d_in[22]; const void* db3 = d_in[23];

  k_detect<<<1, 256, 0, stream>>>((const u16*)patch, FLAG);

  int NC = 64 / Bc;
  for (int c = 0; c < NC; ++c) {
    int b0 = c * Bc;

    // ---- encoder ----
    k_conv_s2k4<true><<<Bc * 1024, 256, 0, stream>>>(patch, ew1, eb1, H1, FLAG,
                                                     b0 * 49152, 3, 128, 64, 64);
    k_enc2<<<Bc * 32, 256, 0, stream>>>(H1, ew2, eb2, H2, FLAG);
    k_conv3x3_v3<false, false, false, true><<<Bc * 32, 256, 0, stream>>>(H2, ew3, eb3, H3, FLAG, 128, 128);
    k_conv3x3_v3<true, false, true, false><<<Bc * 8, 256, 0, stream>>>(H3, er1a, nullptr, T, FLAG, 128, 32);
    k_conv1x1_t4<true, false, false><<<Bc * 32, 256, 0, stream>>>(T, er1b, nullptr, H3, FLAG, 32, 128);
    k_conv3x3_v3<true, false, true, false><<<Bc * 8, 256, 0, stream>>>(H3, er2a, nullptr, T, FLAG, 128, 32);
    k_conv1x1_t4<true, false, true><<<Bc * 32, 256, 0, stream>>>(T, er2b, nullptr, H3, FLAG, 32, 128);
    k_conv1x1_t4<false, true, false><<<Bc * 16, 256, 0, stream>>>(H3, pqw, pqb, Z, FLAG, 128, 64);

    // ---- VQ ----
    k_vq<<<Bc * 4, 256, 0, stream>>>(Z, emb, Z, out + R_RECON + 2 + (size_t)b0 * 1024,
                                     FLAG, LOSSP, b0 * 4);

    // ---- decoder ----
    k_conv3x3_v3<false, true, false, true><<<Bc * 32, 256, 0, stream>>>(Z, dw1, db1, D1, FLAG, 64, 128);
    k_conv3x3_v3<true, false, true, false><<<Bc * 8, 256, 0, stream>>>(D1, dr1a, nullptr, T, FLAG, 128, 32);
    k_conv1x1_t4<true, false, false><<<Bc * 32, 256, 0, stream>>>(T, dr1b, nullptr, D1, FLAG, 32, 128);
    k_conv3x3_v3<true, false, true, false><<<Bc * 8, 256, 0, stream>>>(D1, dr2a, nullptr, T, FLAG, 128, 32);
    k_conv1x1_t4<true, false, true><<<Bc * 32, 256, 0, stream>>>(T, dr2b, nullptr, D1, FLAG, 32, 128);
    k_convT_up1<<<Bc * 16, 256, 0, stream>>>(D1, dw2, db2, D2, FLAG);
    k_convT_up2<<<Bc * 8, 256, 0, stream>>>(D2, dw3, db3, out + (size_t)b0 * 49152, FLAG);
  }

  k_loss_final<<<1, 64, 0, stream>>>(LOSSP, out);
}

// Round 18
// 2565.414 us; speedup vs baseline: 6.4101x; 1.1021x over previous
//
#include <hip/hip_runtime.h>
#include <hip/hip_bf16.h>

typedef __hip_bfloat16 bf16;
typedef unsigned short u16;

#define R_RECON 3145728
#define N_IDX   65536

__device__ __forceinline__ float ldg_in(const void* p, int i, int fl) {
  return fl ? ((const float*)p)[i] : __bfloat162float(((const bf16*)p)[i]);
}

__global__ __launch_bounds__(256) void k_detect(const u16* __restrict__ p, int* __restrict__ flag) {
  __shared__ int s;
  if (threadIdx.x == 0) s = 0;
  __syncthreads();
  for (int i = threadIdx.x; i < 4096; i += 256) {
    float f = __uint_as_float(((unsigned)p[i]) << 16);
    if (!(fabsf(f) < 16384.f)) atomicOr(&s, 1);
  }
  __syncthreads();
  if (threadIdx.x == 0) flag[0] = s;
}

// ---------------- enc1: stride-2 4x4 conv from global input (Cin=3) ----------------
template<bool GIN>
__global__ __launch_bounds__(256) void k_conv_s2k4(
    const void* __restrict__ inp, const void* __restrict__ w,
    const void* __restrict__ bias, float* __restrict__ out,
    const int* __restrict__ flag, int in_off,
    int Cin, int Hin, int Cout, int Hout)
{
  __shared__ float sW[1024];
  int fl = flag[0];
  int tid = threadIdx.x;
  int idx = blockIdx.x * 256 + tid;
  int hw = Hout * Hout;
  int co = (idx / hw) % Cout;
  for (int i = tid; i < Cin * 16; i += 256)
    sW[i] = ldg_in(w, co * Cin * 16 + i, fl);
  __syncthreads();
  int ox = idx % Hout; int t = idx / Hout;
  int oy = t % Hout;
  int n = idx / (hw * Cout);
  float acc = ldg_in(bias, co, fl);
  int iy0 = 2 * oy - 1, ix0 = 2 * ox - 1;
  const float* inf = (const float*)inp;
  for (int ci = 0; ci < Cin; ++ci) {
    int base_in = (n * Cin + ci) * Hin * Hin;
    const float* wp = sW + ci * 16;
    #pragma unroll
    for (int ky = 0; ky < 4; ++ky) {
      int iy = iy0 + ky;
      if ((unsigned)iy >= (unsigned)Hin) continue;
      int rb = base_in + iy * Hin;
      #pragma unroll
      for (int kx = 0; kx < 4; ++kx) {
        int ix = ix0 + kx;
        if ((unsigned)ix >= (unsigned)Hin) continue;
        float v = GIN ? ldg_in(inp, in_off + rb + ix, fl) : inf[rb + ix];
        acc = fmaf(v, wp[ky * 4 + kx], acc);
      }
    }
  }
  out[idx] = fmaxf(acc, 0.f);
}

// ---------------- enc2: s2 k4, 64ch 64x64 -> 128ch 32x32; 4 co/thread, padded LDS ----------------
__global__ __launch_bounds__(256) void k_enc2(
    const float* __restrict__ in, const void* __restrict__ w,
    const void* __restrict__ bias, float* __restrict__ out,
    const int* __restrict__ flag)
{
  const int Cin = 64, Cout = 128;
  const int P = 65;
  __shared__ __align__(16) float sW[4096];   // 4 co x 64ci x 16
  __shared__ float sIn[64 * P];              // one 64x64 plane, padded
  int fl = flag[0];
  int bid = blockIdx.x;
  int cp = bid & 31, n = bid >> 5;
  int co0 = cp * 4;
  int tid = threadIdx.x;
  for (int i = tid; i < 4096; i += 256)
    sW[i] = ldg_in(w, co0 * 1024 + i, fl);
  int oy = tid >> 3, ox0 = (tid & 7) << 2;
  float bvA = ldg_in(bias, co0, fl), bvB = ldg_in(bias, co0 + 1, fl);
  float bvC = ldg_in(bias, co0 + 2, fl), bvD = ldg_in(bias, co0 + 3, fl);
  float a0 = bvA, a1 = bvA, a2 = bvA, a3 = bvA;
  float b0 = bvB, b1 = bvB, b2 = bvB, b3 = bvB;
  float c0 = bvC, c1 = bvC, c2 = bvC, c3 = bvC;
  float d0 = bvD, d1 = bvD, d2 = bvD, d3 = bvD;
  int ry0 = 2 * oy - 1;
  int cx0 = 2 * ox0 - 1;
  const float* ip = in + (size_t)n * Cin * 4096;
  for (int ci = 0; ci < Cin; ++ci) {
    __syncthreads();
    {
      const float4* g4 = (const float4*)(ip + ci * 4096);
      #pragma unroll
      for (int j = 0; j < 4; ++j) {
        int i4 = tid + j * 256;        // over 1024 float4
        float4 v = g4[i4];
        int flat = i4 * 4;
        float* dst = sIn + (flat >> 6) * P + (flat & 63);
        dst[0] = v.x; dst[1] = v.y; dst[2] = v.z; dst[3] = v.w;
      }
    }
    __syncthreads();
    #pragma unroll
    for (int ky = 0; ky < 4; ++ky) {
      int iy = ry0 + ky;
      if ((unsigned)iy < 64u) {
        const float* rp = sIn + iy * P;
        float x0 = (cx0 >= 0) ? rp[cx0] : 0.f;
        float x1 = rp[cx0 + 1], x2 = rp[cx0 + 2], x3 = rp[cx0 + 3], x4 = rp[cx0 + 4];
        float x5 = rp[cx0 + 5], x6 = rp[cx0 + 6], x7 = rp[cx0 + 7], x8 = rp[cx0 + 8];
        float x9 = (cx0 + 9 < 64) ? rp[cx0 + 9] : 0.f;
        int wb = ci * 16 + ky * 4;
        {
          float4 wa = *(const float4*)(sW + wb);
          a0 = fmaf(x0, wa.x, fmaf(x1, wa.y, fmaf(x2, wa.z, fmaf(x3, wa.w, a0))));
          a1 = fmaf(x2, wa.x, fmaf(x3, wa.y, fmaf(x4, wa.z, fmaf(x5, wa.w, a1))));
          a2 = fmaf(x4, wa.x, fmaf(x5, wa.y, fmaf(x6, wa.z, fmaf(x7, wa.w, a2))));
          a3 = fmaf(x6, wa.x, fmaf(x7, wa.y, fmaf(x8, wa.z, fmaf(x9, wa.w, a3))));
          float4 wbv = *(const float4*)(sW + wb + 1024);
          b0 = fmaf(x0, wbv.x, fmaf(x1, wbv.y, fmaf(x2, wbv.z, fmaf(x3, wbv.w, b0))));
          b1 = fmaf(x2, wbv.x, fmaf(x3, wbv.y, fmaf(x4, wbv.z, fmaf(x5, wbv.w, b1))));
          b2 = fmaf(x4, wbv.x, fmaf(x5, wbv.y, fmaf(x6, wbv.z, fmaf(x7, wbv.w, b2))));
          b3 = fmaf(x6, wbv.x, fmaf(x7, wbv.y, fmaf(x8, wbv.z, fmaf(x9, wbv.w, b3))));
        }
        {
          float4 wc = *(const float4*)(sW + wb + 2048);
          c0 = fmaf(x0, wc.x, fmaf(x1, wc.y, fmaf(x2, wc.z, fmaf(x3, wc.w, c0))));
          c1 = fmaf(x2, wc.x, fmaf(x3, wc.y, fmaf(x4, wc.z, fmaf(x5, wc.w, c1))));
          c2 = fmaf(x4, wc.x, fmaf(x5, wc.y, fmaf(x6, wc.z, fmaf(x7, wc.w, c2))));
          c3 = fmaf(x6, wc.x, fmaf(x7, wc.y, fmaf(x8, wc.z, fmaf(x9, wc.w, c3))));
          float4 wd = *(const float4*)(sW + wb + 3072);
          d0 = fmaf(x0, wd.x, fmaf(x1, wd.y, fmaf(x2, wd.z, fmaf(x3, wd.w, d0))));
          d1 = fmaf(x2, wd.x, fmaf(x3, wd.y, fmaf(x4, wd.z, fmaf(x5, wd.w, d1))));
          d2 = fmaf(x4, wd.x, fmaf(x5, wd.y, fmaf(x6, wd.z, fmaf(x7, wd.w, d2))));
          d3 = fmaf(x6, wd.x, fmaf(x7, wd.y, fmaf(x8, wd.z, fmaf(x9, wd.w, d3))));
        }
      }
    }
  }
  float* op = out + (size_t)(n * Cout + co0) * 1024 + oy * 32 + ox0;
  op[0] = fmaxf(a0, 0.f); op[1] = fmaxf(a1, 0.f); op[2] = fmaxf(a2, 0.f); op[3] = fmaxf(a3, 0.f);
  op += 1024;
  op[0] = fmaxf(b0, 0.f); op[1] = fmaxf(b1, 0.f); op[2] = fmaxf(b2, 0.f); op[3] = fmaxf(b3, 0.f);
  op += 1024;
  op[0] = fmaxf(c0, 0.f); op[1] = fmaxf(c1, 0.f); op[2] = fmaxf(c2, 0.f); op[3] = fmaxf(c3, 0.f);
  op += 1024;
  op[0] = fmaxf(d0, 0.f); op[1] = fmaxf(d1, 0.f); op[2] = fmaxf(d2, 0.f); op[3] = fmaxf(d3, 0.f);
}

// ---- 3x3 conv s1 p1 @32x32 v3: 256 thr, 4 co/block, 2 co/thread, 4x2 px, padded LDS ----
#define C4(P0, P1, P2, P3, W0, W1, W2) \
  P0 = fmaf(x0, W0, fmaf(x1, W1, fmaf(x2, W2, P0))); \
  P1 = fmaf(x1, W0, fmaf(x2, W1, fmaf(x3, W2, P1))); \
  P2 = fmaf(x2, W0, fmaf(x3, W1, fmaf(x4, W2, P2))); \
  P3 = fmaf(x3, W0, fmaf(x4, W1, fmaf(x5, W2, P3)));

#define ROW_AB(T, KY) \
  C4(A##T##0, A##T##1, A##T##2, A##T##3, wa[3*KY], wa[3*KY+1], wa[3*KY+2]) \
  C4(B##T##0, B##T##1, B##T##2, B##T##3, wb[3*KY], wb[3*KY+1], wb[3*KY+2])

#define C33_LOAD(RP) \
  x0 = (ox0 > 0) ? (RP)[ox0 - 1] : 0.f; \
  x1 = (RP)[ox0]; x2 = (RP)[ox0 + 1]; x3 = (RP)[ox0 + 2]; x4 = (RP)[ox0 + 3]; \
  x5 = (ox0 < 28) ? (RP)[ox0 + 4] : 0.f; \
  if (IN_RELU) { \
    x0 = fmaxf(x0, 0.f); x1 = fmaxf(x1, 0.f); x2 = fmaxf(x2, 0.f); \
    x3 = fmaxf(x3, 0.f); x4 = fmaxf(x4, 0.f); x5 = fmaxf(x5, 0.f); \
  }

#define ST_ROW4(PTR, P0, P1, P2, P3) \
  if (OUT_RELU) { (PTR)[0] = fmaxf(P0, 0.f); (PTR)[1] = fmaxf(P1, 0.f); \
                  (PTR)[2] = fmaxf(P2, 0.f); (PTR)[3] = fmaxf(P3, 0.f); } \
  else { (PTR)[0] = P0; (PTR)[1] = P1; (PTR)[2] = P2; (PTR)[3] = P3; }

template<bool IN_RELU, bool TRANS_W, bool OUT_RELU, bool HAS_BIAS>
__global__ __launch_bounds__(256) void k_conv3x3_v3(
    const float* __restrict__ in, const void* __restrict__ w,
    const void* __restrict__ bias, float* __restrict__ out,
    const int* __restrict__ flag, int Cin, int Cout)
{
  const int HW = 1024;
  const int PP = 33;
  const int PLANE = 32 * PP;           // 1056
  __shared__ float sW[4608];           // 4 co x Cin x 9, Cin<=128
  __shared__ float sIn[2 * 1056];      // two padded 32x32 planes
  int fl = flag[0];
  int nq = Cout >> 2;
  int bid = blockIdx.x;
  int qc = bid % nq, n = bid / nq;
  int co0 = qc * 4;
  int tid = threadIdx.x;
  int tot = 4 * Cin * 9;
  for (int i = tid; i < tot; i += 256) {
    int cl = i / (Cin * 9), rem = i % (Cin * 9);
    int ci = rem / 9, k = rem % 9;
    int src = TRANS_W ? ((ci * Cout + co0 + cl) * 9 + (8 - k))
                      : (((co0 + cl) * Cin + ci) * 9 + k);
    sW[i] = ldg_in(w, src, fl);
  }
  int cp = tid >> 7;
  int tt = tid & 127;
  int ty = tt >> 3, tx = tt & 7;
  int oy0 = ty * 2, ox0 = tx * 4;
  int coA = co0 + cp * 2;
  const float* WA = sW + (cp * 2) * Cin * 9;
  const float* WB = WA + Cin * 9;
  float bvA = HAS_BIAS ? ldg_in(bias, coA, fl) : 0.f;
  float bvB = HAS_BIAS ? ldg_in(bias, coA + 1, fl) : 0.f;
  float A00=bvA,A01=bvA,A02=bvA,A03=bvA, A10=bvA,A11=bvA,A12=bvA,A13=bvA;
  float B00=bvB,B01=bvB,B02=bvB,B03=bvB, B10=bvB,B11=bvB,B12=bvB,B13=bvB;
  const float* ip = in + (size_t)n * Cin * HW;
  for (int cb = 0; cb < Cin; cb += 2) {
    __syncthreads();
    {
      const float4* g4 = (const float4*)(ip + cb * HW);
      #pragma unroll
      for (int j = 0; j < 2; ++j) {
        int i4 = tid + j * 256;        // over 512 float4 (2 planes)
        float4 v = g4[i4];
        int flat = i4 * 4;
        int pl = flat >> 10, rem = flat & 1023;
        float* dst = sIn + pl * PLANE + (rem >> 5) * PP + (rem & 31);
        dst[0] = v.x; dst[1] = v.y; dst[2] = v.z; dst[3] = v.w;
      }
    }
    __syncthreads();
    #pragma unroll
    for (int u = 0; u < 2; ++u) {
      int ci = cb + u;
      const float* sP = sIn + u * PLANE;
      const float* wa = WA + ci * 9;
      const float* wb = WB + ci * 9;
      float x0, x1, x2, x3, x4, x5;
      if (oy0 > 0) {
        C33_LOAD(sP + (oy0 - 1) * PP)
        ROW_AB(0, 0)
      }
      { C33_LOAD(sP + oy0 * PP)
        ROW_AB(0, 1) ROW_AB(1, 0) }
      { C33_LOAD(sP + (oy0 + 1) * PP)
        ROW_AB(0, 2) ROW_AB(1, 1) }
      if (oy0 < 30) {
        C33_LOAD(sP + (oy0 + 2) * PP)
        ROW_AB(1, 2)
      }
    }
  }
  float* op = out + (size_t)(n * Cout + coA) * HW + oy0 * 32 + ox0;
  ST_ROW4(op,      A00, A01, A02, A03)
  ST_ROW4(op + 32, A10, A11, A12, A13)
  op += HW;
  ST_ROW4(op,      B00, B01, B02, B03)
  ST_ROW4(op + 32, B10, B11, B12, B13)
}

// ---------------- 1x1 conv @32x32: 4co x 4p register tile ----------------
template<bool ACCUM, bool HAS_BIAS, bool OUT_RELU>
__global__ __launch_bounds__(256) void k_conv1x1_t4(
    const float* __restrict__ in, const void* __restrict__ w,
    const void* __restrict__ bias, float* __restrict__ out,
    const int* __restrict__ flag, int Cin, int Cout)
{
  const int HW = 1024;
  __shared__ float sW[512];
  int fl = flag[0];
  int nq = Cout >> 2;
  int bid = blockIdx.x;
  int qc = bid % nq, n = bid / nq;
  int co0 = qc * 4;
  int tid = threadIdx.x;
  for (int i = tid; i < 4 * Cin; i += 256)
    sW[i] = ldg_in(w, co0 * Cin + i, fl);
  __syncthreads();
  float acc[4][4];
  #pragma unroll
  for (int c = 0; c < 4; ++c) {
    float bv = HAS_BIAS ? ldg_in(bias, co0 + c, fl) : 0.f;
    #pragma unroll
    for (int k = 0; k < 4; ++k) acc[c][k] = bv;
  }
  const float* ip = in + (size_t)n * Cin * HW + tid;
  for (int ci = 0; ci < Cin; ++ci) {
    const float* p = ip + ci * HW;
    float x0 = p[0], x1 = p[256], x2 = p[512], x3 = p[768];
    #pragma unroll
    for (int c = 0; c < 4; ++c) {
      float wv = sW[c * Cin + ci];
      acc[c][0] = fmaf(wv, x0, acc[c][0]);
      acc[c][1] = fmaf(wv, x1, acc[c][1]);
      acc[c][2] = fmaf(wv, x2, acc[c][2]);
      acc[c][3] = fmaf(wv, x3, acc[c][3]);
    }
  }
  #pragma unroll
  for (int c = 0; c < 4; ++c) {
    float* op = out + (size_t)(n * Cout + co0 + c) * HW + tid;
    #pragma unroll
    for (int k = 0; k < 4; ++k) {
      float v = acc[c][k];
      if (ACCUM) v += op[k * 256];
      if (OUT_RELU) v = fmaxf(v, 0.f);
      op[k * 256] = v;
    }
  }
}

// ---- ConvTranspose s2 k4 p1 parity-quad macros ----
#define LOADW16V(BASE) { \
  const float4* w4_ = (const float4*)(BASE); \
  float4 t0_ = w4_[0], t1_ = w4_[1], t2_ = w4_[2], t3_ = w4_[3]; \
  w00 = t0_.x; w01 = t0_.y; w02 = t0_.z; w03 = t0_.w; \
  w10 = t1_.x; w11 = t1_.y; w12 = t1_.z; w13 = t1_.w; \
  w20 = t2_.x; w21 = t2_.y; w22 = t2_.z; w23 = t2_.w; \
  w30 = t3_.x; w31 = t3_.y; w32 = t3_.z; w33 = t3_.w; }

#define CT_J(P00, P01, P10, P11, M0, M1, M2, C0, C1, C2, D0, D1, D2) \
  P00 = fmaf(w11, C1, fmaf(w13, C0, fmaf(w31, M1, fmaf(w33, M0, P00)))); \
  P01 = fmaf(w10, C2, fmaf(w12, C1, fmaf(w30, M2, fmaf(w32, M1, P01)))); \
  P10 = fmaf(w01, D1, fmaf(w03, D0, fmaf(w21, C1, fmaf(w23, C0, P10)))); \
  P11 = fmaf(w00, D2, fmaf(w02, D1, fmaf(w20, C2, fmaf(w22, C1, P11))));

#define DECL16(PX, BV) \
  float PX##A0=BV, PX##A1=BV, PX##A2=BV, PX##A3=BV, \
        PX##B0=BV, PX##B1=BV, PX##B2=BV, PX##B3=BV, \
        PX##C0=BV, PX##C1=BV, PX##C2=BV, PX##C3=BV, \
        PX##D0=BV, PX##D1=BV, PX##D2=BV, PX##D3=BV;

#define CT_CO(PX) \
  CT_J(PX##A0, PX##B0, PX##C0, PX##D0, m0, m1, m2, c0, c1, c2, d0, d1, d2) \
  CT_J(PX##A1, PX##B1, PX##C1, PX##D1, m1, m2, m3, c1, c2, c3, d1, d2, d3) \
  CT_J(PX##A2, PX##B2, PX##C2, PX##D2, m2, m3, m4, c2, c3, c4, d2, d3, d4) \
  CT_J(PX##A3, PX##B3, PX##C3, PX##D3, m3, m4, m5, c3, c4, c5, d3, d4, d5)

#define CT_STORE(PX, PTR, HO) \
  (PTR)[0] = fmaxf(PX##A0, 0.f); (PTR)[1] = fmaxf(PX##B0, 0.f); \
  (PTR)[2] = fmaxf(PX##A1, 0.f); (PTR)[3] = fmaxf(PX##B1, 0.f); \
  (PTR)[4] = fmaxf(PX##A2, 0.f); (PTR)[5] = fmaxf(PX##B2, 0.f); \
  (PTR)[6] = fmaxf(PX##A3, 0.f); (PTR)[7] = fmaxf(PX##B3, 0.f); \
  (PTR)[HO]     = fmaxf(PX##C0, 0.f); (PTR)[HO + 1] = fmaxf(PX##D0, 0.f); \
  (PTR)[HO + 2] = fmaxf(PX##C1, 0.f); (PTR)[HO + 3] = fmaxf(PX##D1, 0.f); \
  (PTR)[HO + 4] = fmaxf(PX##C2, 0.f); (PTR)[HO + 5] = fmaxf(PX##D2, 0.f); \
  (PTR)[HO + 6] = fmaxf(PX##C3, 0.f); (PTR)[HO + 7] = fmaxf(PX##D3, 0.f);

// ---------------- up1: convT s2 k4, 128ch 32x32 -> 64ch 64x64, 4 co/thread, staged input ----
__global__ __launch_bounds__(256) void k_convT_up1(
    const float* __restrict__ in, const void* __restrict__ w,
    const void* __restrict__ bias, float* __restrict__ out,
    const int* __restrict__ flag)
{
  const int Cin = 128, Cout = 64;
  const int PP = 33;
  __shared__ __align__(16) float sW[8192];   // 4 co x 128ci x 16 (32 KB)
  __shared__ float sIn[32 * PP];             // one 32x32 plane, padded
  int fl = flag[0];
  int bid = blockIdx.x;
  int cp = bid & 15, n = bid >> 4;
  int co0 = cp * 4;
  int tid = threadIdx.x;
  for (int i = tid; i < 8192; i += 256) {
    int cl = i >> 11, rem = i & 2047;
    int ci = rem >> 4, k = rem & 15;
    sW[i] = ldg_in(w, (ci * Cout + co0 + cl) * 16 + k, fl);
  }
  int qa = tid >> 3;
  int qb0 = (tid & 7) * 4;
  float bv0 = ldg_in(bias, co0, fl), bv1 = ldg_in(bias, co0 + 1, fl);
  float bv2 = ldg_in(bias, co0 + 2, fl), bv3 = ldg_in(bias, co0 + 3, fl);
  DECL16(u, bv0) DECL16(v, bv1) DECL16(y, bv2) DECL16(z, bv3)
  const float* ip = in + (size_t)n * Cin * 1024;
  bool vm = qa >= 1, vd = qa + 1 < 32;
  bool vl = qb0 > 0, vr = qb0 < 28;
  for (int ci = 0; ci < Cin; ++ci) {
    __syncthreads();                         // covers weight staging on iter 0, prior reads after
    {
      float4 g = ((const float4*)(ip + ci * 1024))[tid];
      float* dst = sIn + (tid >> 3) * PP + (tid & 7) * 4;
      dst[0] = g.x; dst[1] = g.y; dst[2] = g.z; dst[3] = g.w;
    }
    __syncthreads();
    const float* rm = sIn + (qa - 1) * PP;
    const float* rc = sIn + qa * PP;
    const float* rd = sIn + (qa + 1) * PP;
    float m0 = (vm && vl) ? rm[qb0 - 1] : 0.f;
    float m1 = vm ? rm[qb0] : 0.f, m2 = vm ? rm[qb0 + 1] : 0.f;
    float m3 = vm ? rm[qb0 + 2] : 0.f, m4 = vm ? rm[qb0 + 3] : 0.f;
    float m5 = (vm && vr) ? rm[qb0 + 4] : 0.f;
    float c0 = vl ? rc[qb0 - 1] : 0.f;
    float c1 = rc[qb0], c2 = rc[qb0 + 1], c3 = rc[qb0 + 2], c4 = rc[qb0 + 3];
    float c5 = vr ? rc[qb0 + 4] : 0.f;
    float d0 = (vd && vl) ? rd[qb0 - 1] : 0.f;
    float d1 = vd ? rd[qb0] : 0.f, d2 = vd ? rd[qb0 + 1] : 0.f;
    float d3 = vd ? rd[qb0 + 2] : 0.f, d4 = vd ? rd[qb0 + 3] : 0.f;
    float d5 = (vd && vr) ? rd[qb0 + 4] : 0.f;
    float w00, w01, w02, w03, w10, w11, w12, w13, w20, w21, w22, w23, w30, w31, w32, w33;
    { LOADW16V(sW + ci * 16)        CT_CO(u) }
    { LOADW16V(sW + 2048 + ci * 16) CT_CO(v) }
    { LOADW16V(sW + 4096 + ci * 16) CT_CO(y) }
    { LOADW16V(sW + 6144 + ci * 16) CT_CO(z) }
  }
  float* op = out + ((size_t)(n * Cout + co0) * 64 + 2 * qa) * 64 + 2 * qb0;
  CT_STORE(u, op, 64) op += (size_t)64 * 64;
  CT_STORE(v, op, 64) op += (size_t)64 * 64;
  CT_STORE(y, op, 64) op += (size_t)64 * 64;
  CT_STORE(z, op, 64)
}

// ---------------- up2: convT s2 k4, 64ch 64x64 -> 3ch 128x128, all 3 co/thread ----------------
__global__ __launch_bounds__(256) void k_convT_up2(
    const float* __restrict__ in, const void* __restrict__ w,
    const void* __restrict__ bias, float* __restrict__ out,
    const int* __restrict__ flag)
{
  const int Cin = 64;
  __shared__ __align__(16) float sW[3072];
  int fl = flag[0];
  int bid = blockIdx.x;
  int s = bid & 7, n = bid >> 3;
  int tid = threadIdx.x;
  for (int i = tid; i < 3072; i += 256)
    sW[i] = ldg_in(w, i, fl);
  __syncthreads();
  int qa = s * 8 + (tid >> 5);
  int qb0 = (tid & 31) * 2;
  float bp = ldg_in(bias, 0, fl), bq = ldg_in(bias, 1, fl), br = ldg_in(bias, 2, fl);
  float pA0 = bp, pA1 = bp, pB0 = bp, pB1 = bp, pC0 = bp, pC1 = bp, pD0 = bp, pD1 = bp;
  float qA0 = bq, qA1 = bq, qB0_ = bq, qB1 = bq, qC0 = bq, qC1 = bq, qD0 = bq, qD1 = bq;
  float rA0 = br, rA1 = br, rB0 = br, rB1 = br, rC0 = br, rC1 = br, rD0 = br, rD1 = br;
  const float* ip = in + (size_t)n * Cin * 4096;
  bool vm = qa >= 1, vd = qa + 1 < 64;
  bool vl = qb0 > 0, vr = qb0 < 62;
  for (int ci = 0; ci < Cin; ++ci) {
    const float* p = ip + ci * 4096;
    const float* rm = p + (qa - 1) * 64;
    const float* rc = p + qa * 64;
    const float* rd = p + (qa + 1) * 64;
    float m0 = (vm && vl) ? rm[qb0 - 1] : 0.f;
    float m1 = vm ? rm[qb0] : 0.f, m2 = vm ? rm[qb0 + 1] : 0.f;
    float m3 = (vm && vr) ? rm[qb0 + 2] : 0.f;
    float c0 = vl ? rc[qb0 - 1] : 0.f;
    float c1 = rc[qb0], c2 = rc[qb0 + 1];
    float c3 = vr ? rc[qb0 + 2] : 0.f;
    float d0 = (vd && vl) ? rd[qb0 - 1] : 0.f;
    float d1 = vd ? rd[qb0] : 0.f, d2 = vd ? rd[qb0 + 1] : 0.f;
    float d3 = (vd && vr) ? rd[qb0 + 2] : 0.f;
    float w00, w01, w02, w03, w10, w11, w12, w13, w20, w21, w22, w23, w30, w31, w32, w33;
    {
      LOADW16V(sW + ci * 48)
      CT_J(pA0, pB0, pC0, pD0, m0, m1, m2, c0, c1, c2, d0, d1, d2)
      CT_J(pA1, pB1, pC1, pD1, m1, m2, m3, c1, c2, c3, d1, d2, d3)
    }
    {
      LOADW16V(sW + ci * 48 + 16)
      CT_J(qA0, qB0_, qC0, qD0, m0, m1, m2, c0, c1, c2, d0, d1, d2)
      CT_J(qA1, qB1, qC1, qD1, m1, m2, m3, c1, c2, c3, d1, d2, d3)
    }
    {
      LOADW16V(sW + ci * 48 + 32)
      CT_J(rA0, rB0, rC0, rD0, m0, m1, m2, c0, c1, c2, d0, d1, d2)
      CT_J(rA1, rB1, rC1, rD1, m1, m2, m3, c1, c2, c3, d1, d2, d3)
    }
  }
  float* op = out + ((size_t)(n * 3 + 0) * 128 + 2 * qa) * 128 + 2 * qb0;
  op[0] = pA0; op[1] = pB0; op[2] = pA1; op[3] = pB1;
  op[128] = pC0; op[129] = pD0; op[130] = pC1; op[131] = pD1;
  op += (size_t)128 * 128;
  op[0] = qA0; op[1] = qB0_; op[2] = qA1; op[3] = qB1;
  op[128] = qC0; op[129] = qD0; op[130] = qC1; op[131] = qD1;
  op += (size_t)128 * 128;
  op[0] = rA0; op[1] = rB0; op[2] = rA1; op[3] = rB1;
  op[128] = rC0; op[129] = rD0; op[130] = rC1; op[131] = rD1;
}

// ---------------- VQ: argmin (first-min), zq in-place, idx (fp32) to d_out ----------------
__global__ __launch_bounds__(256) void k_vq(
    const float* __restrict__ z, const void* __restrict__ emb,
    float* __restrict__ zq, float* __restrict__ idx_out,
    const int* __restrict__ flag, float* __restrict__ lossp, int lossbase)
{
  const int PE = 65;
  __shared__ float sE[128 * PE];
  __shared__ float sEE[128];
  __shared__ float wsum[4];
  int fl = flag[0];
  int tid = threadIdx.x;
  int n = blockIdx.x * 256 + tid;
  int nb = n >> 10, p = n & 1023;
  const float* zp = z + nb * 65536 + p;
  float zv[64];
  float zz = 0.f;
  #pragma unroll
  for (int d = 0; d < 64; ++d) { zv[d] = zp[d * 1024]; zz = fmaf(zv[d], zv[d], zz); }
  float best = 3.4e38f; int bidx = 0;
  for (int kb = 0; kb < 8; ++kb) {
    __syncthreads();
    for (int i = tid; i < 8192; i += 256)
      sE[(i >> 6) * PE + (i & 63)] = ldg_in(emb, kb * 8192 + i, fl);
    __syncthreads();
    if (tid < 128) {
      const float* ep = sE + tid * PE;
      float s = 0.f;
      #pragma unroll
      for (int d = 0; d < 64; ++d) s = fmaf(ep[d], ep[d], s);
      sEE[tid] = s;
    }
    __syncthreads();
    for (int k = 0; k < 128; ++k) {
      const float* ep = sE + k * PE;
      float dot = 0.f;
      #pragma unroll
      for (int d = 0; d < 64; ++d) dot = fmaf(zv[d], ep[d], dot);
      float dist = zz + sEE[k] - 2.f * dot;
      if (dist < best) { best = dist; bidx = kb * 128 + k; }  // strict <: first min wins
    }
  }
  idx_out[n] = (float)bidx;
  float ls = 0.f;
  float* qp = zq + nb * 65536 + p;
  #pragma unroll
  for (int d = 0; d < 64; ++d) {
    float e = ldg_in(emb, bidx * 64 + d, fl);
    qp[d * 1024] = e;
    float df = e - zv[d];
    ls = fmaf(df, df, ls);
  }
  #pragma unroll
  for (int off = 32; off > 0; off >>= 1) ls += __shfl_down(ls, off);
  if ((tid & 63) == 0) wsum[tid >> 6] = ls;
  __syncthreads();
  if (tid == 0) lossp[lossbase + blockIdx.x] = wsum[0] + wsum[1] + wsum[2] + wsum[3];
}

__global__ void k_loss_final(const float* __restrict__ lossp, float* __restrict__ out) {
  if (threadIdx.x == 0 && blockIdx.x == 0) {
    float s = 0.f;
    for (int i = 0; i < 256; ++i) s += lossp[i];
    float L = s * (1.f / 4194304.f);
    out[R_RECON + 0] = L;
    out[R_RECON + 1] = L;
  }
}

extern "C" void kernel_launch(void* const* d_in, const int* in_sizes, int n_in,
                              void* d_out, int out_size, void* d_ws, size_t ws_size,
                              hipStream_t stream)
{
  float* out = (float*)d_out;          // fp32 output (established R8-R10)

  float* F = (float*)d_ws;
  float* LOSSP = F;
  int* FLAG = (int*)(F + 256);
  float* A = F + 272;

  int Bc = 64;
  while (Bc > 1 && 4ull * (272ull + (size_t)Bc * 393216ull) > ws_size) Bc >>= 1;
  float* H1 = A;
  float* H2 = A + (size_t)Bc * 262144;
  float* H3 = A;
  float* T  = A + (size_t)Bc * 131072;
  float* Z  = A + (size_t)Bc * 163840;
  float* D1 = H2;
  float* D2 = A;

  const void* patch = d_in[0];
  const void* ew1 = d_in[1];  const void* eb1 = d_in[2];
  const void* ew2 = d_in[3];  const void* eb2 = d_in[4];
  const void* ew3 = d_in[5];  const void* eb3 = d_in[6];
  const void* er1a = d_in[7]; const void* er1b = d_in[8];
  const void* er2a = d_in[9]; const void* er2b = d_in[10];
  const void* pqw = d_in[11]; const void* pqb = d_in[12];
  const void* emb = d_in[13];
  const void* dw1 = d_in[14]; const void* db1 = d_in[15];
  const void* dr1a = d_in[16]; const void* dr1b = d_in[17];
  const void* dr2a = d_in[18]; const void* dr2b = d_in[19];
  const void* dw2 = d_in[20]; const void* db2 = d_in[21];
  const void* dw3 = d_in[22]; const void* db3 = d_in[23];

  k_detect<<<1, 256, 0, stream>>>((const u16*)patch, FLAG);

  int NC = 64 / Bc;
  for (int c = 0; c < NC; ++c) {
    int b0 = c * Bc;

    // ---- encoder ----
    k_conv_s2k4<true><<<Bc * 1024, 256, 0, stream>>>(patch, ew1, eb1, H1, FLAG,
                                                     b0 * 49152, 3, 128, 64, 64);
    k_enc2<<<Bc * 32, 256, 0, stream>>>(H1, ew2, eb2, H2, FLAG);
    k_conv3x3_v3<false, false, false, true><<<Bc * 32, 256, 0, stream>>>(H2, ew3, eb3, H3, FLAG, 128, 128);
    k_conv3x3_v3<true, false, true, false><<<Bc * 8, 256, 0, stream>>>(H3, er1a, nullptr, T, FLAG, 128, 32);
    k_conv1x1_t4<true, false, false><<<Bc * 32, 256, 0, stream>>>(T, er1b, nullptr, H3, FLAG, 32, 128);
    k_conv3x3_v3<true, false, true, false><<<Bc * 8, 256, 0, stream>>>(H3, er2a, nullptr, T, FLAG, 128, 32);
    k_conv1x1_t4<true, false, true><<<Bc * 32, 256, 0, stream>>>(T, er2b, nullptr, H3, FLAG, 32, 128);
    k_conv1x1_t4<false, true, false><<<Bc * 16, 256, 0, stream>>>(H3, pqw, pqb, Z, FLAG, 128, 64);

    // ---- VQ ----
    k_vq<<<Bc * 4, 256, 0, stream>>>(Z, emb, Z, out + R_RECON + 2 + (size_t)b0 * 1024,
                                     FLAG, LOSSP, b0 * 4);

    // ---- decoder ----
    k_conv3x3_v3<false, true, false, true><<<Bc * 32, 256, 0, stream>>>(Z, dw1, db1, D1, FLAG, 64, 128);
    k_conv3x3_v3<true, false, true, false><<<Bc * 8, 256, 0, stream>>>(D1, dr1a, nullptr, T, FLAG, 128, 32);
    k_conv1x1_t4<true, false, false><<<Bc * 32, 256, 0, stream>>>(T, dr1b, nullptr, D1, FLAG, 32, 128);
    k_conv3x3_v3<true, false, true, false><<<Bc * 8, 256, 0, stream>>>(D1, dr2a, nullptr, T, FLAG, 128, 32);
    k_conv1x1_t4<true, false, true><<<Bc * 32, 256, 0, stream>>>(T, dr2b, nullptr, D1, FLAG, 32, 128);
    k_convT_up1<<<Bc * 16, 256, 0, stream>>>(D1, dw2, db2, D2, FLAG);
    k_convT_up2<<<Bc * 8, 256, 0, stream>>>(D2, dw3, db3, out + (size_t)b0 * 49152, FLAG);
  }

  k_loss_final<<<1, 64, 0, stream>>>(LOSSP, out);
}

// Round 19
// 2237.543 us; speedup vs baseline: 7.3494x; 1.1465x over previous
//
#include <hip/hip_runtime.h>
#include <hip/hip_bf16.h>

typedef __hip_bfloat16 bf16;
typedef unsigned short u16;

#define R_RECON 3145728
#define N_IDX   65536

__device__ __forceinline__ float ldg_in(const void* p, int i, int fl) {
  return fl ? ((const float*)p)[i] : __bfloat162float(((const bf16*)p)[i]);
}
__device__ __forceinline__ float cvt(float v) { return v; }
__device__ __forceinline__ float cvt(bf16 v) { return __bfloat162float(v); }

__global__ __launch_bounds__(256) void k_detect(const u16* __restrict__ p, int* __restrict__ flag) {
  __shared__ int s;
  if (threadIdx.x == 0) s = 0;
  __syncthreads();
  for (int i = threadIdx.x; i < 4096; i += 256) {
    float f = __uint_as_float(((unsigned)p[i]) << 16);
    if (!(fabsf(f) < 16384.f)) atomicOr(&s, 1);
  }
  __syncthreads();
  if (threadIdx.x == 0) flag[0] = s;
}

// ---------------- enc1: s2 k4 p1, 3ch 128x128 -> 64ch 64x64; 2 co/thread, 4-wide ox ----
template<typename T>
__device__ __forceinline__ void enc1_loop(
    const T* __restrict__ ip, int iy0, int cx0, const float* sW,
    float& a0, float& a1, float& a2, float& a3,
    float& b0, float& b1, float& b2, float& b3)
{
  #pragma unroll
  for (int ci = 0; ci < 3; ++ci) {
    const T* cp = ip + ci * 16384;
    #pragma unroll
    for (int ky = 0; ky < 4; ++ky) {
      int iy = iy0 + ky;
      if ((unsigned)iy < 128u) {
        const T* rp = cp + iy * 128;
        float x0 = (cx0 >= 0) ? cvt(rp[cx0]) : 0.f;
        float x1 = cvt(rp[cx0 + 1]), x2 = cvt(rp[cx0 + 2]);
        float x3 = cvt(rp[cx0 + 3]), x4 = cvt(rp[cx0 + 4]);
        float x5 = cvt(rp[cx0 + 5]), x6 = cvt(rp[cx0 + 6]);
        float x7 = cvt(rp[cx0 + 7]), x8 = cvt(rp[cx0 + 8]);
        float x9 = (cx0 + 9 < 128) ? cvt(rp[cx0 + 9]) : 0.f;
        const float* WA = sW + ci * 16 + ky * 4;
        float wa0 = WA[0], wa1 = WA[1], wa2 = WA[2], wa3 = WA[3];
        a0 = fmaf(x0, wa0, fmaf(x1, wa1, fmaf(x2, wa2, fmaf(x3, wa3, a0))));
        a1 = fmaf(x2, wa0, fmaf(x3, wa1, fmaf(x4, wa2, fmaf(x5, wa3, a1))));
        a2 = fmaf(x4, wa0, fmaf(x5, wa1, fmaf(x6, wa2, fmaf(x7, wa3, a2))));
        a3 = fmaf(x6, wa0, fmaf(x7, wa1, fmaf(x8, wa2, fmaf(x9, wa3, a3))));
        const float* WB = WA + 48;
        float wb0 = WB[0], wb1 = WB[1], wb2 = WB[2], wb3 = WB[3];
        b0 = fmaf(x0, wb0, fmaf(x1, wb1, fmaf(x2, wb2, fmaf(x3, wb3, b0))));
        b1 = fmaf(x2, wb0, fmaf(x3, wb1, fmaf(x4, wb2, fmaf(x5, wb3, b1))));
        b2 = fmaf(x4, wb0, fmaf(x5, wb1, fmaf(x6, wb2, fmaf(x7, wb3, b2))));
        b3 = fmaf(x6, wb0, fmaf(x7, wb1, fmaf(x8, wb2, fmaf(x9, wb3, b3))));
      }
    }
  }
}

__global__ __launch_bounds__(256) void k_enc1(
    const void* __restrict__ patch, const void* __restrict__ w,
    const void* __restrict__ bias, float* __restrict__ out,
    const int* __restrict__ flag, int n0)
{
  __shared__ float sW[96];             // 2 co x 3 ci x 16
  __shared__ float sB[2];
  int fl = flag[0];
  int bid = blockIdx.x;
  int rg = bid & 3; int t = bid >> 2;
  int cp = t & 31;  int n = t >> 5;    // n relative to chunk
  int co0 = cp * 2;
  int tid = threadIdx.x;
  if (tid < 96) sW[tid] = ldg_in(w, co0 * 48 + tid, fl);
  if (tid < 2)  sB[tid] = ldg_in(bias, co0 + tid, fl);
  __syncthreads();
  int ty = tid >> 4, txq = tid & 15;
  int oy = rg * 16 + ty;
  int ox0 = txq * 4;
  int iy0 = 2 * oy - 1, cx0 = 2 * ox0 - 1;
  float bv0 = sB[0], bv1 = sB[1];
  float a0 = bv0, a1 = bv0, a2 = bv0, a3 = bv0;
  float b0 = bv1, b1 = bv1, b2 = bv1, b3 = bv1;
  size_t ibase = (size_t)(n0 + n) * 49152;
  if (fl) enc1_loop((const float*)patch + ibase, iy0, cx0, sW, a0, a1, a2, a3, b0, b1, b2, b3);
  else    enc1_loop((const bf16*)patch + ibase, iy0, cx0, sW, a0, a1, a2, a3, b0, b1, b2, b3);
  float* op = out + (size_t)(n * 64 + co0) * 4096 + oy * 64 + ox0;
  op[0] = fmaxf(a0, 0.f); op[1] = fmaxf(a1, 0.f);
  op[2] = fmaxf(a2, 0.f); op[3] = fmaxf(a3, 0.f);
  op += 4096;
  op[0] = fmaxf(b0, 0.f); op[1] = fmaxf(b1, 0.f);
  op[2] = fmaxf(b2, 0.f); op[3] = fmaxf(b3, 0.f);
}

// ---------------- enc2: s2 k4, 64ch 64x64 -> 128ch 32x32; 4 co/thread, padded LDS ----------------
__global__ __launch_bounds__(256) void k_enc2(
    const float* __restrict__ in, const void* __restrict__ w,
    const void* __restrict__ bias, float* __restrict__ out,
    const int* __restrict__ flag)
{
  const int Cin = 64, Cout = 128;
  const int P = 65;
  __shared__ __align__(16) float sW[4096];
  __shared__ float sIn[64 * P];
  int fl = flag[0];
  int bid = blockIdx.x;
  int cp = bid & 31, n = bid >> 5;
  int co0 = cp * 4;
  int tid = threadIdx.x;
  for (int i = tid; i < 4096; i += 256)
    sW[i] = ldg_in(w, co0 * 1024 + i, fl);
  int oy = tid >> 3, ox0 = (tid & 7) << 2;
  float bvA = ldg_in(bias, co0, fl), bvB = ldg_in(bias, co0 + 1, fl);
  float bvC = ldg_in(bias, co0 + 2, fl), bvD = ldg_in(bias, co0 + 3, fl);
  float a0 = bvA, a1 = bvA, a2 = bvA, a3 = bvA;
  float b0 = bvB, b1 = bvB, b2 = bvB, b3 = bvB;
  float c0 = bvC, c1 = bvC, c2 = bvC, c3 = bvC;
  float d0 = bvD, d1 = bvD, d2 = bvD, d3 = bvD;
  int ry0 = 2 * oy - 1;
  int cx0 = 2 * ox0 - 1;
  const float* ip = in + (size_t)n * Cin * 4096;
  for (int ci = 0; ci < Cin; ++ci) {
    __syncthreads();
    {
      const float4* g4 = (const float4*)(ip + ci * 4096);
      #pragma unroll
      for (int j = 0; j < 4; ++j) {
        int i4 = tid + j * 256;
        float4 v = g4[i4];
        int flat = i4 * 4;
        float* dst = sIn + (flat >> 6) * P + (flat & 63);
        dst[0] = v.x; dst[1] = v.y; dst[2] = v.z; dst[3] = v.w;
      }
    }
    __syncthreads();
    #pragma unroll
    for (int ky = 0; ky < 4; ++ky) {
      int iy = ry0 + ky;
      if ((unsigned)iy < 64u) {
        const float* rp = sIn + iy * P;
        float x0 = (cx0 >= 0) ? rp[cx0] : 0.f;
        float x1 = rp[cx0 + 1], x2 = rp[cx0 + 2], x3 = rp[cx0 + 3], x4 = rp[cx0 + 4];
        float x5 = rp[cx0 + 5], x6 = rp[cx0 + 6], x7 = rp[cx0 + 7], x8 = rp[cx0 + 8];
        float x9 = (cx0 + 9 < 64) ? rp[cx0 + 9] : 0.f;
        int wb = ci * 16 + ky * 4;
        {
          float4 wa = *(const float4*)(sW + wb);
          a0 = fmaf(x0, wa.x, fmaf(x1, wa.y, fmaf(x2, wa.z, fmaf(x3, wa.w, a0))));
          a1 = fmaf(x2, wa.x, fmaf(x3, wa.y, fmaf(x4, wa.z, fmaf(x5, wa.w, a1))));
          a2 = fmaf(x4, wa.x, fmaf(x5, wa.y, fmaf(x6, wa.z, fmaf(x7, wa.w, a2))));
          a3 = fmaf(x6, wa.x, fmaf(x7, wa.y, fmaf(x8, wa.z, fmaf(x9, wa.w, a3))));
          float4 wbv = *(const float4*)(sW + wb + 1024);
          b0 = fmaf(x0, wbv.x, fmaf(x1, wbv.y, fmaf(x2, wbv.z, fmaf(x3, wbv.w, b0))));
          b1 = fmaf(x2, wbv.x, fmaf(x3, wbv.y, fmaf(x4, wbv.z, fmaf(x5, wbv.w, b1))));
          b2 = fmaf(x4, wbv.x, fmaf(x5, wbv.y, fmaf(x6, wbv.z, fmaf(x7, wbv.w, b2))));
          b3 = fmaf(x6, wbv.x, fmaf(x7, wbv.y, fmaf(x8, wbv.z, fmaf(x9, wbv.w, b3))));
        }
        {
          float4 wc = *(const float4*)(sW + wb + 2048);
          c0 = fmaf(x0, wc.x, fmaf(x1, wc.y, fmaf(x2, wc.z, fmaf(x3, wc.w, c0))));
          c1 = fmaf(x2, wc.x, fmaf(x3, wc.y, fmaf(x4, wc.z, fmaf(x5, wc.w, c1))));
          c2 = fmaf(x4, wc.x, fmaf(x5, wc.y, fmaf(x6, wc.z, fmaf(x7, wc.w, c2))));
          c3 = fmaf(x6, wc.x, fmaf(x7, wc.y, fmaf(x8, wc.z, fmaf(x9, wc.w, c3))));
          float4 wd = *(const float4*)(sW + wb + 3072);
          d0 = fmaf(x0, wd.x, fmaf(x1, wd.y, fmaf(x2, wd.z, fmaf(x3, wd.w, d0))));
          d1 = fmaf(x2, wd.x, fmaf(x3, wd.y, fmaf(x4, wd.z, fmaf(x5, wd.w, d1))));
          d2 = fmaf(x4, wd.x, fmaf(x5, wd.y, fmaf(x6, wd.z, fmaf(x7, wd.w, d2))));
          d3 = fmaf(x6, wd.x, fmaf(x7, wd.y, fmaf(x8, wd.z, fmaf(x9, wd.w, d3))));
        }
      }
    }
  }
  float* op = out + (size_t)(n * Cout + co0) * 1024 + oy * 32 + ox0;
  op[0] = fmaxf(a0, 0.f); op[1] = fmaxf(a1, 0.f); op[2] = fmaxf(a2, 0.f); op[3] = fmaxf(a3, 0.f);
  op += 1024;
  op[0] = fmaxf(b0, 0.f); op[1] = fmaxf(b1, 0.f); op[2] = fmaxf(b2, 0.f); op[3] = fmaxf(b3, 0.f);
  op += 1024;
  op[0] = fmaxf(c0, 0.f); op[1] = fmaxf(c1, 0.f); op[2] = fmaxf(c2, 0.f); op[3] = fmaxf(c3, 0.f);
  op += 1024;
  op[0] = fmaxf(d0, 0.f); op[1] = fmaxf(d1, 0.f); op[2] = fmaxf(d2, 0.f); op[3] = fmaxf(d3, 0.f);
}

// ---- 3x3 conv s1 p1 @32x32 v3: 256 thr, 4 co/block, 2 co/thread, 4x2 px, padded LDS ----
#define C4(P0, P1, P2, P3, W0, W1, W2) \
  P0 = fmaf(x0, W0, fmaf(x1, W1, fmaf(x2, W2, P0))); \
  P1 = fmaf(x1, W0, fmaf(x2, W1, fmaf(x3, W2, P1))); \
  P2 = fmaf(x2, W0, fmaf(x3, W1, fmaf(x4, W2, P2))); \
  P3 = fmaf(x3, W0, fmaf(x4, W1, fmaf(x5, W2, P3)));

#define ROW_AB(T, KY) \
  C4(A##T##0, A##T##1, A##T##2, A##T##3, wa[3*KY], wa[3*KY+1], wa[3*KY+2]) \
  C4(B##T##0, B##T##1, B##T##2, B##T##3, wb[3*KY], wb[3*KY+1], wb[3*KY+2])

#define C33_LOAD(RP) \
  x0 = (ox0 > 0) ? (RP)[ox0 - 1] : 0.f; \
  x1 = (RP)[ox0]; x2 = (RP)[ox0 + 1]; x3 = (RP)[ox0 + 2]; x4 = (RP)[ox0 + 3]; \
  x5 = (ox0 < 28) ? (RP)[ox0 + 4] : 0.f; \
  if (IN_RELU) { \
    x0 = fmaxf(x0, 0.f); x1 = fmaxf(x1, 0.f); x2 = fmaxf(x2, 0.f); \
    x3 = fmaxf(x3, 0.f); x4 = fmaxf(x4, 0.f); x5 = fmaxf(x5, 0.f); \
  }

#define ST_ROW4(PTR, P0, P1, P2, P3) \
  if (OUT_RELU) { (PTR)[0] = fmaxf(P0, 0.f); (PTR)[1] = fmaxf(P1, 0.f); \
                  (PTR)[2] = fmaxf(P2, 0.f); (PTR)[3] = fmaxf(P3, 0.f); } \
  else { (PTR)[0] = P0; (PTR)[1] = P1; (PTR)[2] = P2; (PTR)[3] = P3; }

template<bool IN_RELU, bool TRANS_W, bool OUT_RELU, bool HAS_BIAS>
__global__ __launch_bounds__(256) void k_conv3x3_v3(
    const float* __restrict__ in, const void* __restrict__ w,
    const void* __restrict__ bias, float* __restrict__ out,
    const int* __restrict__ flag, int Cin, int Cout)
{
  const int HW = 1024;
  const int PP = 33;
  const int PLANE = 32 * PP;
  __shared__ float sW[4608];
  __shared__ float sIn[2 * 1056];
  int fl = flag[0];
  int nq = Cout >> 2;
  int bid = blockIdx.x;
  int qc = bid % nq, n = bid / nq;
  int co0 = qc * 4;
  int tid = threadIdx.x;
  int tot = 4 * Cin * 9;
  for (int i = tid; i < tot; i += 256) {
    int cl = i / (Cin * 9), rem = i % (Cin * 9);
    int ci = rem / 9, k = rem % 9;
    int src = TRANS_W ? ((ci * Cout + co0 + cl) * 9 + (8 - k))
                      : (((co0 + cl) * Cin + ci) * 9 + k);
    sW[i] = ldg_in(w, src, fl);
  }
  int cp = tid >> 7;
  int tt = tid & 127;
  int ty = tt >> 3, tx = tt & 7;
  int oy0 = ty * 2, ox0 = tx * 4;
  int coA = co0 + cp * 2;
  const float* WA = sW + (cp * 2) * Cin * 9;
  const float* WB = WA + Cin * 9;
  float bvA = HAS_BIAS ? ldg_in(bias, coA, fl) : 0.f;
  float bvB = HAS_BIAS ? ldg_in(bias, coA + 1, fl) : 0.f;
  float A00=bvA,A01=bvA,A02=bvA,A03=bvA, A10=bvA,A11=bvA,A12=bvA,A13=bvA;
  float B00=bvB,B01=bvB,B02=bvB,B03=bvB, B10=bvB,B11=bvB,B12=bvB,B13=bvB;
  const float* ip = in + (size_t)n * Cin * HW;
  for (int cb = 0; cb < Cin; cb += 2) {
    __syncthreads();
    {
      const float4* g4 = (const float4*)(ip + cb * HW);
      #pragma unroll
      for (int j = 0; j < 2; ++j) {
        int i4 = tid + j * 256;
        float4 v = g4[i4];
        int flat = i4 * 4;
        int pl = flat >> 10, rem = flat & 1023;
        float* dst = sIn + pl * PLANE + (rem >> 5) * PP + (rem & 31);
        dst[0] = v.x; dst[1] = v.y; dst[2] = v.z; dst[3] = v.w;
      }
    }
    __syncthreads();
    #pragma unroll
    for (int u = 0; u < 2; ++u) {
      int ci = cb + u;
      const float* sP = sIn + u * PLANE;
      const float* wa = WA + ci * 9;
      const float* wb = WB + ci * 9;
      float x0, x1, x2, x3, x4, x5;
      if (oy0 > 0) {
        C33_LOAD(sP + (oy0 - 1) * PP)
        ROW_AB(0, 0)
      }
      { C33_LOAD(sP + oy0 * PP)
        ROW_AB(0, 1) ROW_AB(1, 0) }
      { C33_LOAD(sP + (oy0 + 1) * PP)
        ROW_AB(0, 2) ROW_AB(1, 1) }
      if (oy0 < 30) {
        C33_LOAD(sP + (oy0 + 2) * PP)
        ROW_AB(1, 2)
      }
    }
  }
  float* op = out + (size_t)(n * Cout + coA) * HW + oy0 * 32 + ox0;
  ST_ROW4(op,      A00, A01, A02, A03)
  ST_ROW4(op + 32, A10, A11, A12, A13)
  op += HW;
  ST_ROW4(op,      B00, B01, B02, B03)
  ST_ROW4(op + 32, B10, B11, B12, B13)
}

// ---------------- 1x1 conv @32x32: 4co x 4p register tile ----------------
template<bool ACCUM, bool HAS_BIAS, bool OUT_RELU>
__global__ __launch_bounds__(256) void k_conv1x1_t4(
    const float* __restrict__ in, const void* __restrict__ w,
    const void* __restrict__ bias, float* __restrict__ out,
    const int* __restrict__ flag, int Cin, int Cout)
{
  const int HW = 1024;
  __shared__ float sW[512];
  int fl = flag[0];
  int nq = Cout >> 2;
  int bid = blockIdx.x;
  int qc = bid % nq, n = bid / nq;
  int co0 = qc * 4;
  int tid = threadIdx.x;
  for (int i = tid; i < 4 * Cin; i += 256)
    sW[i] = ldg_in(w, co0 * Cin + i, fl);
  __syncthreads();
  float acc[4][4];
  #pragma unroll
  for (int c = 0; c < 4; ++c) {
    float bv = HAS_BIAS ? ldg_in(bias, co0 + c, fl) : 0.f;
    #pragma unroll
    for (int k = 0; k < 4; ++k) acc[c][k] = bv;
  }
  const float* ip = in + (size_t)n * Cin * HW + tid;
  for (int ci = 0; ci < Cin; ++ci) {
    const float* p = ip + ci * HW;
    float x0 = p[0], x1 = p[256], x2 = p[512], x3 = p[768];
    #pragma unroll
    for (int c = 0; c < 4; ++c) {
      float wv = sW[c * Cin + ci];
      acc[c][0] = fmaf(wv, x0, acc[c][0]);
      acc[c][1] = fmaf(wv, x1, acc[c][1]);
      acc[c][2] = fmaf(wv, x2, acc[c][2]);
      acc[c][3] = fmaf(wv, x3, acc[c][3]);
    }
  }
  #pragma unroll
  for (int c = 0; c < 4; ++c) {
    float* op = out + (size_t)(n * Cout + co0 + c) * HW + tid;
    #pragma unroll
    for (int k = 0; k < 4; ++k) {
      float v = acc[c][k];
      if (ACCUM) v += op[k * 256];
      if (OUT_RELU) v = fmaxf(v, 0.f);
      op[k * 256] = v;
    }
  }
}

// ---- ConvTranspose s2 k4 p1 parity-quad macros ----
#define LOADW16V(BASE) { \
  const float4* w4_ = (const float4*)(BASE); \
  float4 t0_ = w4_[0], t1_ = w4_[1], t2_ = w4_[2], t3_ = w4_[3]; \
  w00 = t0_.x; w01 = t0_.y; w02 = t0_.z; w03 = t0_.w; \
  w10 = t1_.x; w11 = t1_.y; w12 = t1_.z; w13 = t1_.w; \
  w20 = t2_.x; w21 = t2_.y; w22 = t2_.z; w23 = t2_.w; \
  w30 = t3_.x; w31 = t3_.y; w32 = t3_.z; w33 = t3_.w; }

#define CT_J(P00, P01, P10, P11, M0, M1, M2, C0, C1, C2, D0, D1, D2) \
  P00 = fmaf(w11, C1, fmaf(w13, C0, fmaf(w31, M1, fmaf(w33, M0, P00)))); \
  P01 = fmaf(w10, C2, fmaf(w12, C1, fmaf(w30, M2, fmaf(w32, M1, P01)))); \
  P10 = fmaf(w01, D1, fmaf(w03, D0, fmaf(w21, C1, fmaf(w23, C0, P10)))); \
  P11 = fmaf(w00, D2, fmaf(w02, D1, fmaf(w20, C2, fmaf(w22, C1, P11))));

#define DECL16(PX, BV) \
  float PX##A0=BV, PX##A1=BV, PX##A2=BV, PX##A3=BV, \
        PX##B0=BV, PX##B1=BV, PX##B2=BV, PX##B3=BV, \
        PX##C0=BV, PX##C1=BV, PX##C2=BV, PX##C3=BV, \
        PX##D0=BV, PX##D1=BV, PX##D2=BV, PX##D3=BV;

#define CT_CO(PX) \
  CT_J(PX##A0, PX##B0, PX##C0, PX##D0, m0, m1, m2, c0, c1, c2, d0, d1, d2) \
  CT_J(PX##A1, PX##B1, PX##C1, PX##D1, m1, m2, m3, c1, c2, c3, d1, d2, d3) \
  CT_J(PX##A2, PX##B2, PX##C2, PX##D2, m2, m3, m4, c2, c3, c4, d2, d3, d4) \
  CT_J(PX##A3, PX##B3, PX##C3, PX##D3, m3, m4, m5, c3, c4, c5, d3, d4, d5)

#define CT_STORE(PX, PTR, HO) \
  (PTR)[0] = fmaxf(PX##A0, 0.f); (PTR)[1] = fmaxf(PX##B0, 0.f); \
  (PTR)[2] = fmaxf(PX##A1, 0.f); (PTR)[3] = fmaxf(PX##B1, 0.f); \
  (PTR)[4] = fmaxf(PX##A2, 0.f); (PTR)[5] = fmaxf(PX##B2, 0.f); \
  (PTR)[6] = fmaxf(PX##A3, 0.f); (PTR)[7] = fmaxf(PX##B3, 0.f); \
  (PTR)[HO]     = fmaxf(PX##C0, 0.f); (PTR)[HO + 1] = fmaxf(PX##D0, 0.f); \
  (PTR)[HO + 2] = fmaxf(PX##C1, 0.f); (PTR)[HO + 3] = fmaxf(PX##D1, 0.f); \
  (PTR)[HO + 4] = fmaxf(PX##C2, 0.f); (PTR)[HO + 5] = fmaxf(PX##D2, 0.f); \
  (PTR)[HO + 6] = fmaxf(PX##C3, 0.f); (PTR)[HO + 7] = fmaxf(PX##D3, 0.f);

// ---------------- up1: convT s2 k4, 128ch 32x32 -> 64ch 64x64, 4 co/thread, staged input ----
__global__ __launch_bounds__(256) void k_convT_up1(
    const float* __restrict__ in, const void* __restrict__ w,
    const void* __restrict__ bias, float* __restrict__ out,
    const int* __restrict__ flag)
{
  const int Cin = 128, Cout = 64;
  const int PP = 33;
  __shared__ __align__(16) float sW[8192];
  __shared__ float sIn[32 * PP];
  int fl = flag[0];
  int bid = blockIdx.x;
  int cp = bid & 15, n = bid >> 4;
  int co0 = cp * 4;
  int tid = threadIdx.x;
  for (int i = tid; i < 8192; i += 256) {
    int cl = i >> 11, rem = i & 2047;
    int ci = rem >> 4, k = rem & 15;
    sW[i] = ldg_in(w, (ci * Cout + co0 + cl) * 16 + k, fl);
  }
  int qa = tid >> 3;
  int qb0 = (tid & 7) * 4;
  float bv0 = ldg_in(bias, co0, fl), bv1 = ldg_in(bias, co0 + 1, fl);
  float bv2 = ldg_in(bias, co0 + 2, fl), bv3 = ldg_in(bias, co0 + 3, fl);
  DECL16(u, bv0) DECL16(v, bv1) DECL16(y, bv2) DECL16(z, bv3)
  const float* ip = in + (size_t)n * Cin * 1024;
  bool vm = qa >= 1, vd = qa + 1 < 32;
  bool vl = qb0 > 0, vr = qb0 < 28;
  for (int ci = 0; ci < Cin; ++ci) {
    __syncthreads();
    {
      float4 g = ((const float4*)(ip + ci * 1024))[tid];
      float* dst = sIn + (tid >> 3) * PP + (tid & 7) * 4;
      dst[0] = g.x; dst[1] = g.y; dst[2] = g.z; dst[3] = g.w;
    }
    __syncthreads();
    const float* rm = sIn + (qa - 1) * PP;
    const float* rc = sIn + qa * PP;
    const float* rd = sIn + (qa + 1) * PP;
    float m0 = (vm && vl) ? rm[qb0 - 1] : 0.f;
    float m1 = vm ? rm[qb0] : 0.f, m2 = vm ? rm[qb0 + 1] : 0.f;
    float m3 = vm ? rm[qb0 + 2] : 0.f, m4 = vm ? rm[qb0 + 3] : 0.f;
    float m5 = (vm && vr) ? rm[qb0 + 4] : 0.f;
    float c0 = vl ? rc[qb0 - 1] : 0.f;
    float c1 = rc[qb0], c2 = rc[qb0 + 1], c3 = rc[qb0 + 2], c4 = rc[qb0 + 3];
    float c5 = vr ? rc[qb0 + 4] : 0.f;
    float d0 = (vd && vl) ? rd[qb0 - 1] : 0.f;
    float d1 = vd ? rd[qb0] : 0.f, d2 = vd ? rd[qb0 + 1] : 0.f;
    float d3 = vd ? rd[qb0 + 2] : 0.f, d4 = vd ? rd[qb0 + 3] : 0.f;
    float d5 = (vd && vr) ? rd[qb0 + 4] : 0.f;
    float w00, w01, w02, w03, w10, w11, w12, w13, w20, w21, w22, w23, w30, w31, w32, w33;
    { LOADW16V(sW + ci * 16)        CT_CO(u) }
    { LOADW16V(sW + 2048 + ci * 16) CT_CO(v) }
    { LOADW16V(sW + 4096 + ci * 16) CT_CO(y) }
    { LOADW16V(sW + 6144 + ci * 16) CT_CO(z) }
  }
  float* op = out + ((size_t)(n * Cout + co0) * 64 + 2 * qa) * 64 + 2 * qb0;
  CT_STORE(u, op, 64) op += (size_t)64 * 64;
  CT_STORE(v, op, 64) op += (size_t)64 * 64;
  CT_STORE(y, op, 64) op += (size_t)64 * 64;
  CT_STORE(z, op, 64)
}

// ---------------- up2: convT s2 k4, 64ch 64x64 -> 3ch 128x128, all 3 co/thread ----------------
__global__ __launch_bounds__(256) void k_convT_up2(
    const float* __restrict__ in, const void* __restrict__ w,
    const void* __restrict__ bias, float* __restrict__ out,
    const int* __restrict__ flag)
{
  const int Cin = 64;
  __shared__ __align__(16) float sW[3072];
  int fl = flag[0];
  int bid = blockIdx.x;
  int s = bid & 7, n = bid >> 3;
  int tid = threadIdx.x;
  for (int i = tid; i < 3072; i += 256)
    sW[i] = ldg_in(w, i, fl);
  __syncthreads();
  int qa = s * 8 + (tid >> 5);
  int qb0 = (tid & 31) * 2;
  float bp = ldg_in(bias, 0, fl), bq = ldg_in(bias, 1, fl), br = ldg_in(bias, 2, fl);
  float pA0 = bp, pA1 = bp, pB0 = bp, pB1 = bp, pC0 = bp, pC1 = bp, pD0 = bp, pD1 = bp;
  float qA0 = bq, qA1 = bq, qB0_ = bq, qB1 = bq, qC0 = bq, qC1 = bq, qD0 = bq, qD1 = bq;
  float rA0 = br, rA1 = br, rB0 = br, rB1 = br, rC0 = br, rC1 = br, rD0 = br, rD1 = br;
  const float* ip = in + (size_t)n * Cin * 4096;
  bool vm = qa >= 1, vd = qa + 1 < 64;
  bool vl = qb0 > 0, vr = qb0 < 62;
  for (int ci = 0; ci < Cin; ++ci) {
    const float* p = ip + ci * 4096;
    const float* rm = p + (qa - 1) * 64;
    const float* rc = p + qa * 64;
    const float* rd = p + (qa + 1) * 64;
    float m0 = (vm && vl) ? rm[qb0 - 1] : 0.f;
    float m1 = vm ? rm[qb0] : 0.f, m2 = vm ? rm[qb0 + 1] : 0.f;
    float m3 = (vm && vr) ? rm[qb0 + 2] : 0.f;
    float c0 = vl ? rc[qb0 - 1] : 0.f;
    float c1 = rc[qb0], c2 = rc[qb0 + 1];
    float c3 = vr ? rc[qb0 + 2] : 0.f;
    float d0 = (vd && vl) ? rd[qb0 - 1] : 0.f;
    float d1 = vd ? rd[qb0] : 0.f, d2 = vd ? rd[qb0 + 1] : 0.f;
    float d3 = (vd && vr) ? rd[qb0 + 2] : 0.f;
    float w00, w01, w02, w03, w10, w11, w12, w13, w20, w21, w22, w23, w30, w31, w32, w33;
    {
      LOADW16V(sW + ci * 48)
      CT_J(pA0, pB0, pC0, pD0, m0, m1, m2, c0, c1, c2, d0, d1, d2)
      CT_J(pA1, pB1, pC1, pD1, m1, m2, m3, c1, c2, c3, d1, d2, d3)
    }
    {
      LOADW16V(sW + ci * 48 + 16)
      CT_J(qA0, qB0_, qC0, qD0, m0, m1, m2, c0, c1, c2, d0, d1, d2)
      CT_J(qA1, qB1, qC1, qD1, m1, m2, m3, c1, c2, c3, d1, d2, d3)
    }
    {
      LOADW16V(sW + ci * 48 + 32)
      CT_J(rA0, rB0, rC0, rD0, m0, m1, m2, c0, c1, c2, d0, d1, d2)
      CT_J(rA1, rB1, rC1, rD1, m1, m2, m3, c1, c2, c3, d1, d2, d3)
    }
  }
  float* op = out + ((size_t)(n * 3 + 0) * 128 + 2 * qa) * 128 + 2 * qb0;
  op[0] = pA0; op[1] = pB0; op[2] = pA1; op[3] = pB1;
  op[128] = pC0; op[129] = pD0; op[130] = pC1; op[131] = pD1;
  op += (size_t)128 * 128;
  op[0] = qA0; op[1] = qB0_; op[2] = qA1; op[3] = qB1;
  op[128] = qC0; op[129] = qD0; op[130] = qC1; op[131] = qD1;
  op += (size_t)128 * 128;
  op[0] = rA0; op[1] = rB0; op[2] = rA1; op[3] = rB1;
  op[128] = rC0; op[129] = rD0; op[130] = rC1; op[131] = rD1;
}

// ---------------- VQ phase 1: per-chunk argmin (256 codebook rows per chunk) ----------------
// dist formula identical to monolithic version (zz + sEE[k] - 2*dot) -> fp values
// bit-identical; chunk-ascending combine in phase 2 preserves global first-min exactly.
__global__ __launch_bounds__(256) void k_vq1(
    const float* __restrict__ z, const void* __restrict__ emb,
    const int* __restrict__ flag, float* __restrict__ distb, float* __restrict__ idxb)
{
  const int PE = 65;
  __shared__ float sE[128 * PE];
  __shared__ float sEE[128];
  int fl = flag[0];
  int tid = threadIdx.x;
  int bid = blockIdx.x;
  int ch = bid & 3, vb = bid >> 2;
  int n = vb * 256 + tid;
  int nb = n >> 10, p = n & 1023;
  const float* zp = z + nb * 65536 + p;
  float zv[64];
  float zz = 0.f;
  #pragma unroll
  for (int d = 0; d < 64; ++d) { zv[d] = zp[d * 1024]; zz = fmaf(zv[d], zv[d], zz); }
  float best = 3.4e38f; int bidx = ch * 256;
  for (int kb = ch * 2; kb < ch * 2 + 2; ++kb) {
    __syncthreads();
    for (int i = tid; i < 8192; i += 256)
      sE[(i >> 6) * PE + (i & 63)] = ldg_in(emb, kb * 8192 + i, fl);
    __syncthreads();
    if (tid < 128) {
      const float* ep = sE + tid * PE;
      float s = 0.f;
      #pragma unroll
      for (int d = 0; d < 64; ++d) s = fmaf(ep[d], ep[d], s);
      sEE[tid] = s;
    }
    __syncthreads();
    for (int k = 0; k < 128; ++k) {
      const float* ep = sE + k * PE;
      float dot = 0.f;
      #pragma unroll
      for (int d = 0; d < 64; ++d) dot = fmaf(zv[d], ep[d], dot);
      float dist = zz + sEE[k] - 2.f * dot;
      if (dist < best) { best = dist; bidx = kb * 128 + k; }  // strict <: first min wins
    }
  }
  distb[ch * 65536 + n] = best;
  idxb[ch * 65536 + n] = (float)bidx;
}

// ---------------- VQ phase 2: combine chunks, gather zq, loss partials ----------------
__global__ __launch_bounds__(256) void k_vq2(
    const float* __restrict__ z, const void* __restrict__ emb,
    const int* __restrict__ flag, const float* __restrict__ distb,
    const float* __restrict__ idxb, float* __restrict__ zq,
    float* __restrict__ idx_out, float* __restrict__ lossp, int lossbase)
{
  __shared__ float wsum[4];
  int fl = flag[0];
  int tid = threadIdx.x;
  int n = blockIdx.x * 256 + tid;
  float best = distb[n];
  int bidx = (int)idxb[n];
  #pragma unroll
  for (int c = 1; c < 4; ++c) {
    float d = distb[c * 65536 + n];
    if (d < best) { best = d; bidx = (int)idxb[c * 65536 + n]; }  // earlier chunk wins ties
  }
  idx_out[n] = (float)bidx;
  int nb = n >> 10, p = n & 1023;
  const float* zp = z + nb * 65536 + p;
  float* qp = zq + nb * 65536 + p;
  float ls = 0.f;
  #pragma unroll
  for (int d = 0; d < 64; ++d) {
    float e = ldg_in(emb, bidx * 64 + d, fl);
    float zvd = zp[d * 1024];
    qp[d * 1024] = e;                  // in-place over z: thread owns its column
    float df = e - zvd;
    ls = fmaf(df, df, ls);
  }
  #pragma unroll
  for (int off = 32; off > 0; off >>= 1) ls += __shfl_down(ls, off);
  if ((tid & 63) == 0) wsum[tid >> 6] = ls;
  __syncthreads();
  if (tid == 0) lossp[lossbase + blockIdx.x] = wsum[0] + wsum[1] + wsum[2] + wsum[3];
}

__global__ void k_loss_final(const float* __restrict__ lossp, float* __restrict__ out) {
  if (threadIdx.x == 0 && blockIdx.x == 0) {
    float s = 0.f;
    for (int i = 0; i < 256; ++i) s += lossp[i];
    float L = s * (1.f / 4194304.f);
    out[R_RECON + 0] = L;
    out[R_RECON + 1] = L;
  }
}

extern "C" void kernel_launch(void* const* d_in, const int* in_sizes, int n_in,
                              void* d_out, int out_size, void* d_ws, size_t ws_size,
                              hipStream_t stream)
{
  float* out = (float*)d_out;          // fp32 output (established R8-R10)

  // ws: LOSSP[256] | FLAG | VQ dist[4*65536] | VQ idx[4*65536] | arena
  float* F = (float*)d_ws;
  float* LOSSP = F;
  int* FLAG = (int*)(F + 256);
  float* VQD = F + 272;
  float* VQI = VQD + 262144;
  float* A = VQI + 262144;

  int Bc = 64;
  while (Bc > 1 && 4ull * (272ull + 524288ull + (size_t)Bc * 393216ull) > ws_size) Bc >>= 1;
  float* H1 = A;
  float* H2 = A + (size_t)Bc * 262144;
  float* H3 = A;
  float* T  = A + (size_t)Bc * 131072;
  float* Z  = A + (size_t)Bc * 163840;
  float* D1 = H2;
  float* D2 = A;

  const void* patch = d_in[0];
  const void* ew1 = d_in[1];  const void* eb1 = d_in[2];
  const void* ew2 = d_in[3];  const void* eb2 = d_in[4];
  const void* ew3 = d_in[5];  const void* eb3 = d_in[6];
  const void* er1a = d_in[7]; const void* er1b = d_in[8];
  const void* er2a = d_in[9]; const void* er2b = d_in[10];
  const void* pqw = d_in[11]; const void* pqb = d_in[12];
  const void* emb = d_in[13];
  const void* dw1 = d_in[14]; const void* db1 = d_in[15];
  const void* dr1a = d_in[16]; const void* dr1b = d_in[17];
  const void* dr2a = d_in[18]; const void* dr2b = d_in[19];
  const void* dw2 = d_in[20]; const void* db2 = d_in[21];
  const void* dw3 = d_in[22]; const void* db3 = d_in[23];

  k_detect<<<1, 256, 0, stream>>>((const u16*)patch, FLAG);

  int NC = 64 / Bc;
  for (int c = 0; c < NC; ++c) {
    int b0 = c * Bc;

    // ---- encoder ----
    k_enc1<<<Bc * 128, 256, 0, stream>>>(patch, ew1, eb1, H1, FLAG, b0);
    k_enc2<<<Bc * 32, 256, 0, stream>>>(H1, ew2, eb2, H2, FLAG);
    k_conv3x3_v3<false, false, false, true><<<Bc * 32, 256, 0, stream>>>(H2, ew3, eb3, H3, FLAG, 128, 128);
    k_conv3x3_v3<true, false, true, false><<<Bc * 8, 256, 0, stream>>>(H3, er1a, nullptr, T, FLAG, 128, 32);
    k_conv1x1_t4<true, false, false><<<Bc * 32, 256, 0, stream>>>(T, er1b, nullptr, H3, FLAG, 32, 128);
    k_conv3x3_v3<true, false, true, false><<<Bc * 8, 256, 0, stream>>>(H3, er2a, nullptr, T, FLAG, 128, 32);
    k_conv1x1_t4<true, false, true><<<Bc * 32, 256, 0, stream>>>(T, er2b, nullptr, H3, FLAG, 32, 128);
    k_conv1x1_t4<false, true, false><<<Bc * 16, 256, 0, stream>>>(H3, pqw, pqb, Z, FLAG, 128, 64);

    // ---- VQ (2-phase: codebook-split argmin, then combine + gather + loss) ----
    k_vq1<<<Bc * 16, 256, 0, stream>>>(Z, emb, FLAG, VQD, VQI);
    k_vq2<<<Bc * 4, 256, 0, stream>>>(Z, emb, FLAG, VQD, VQI, Z,
                                      out + R_RECON + 2 + (size_t)b0 * 1024, LOSSP, b0 * 4);

    // ---- decoder ----
    k_conv3x3_v3<false, true, false, true><<<Bc * 32, 256, 0, stream>>>(Z, dw1, db1, D1, FLAG, 64, 128);
    k_conv3x3_v3<true, false, true, false><<<Bc * 8, 256, 0, stream>>>(D1, dr1a, nullptr, T, FLAG, 128, 32);
    k_conv1x1_t4<true, false, false><<<Bc * 32, 256, 0, stream>>>(T, dr1b, nullptr, D1, FLAG, 32, 128);
    k_conv3x3_v3<true, false, true, false><<<Bc * 8, 256, 0, stream>>>(D1, dr2a, nullptr, T, FLAG, 128, 32);
    k_conv1x1_t4<true, false, true><<<Bc * 32, 256, 0, stream>>>(T, dr2b, nullptr, D1, FLAG, 32, 128);
    k_convT_up1<<<Bc * 16, 256, 0, stream>>>(D1, dw2, db2, D2, FLAG);
    k_convT_up2<<<Bc * 8, 256, 0, stream>>>(D2, dw3, db3, out + (size_t)b0 * 49152, FLAG);
  }

  k_loss_final<<<1, 64, 0, stream>>>(LOSSP, out);
}

// Round 20
// 2125.177 us; speedup vs baseline: 7.7379x; 1.0529x over previous
//
#include <hip/hip_runtime.h>
#include <hip/hip_bf16.h>

typedef __hip_bfloat16 bf16;
typedef unsigned short u16;

#define R_RECON 3145728
#define N_IDX   65536

__device__ __forceinline__ float ldg_in(const void* p, int i, int fl) {
  return fl ? ((const float*)p)[i] : __bfloat162float(((const bf16*)p)[i]);
}
__device__ __forceinline__ float cvt(float v) { return v; }
__device__ __forceinline__ float cvt(bf16 v) { return __bfloat162float(v); }

__global__ __launch_bounds__(256) void k_detect(const u16* __restrict__ p, int* __restrict__ flag) {
  __shared__ int s;
  if (threadIdx.x == 0) s = 0;
  __syncthreads();
  for (int i = threadIdx.x; i < 4096; i += 256) {
    float f = __uint_as_float(((unsigned)p[i]) << 16);
    if (!(fabsf(f) < 16384.f)) atomicOr(&s, 1);
  }
  __syncthreads();
  if (threadIdx.x == 0) flag[0] = s;
}

// ---------------- enc1: s2 k4 p1, 3ch 128x128 -> 64ch 64x64; 2 co/thread, 4-wide ox ----
template<typename T>
__device__ __forceinline__ void enc1_loop(
    const T* __restrict__ ip, int iy0, int cx0, const float* sW,
    float& a0, float& a1, float& a2, float& a3,
    float& b0, float& b1, float& b2, float& b3)
{
  #pragma unroll
  for (int ci = 0; ci < 3; ++ci) {
    const T* cp = ip + ci * 16384;
    #pragma unroll
    for (int ky = 0; ky < 4; ++ky) {
      int iy = iy0 + ky;
      if ((unsigned)iy < 128u) {
        const T* rp = cp + iy * 128;
        float x0 = (cx0 >= 0) ? cvt(rp[cx0]) : 0.f;
        float x1 = cvt(rp[cx0 + 1]), x2 = cvt(rp[cx0 + 2]);
        float x3 = cvt(rp[cx0 + 3]), x4 = cvt(rp[cx0 + 4]);
        float x5 = cvt(rp[cx0 + 5]), x6 = cvt(rp[cx0 + 6]);
        float x7 = cvt(rp[cx0 + 7]), x8 = cvt(rp[cx0 + 8]);
        float x9 = (cx0 + 9 < 128) ? cvt(rp[cx0 + 9]) : 0.f;
        const float* WA = sW + ci * 16 + ky * 4;
        float wa0 = WA[0], wa1 = WA[1], wa2 = WA[2], wa3 = WA[3];
        a0 = fmaf(x0, wa0, fmaf(x1, wa1, fmaf(x2, wa2, fmaf(x3, wa3, a0))));
        a1 = fmaf(x2, wa0, fmaf(x3, wa1, fmaf(x4, wa2, fmaf(x5, wa3, a1))));
        a2 = fmaf(x4, wa0, fmaf(x5, wa1, fmaf(x6, wa2, fmaf(x7, wa3, a2))));
        a3 = fmaf(x6, wa0, fmaf(x7, wa1, fmaf(x8, wa2, fmaf(x9, wa3, a3))));
        const float* WB = WA + 48;
        float wb0 = WB[0], wb1 = WB[1], wb2 = WB[2], wb3 = WB[3];
        b0 = fmaf(x0, wb0, fmaf(x1, wb1, fmaf(x2, wb2, fmaf(x3, wb3, b0))));
        b1 = fmaf(x2, wb0, fmaf(x3, wb1, fmaf(x4, wb2, fmaf(x5, wb3, b1))));
        b2 = fmaf(x4, wb0, fmaf(x5, wb1, fmaf(x6, wb2, fmaf(x7, wb3, b2))));
        b3 = fmaf(x6, wb0, fmaf(x7, wb1, fmaf(x8, wb2, fmaf(x9, wb3, b3))));
      }
    }
  }
}

__global__ __launch_bounds__(256) void k_enc1(
    const void* __restrict__ patch, const void* __restrict__ w,
    const void* __restrict__ bias, float* __restrict__ out,
    const int* __restrict__ flag, int n0)
{
  __shared__ float sW[96];
  __shared__ float sB[2];
  int fl = flag[0];
  int bid = blockIdx.x;
  int rg = bid & 3; int t = bid >> 2;
  int cp = t & 31;  int n = t >> 5;
  int co0 = cp * 2;
  int tid = threadIdx.x;
  if (tid < 96) sW[tid] = ldg_in(w, co0 * 48 + tid, fl);
  if (tid < 2)  sB[tid] = ldg_in(bias, co0 + tid, fl);
  __syncthreads();
  int ty = tid >> 4, txq = tid & 15;
  int oy = rg * 16 + ty;
  int ox0 = txq * 4;
  int iy0 = 2 * oy - 1, cx0 = 2 * ox0 - 1;
  float bv0 = sB[0], bv1 = sB[1];
  float a0 = bv0, a1 = bv0, a2 = bv0, a3 = bv0;
  float b0 = bv1, b1 = bv1, b2 = bv1, b3 = bv1;
  size_t ibase = (size_t)(n0 + n) * 49152;
  if (fl) enc1_loop((const float*)patch + ibase, iy0, cx0, sW, a0, a1, a2, a3, b0, b1, b2, b3);
  else    enc1_loop((const bf16*)patch + ibase, iy0, cx0, sW, a0, a1, a2, a3, b0, b1, b2, b3);
  float* op = out + (size_t)(n * 64 + co0) * 4096 + oy * 64 + ox0;
  op[0] = fmaxf(a0, 0.f); op[1] = fmaxf(a1, 0.f);
  op[2] = fmaxf(a2, 0.f); op[3] = fmaxf(a3, 0.f);
  op += 4096;
  op[0] = fmaxf(b0, 0.f); op[1] = fmaxf(b1, 0.f);
  op[2] = fmaxf(b2, 0.f); op[3] = fmaxf(b3, 0.f);
}

// ---------------- enc2: s2 k4, 64ch 64x64 -> 128ch 32x32; 4 co/thread, padded LDS ----------------
__global__ __launch_bounds__(256) void k_enc2(
    const float* __restrict__ in, const void* __restrict__ w,
    const void* __restrict__ bias, float* __restrict__ out,
    const int* __restrict__ flag)
{
  const int Cin = 64, Cout = 128;
  const int P = 65;
  __shared__ __align__(16) float sW[4096];
  __shared__ float sIn[64 * P];
  int fl = flag[0];
  int bid = blockIdx.x;
  int cp = bid & 31, n = bid >> 5;
  int co0 = cp * 4;
  int tid = threadIdx.x;
  for (int i = tid; i < 4096; i += 256)
    sW[i] = ldg_in(w, co0 * 1024 + i, fl);
  int oy = tid >> 3, ox0 = (tid & 7) << 2;
  float bvA = ldg_in(bias, co0, fl), bvB = ldg_in(bias, co0 + 1, fl);
  float bvC = ldg_in(bias, co0 + 2, fl), bvD = ldg_in(bias, co0 + 3, fl);
  float a0 = bvA, a1 = bvA, a2 = bvA, a3 = bvA;
  float b0 = bvB, b1 = bvB, b2 = bvB, b3 = bvB;
  float c0 = bvC, c1 = bvC, c2 = bvC, c3 = bvC;
  float d0 = bvD, d1 = bvD, d2 = bvD, d3 = bvD;
  int ry0 = 2 * oy - 1;
  int cx0 = 2 * ox0 - 1;
  const float* ip = in + (size_t)n * Cin * 4096;
  for (int ci = 0; ci < Cin; ++ci) {
    __syncthreads();
    {
      const float4* g4 = (const float4*)(ip + ci * 4096);
      #pragma unroll
      for (int j = 0; j < 4; ++j) {
        int i4 = tid + j * 256;
        float4 v = g4[i4];
        int flat = i4 * 4;
        float* dst = sIn + (flat >> 6) * P + (flat & 63);
        dst[0] = v.x; dst[1] = v.y; dst[2] = v.z; dst[3] = v.w;
      }
    }
    __syncthreads();
    #pragma unroll
    for (int ky = 0; ky < 4; ++ky) {
      int iy = ry0 + ky;
      if ((unsigned)iy < 64u) {
        const float* rp = sIn + iy * P;
        float x0 = (cx0 >= 0) ? rp[cx0] : 0.f;
        float x1 = rp[cx0 + 1], x2 = rp[cx0 + 2], x3 = rp[cx0 + 3], x4 = rp[cx0 + 4];
        float x5 = rp[cx0 + 5], x6 = rp[cx0 + 6], x7 = rp[cx0 + 7], x8 = rp[cx0 + 8];
        float x9 = (cx0 + 9 < 64) ? rp[cx0 + 9] : 0.f;
        int wb = ci * 16 + ky * 4;
        {
          float4 wa = *(const float4*)(sW + wb);
          a0 = fmaf(x0, wa.x, fmaf(x1, wa.y, fmaf(x2, wa.z, fmaf(x3, wa.w, a0))));
          a1 = fmaf(x2, wa.x, fmaf(x3, wa.y, fmaf(x4, wa.z, fmaf(x5, wa.w, a1))));
          a2 = fmaf(x4, wa.x, fmaf(x5, wa.y, fmaf(x6, wa.z, fmaf(x7, wa.w, a2))));
          a3 = fmaf(x6, wa.x, fmaf(x7, wa.y, fmaf(x8, wa.z, fmaf(x9, wa.w, a3))));
          float4 wbv = *(const float4*)(sW + wb + 1024);
          b0 = fmaf(x0, wbv.x, fmaf(x1, wbv.y, fmaf(x2, wbv.z, fmaf(x3, wbv.w, b0))));
          b1 = fmaf(x2, wbv.x, fmaf(x3, wbv.y, fmaf(x4, wbv.z, fmaf(x5, wbv.w, b1))));
          b2 = fmaf(x4, wbv.x, fmaf(x5, wbv.y, fmaf(x6, wbv.z, fmaf(x7, wbv.w, b2))));
          b3 = fmaf(x6, wbv.x, fmaf(x7, wbv.y, fmaf(x8, wbv.z, fmaf(x9, wbv.w, b3))));
        }
        {
          float4 wc = *(const float4*)(sW + wb + 2048);
          c0 = fmaf(x0, wc.x, fmaf(x1, wc.y, fmaf(x2, wc.z, fmaf(x3, wc.w, c0))));
          c1 = fmaf(x2, wc.x, fmaf(x3, wc.y, fmaf(x4, wc.z, fmaf(x5, wc.w, c1))));
          c2 = fmaf(x4, wc.x, fmaf(x5, wc.y, fmaf(x6, wc.z, fmaf(x7, wc.w, c2))));
          c3 = fmaf(x6, wc.x, fmaf(x7, wc.y, fmaf(x8, wc.z, fmaf(x9, wc.w, c3))));
          float4 wd = *(const float4*)(sW + wb + 3072);
          d0 = fmaf(x0, wd.x, fmaf(x1, wd.y, fmaf(x2, wd.z, fmaf(x3, wd.w, d0))));
          d1 = fmaf(x2, wd.x, fmaf(x3, wd.y, fmaf(x4, wd.z, fmaf(x5, wd.w, d1))));
          d2 = fmaf(x4, wd.x, fmaf(x5, wd.y, fmaf(x6, wd.z, fmaf(x7, wd.w, d2))));
          d3 = fmaf(x6, wd.x, fmaf(x7, wd.y, fmaf(x8, wd.z, fmaf(x9, wd.w, d3))));
        }
      }
    }
  }
  float* op = out + (size_t)(n * Cout + co0) * 1024 + oy * 32 + ox0;
  op[0] = fmaxf(a0, 0.f); op[1] = fmaxf(a1, 0.f); op[2] = fmaxf(a2, 0.f); op[3] = fmaxf(a3, 0.f);
  op += 1024;
  op[0] = fmaxf(b0, 0.f); op[1] = fmaxf(b1, 0.f); op[2] = fmaxf(b2, 0.f); op[3] = fmaxf(b3, 0.f);
  op += 1024;
  op[0] = fmaxf(c0, 0.f); op[1] = fmaxf(c1, 0.f); op[2] = fmaxf(c2, 0.f); op[3] = fmaxf(c3, 0.f);
  op += 1024;
  op[0] = fmaxf(d0, 0.f); op[1] = fmaxf(d1, 0.f); op[2] = fmaxf(d2, 0.f); op[3] = fmaxf(d3, 0.f);
}

// ---- 3x3 conv s1 p1 @32x32 v4: 1 row x 8 px per thread (stride-1 rows -> conflict-free),
//      4 co/block, 2 co/thread, padded LDS. Chain order per output: ky asc, kx asc (bit-identical).
#define LOAD10(RP) \
  x0 = (ox0 > 0) ? (RP)[ox0 - 1] : 0.f; \
  x1 = (RP)[ox0];     x2 = (RP)[ox0 + 1]; x3 = (RP)[ox0 + 2]; x4 = (RP)[ox0 + 3]; \
  x5 = (RP)[ox0 + 4]; x6 = (RP)[ox0 + 5]; x7 = (RP)[ox0 + 6]; x8 = (RP)[ox0 + 7]; \
  x9 = (ox0 < 24) ? (RP)[ox0 + 8] : 0.f; \
  if (IN_RELU) { \
    x0 = fmaxf(x0, 0.f); x1 = fmaxf(x1, 0.f); x2 = fmaxf(x2, 0.f); x3 = fmaxf(x3, 0.f); \
    x4 = fmaxf(x4, 0.f); x5 = fmaxf(x5, 0.f); x6 = fmaxf(x6, 0.f); x7 = fmaxf(x7, 0.f); \
    x8 = fmaxf(x8, 0.f); x9 = fmaxf(x9, 0.f); \
  }

#define C8(PX, W0, W1, W2) \
  PX##0 = fmaf(x0, W0, fmaf(x1, W1, fmaf(x2, W2, PX##0))); \
  PX##1 = fmaf(x1, W0, fmaf(x2, W1, fmaf(x3, W2, PX##1))); \
  PX##2 = fmaf(x2, W0, fmaf(x3, W1, fmaf(x4, W2, PX##2))); \
  PX##3 = fmaf(x3, W0, fmaf(x4, W1, fmaf(x5, W2, PX##3))); \
  PX##4 = fmaf(x4, W0, fmaf(x5, W1, fmaf(x6, W2, PX##4))); \
  PX##5 = fmaf(x5, W0, fmaf(x6, W1, fmaf(x7, W2, PX##5))); \
  PX##6 = fmaf(x6, W0, fmaf(x7, W1, fmaf(x8, W2, PX##6))); \
  PX##7 = fmaf(x7, W0, fmaf(x8, W1, fmaf(x9, W2, PX##7)));

#define ROW8_AB(KY) \
  C8(A, wa[3*KY], wa[3*KY+1], wa[3*KY+2]) \
  C8(B, wb[3*KY], wb[3*KY+1], wb[3*KY+2])

template<bool IN_RELU, bool TRANS_W, bool OUT_RELU, bool HAS_BIAS>
__global__ __launch_bounds__(256) void k_conv3x3_v4(
    const float* __restrict__ in, const void* __restrict__ w,
    const void* __restrict__ bias, float* __restrict__ out,
    const int* __restrict__ flag, int Cin, int Cout)
{
  const int HW = 1024;
  const int PP = 33;
  const int PLANE = 32 * PP;
  __shared__ float sW[4608];           // 4 co x Cin x 9, Cin<=128
  __shared__ float sIn[2 * 1056];
  int fl = flag[0];
  int nq = Cout >> 2;
  int bid = blockIdx.x;
  int qc = bid % nq, n = bid / nq;
  int co0 = qc * 4;
  int tid = threadIdx.x;
  int tot = 4 * Cin * 9;
  for (int i = tid; i < tot; i += 256) {
    int cl = i / (Cin * 9), rem = i % (Cin * 9);
    int ci = rem / 9, k = rem % 9;
    int src = TRANS_W ? ((ci * Cout + co0 + cl) * 9 + (8 - k))
                      : (((co0 + cl) * Cin + ci) * 9 + k);
    sW[i] = ldg_in(w, src, fl);
  }
  int cp = tid >> 7;                   // co-pair sel
  int tt = tid & 127;
  int ty = tt >> 2;                    // output row 0..31 (stride-1 across lanes)
  int tx = tt & 3;
  int ox0 = tx * 8;
  int coA = co0 + cp * 2;
  const float* WA = sW + (cp * 2) * Cin * 9;
  const float* WB = WA + Cin * 9;
  float bvA = HAS_BIAS ? ldg_in(bias, coA, fl) : 0.f;
  float bvB = HAS_BIAS ? ldg_in(bias, coA + 1, fl) : 0.f;
  float A0=bvA,A1=bvA,A2=bvA,A3=bvA,A4=bvA,A5=bvA,A6=bvA,A7=bvA;
  float B0=bvB,B1=bvB,B2=bvB,B3=bvB,B4=bvB,B5=bvB,B6=bvB,B7=bvB;
  const float* ip = in + (size_t)n * Cin * HW;
  for (int cb = 0; cb < Cin; cb += 2) {
    __syncthreads();
    {
      const float4* g4 = (const float4*)(ip + cb * HW);
      #pragma unroll
      for (int j = 0; j < 2; ++j) {
        int i4 = tid + j * 256;
        float4 v = g4[i4];
        int flat = i4 * 4;
        int pl = flat >> 10, rem = flat & 1023;
        float* dst = sIn + pl * PLANE + (rem >> 5) * PP + (rem & 31);
        dst[0] = v.x; dst[1] = v.y; dst[2] = v.z; dst[3] = v.w;
      }
    }
    __syncthreads();
    #pragma unroll
    for (int u = 0; u < 2; ++u) {
      int ci = cb + u;
      const float* sP = sIn + u * PLANE;
      const float* wa = WA + ci * 9;
      const float* wb = WB + ci * 9;
      float x0, x1, x2, x3, x4, x5, x6, x7, x8, x9;
      if (ty > 0) {                    // iy = ty-1 -> ky0
        LOAD10(sP + (ty - 1) * PP)
        ROW8_AB(0)
      }
      {                                // iy = ty -> ky1
        LOAD10(sP + ty * PP)
        ROW8_AB(1)
      }
      if (ty < 31) {                   // iy = ty+1 -> ky2
        LOAD10(sP + (ty + 1) * PP)
        ROW8_AB(2)
      }
    }
  }
  float* op = out + (size_t)(n * Cout + coA) * HW + ty * 32 + ox0;
  if (OUT_RELU) {
    op[0] = fmaxf(A0, 0.f); op[1] = fmaxf(A1, 0.f); op[2] = fmaxf(A2, 0.f); op[3] = fmaxf(A3, 0.f);
    op[4] = fmaxf(A4, 0.f); op[5] = fmaxf(A5, 0.f); op[6] = fmaxf(A6, 0.f); op[7] = fmaxf(A7, 0.f);
    op += HW;
    op[0] = fmaxf(B0, 0.f); op[1] = fmaxf(B1, 0.f); op[2] = fmaxf(B2, 0.f); op[3] = fmaxf(B3, 0.f);
    op[4] = fmaxf(B4, 0.f); op[5] = fmaxf(B5, 0.f); op[6] = fmaxf(B6, 0.f); op[7] = fmaxf(B7, 0.f);
  } else {
    op[0] = A0; op[1] = A1; op[2] = A2; op[3] = A3;
    op[4] = A4; op[5] = A5; op[6] = A6; op[7] = A7;
    op += HW;
    op[0] = B0; op[1] = B1; op[2] = B2; op[3] = B3;
    op[4] = B4; op[5] = B5; op[6] = B6; op[7] = B7;
  }
}

// ---------------- 1x1 conv @32x32: 4co x 4p register tile ----------------
template<bool ACCUM, bool HAS_BIAS, bool OUT_RELU>
__global__ __launch_bounds__(256) void k_conv1x1_t4(
    const float* __restrict__ in, const void* __restrict__ w,
    const void* __restrict__ bias, float* __restrict__ out,
    const int* __restrict__ flag, int Cin, int Cout)
{
  const int HW = 1024;
  __shared__ float sW[512];
  int fl = flag[0];
  int nq = Cout >> 2;
  int bid = blockIdx.x;
  int qc = bid % nq, n = bid / nq;
  int co0 = qc * 4;
  int tid = threadIdx.x;
  for (int i = tid; i < 4 * Cin; i += 256)
    sW[i] = ldg_in(w, co0 * Cin + i, fl);
  __syncthreads();
  float acc[4][4];
  #pragma unroll
  for (int c = 0; c < 4; ++c) {
    float bv = HAS_BIAS ? ldg_in(bias, co0 + c, fl) : 0.f;
    #pragma unroll
    for (int k = 0; k < 4; ++k) acc[c][k] = bv;
  }
  const float* ip = in + (size_t)n * Cin * HW + tid;
  for (int ci = 0; ci < Cin; ++ci) {
    const float* p = ip + ci * HW;
    float x0 = p[0], x1 = p[256], x2 = p[512], x3 = p[768];
    #pragma unroll
    for (int c = 0; c < 4; ++c) {
      float wv = sW[c * Cin + ci];
      acc[c][0] = fmaf(wv, x0, acc[c][0]);
      acc[c][1] = fmaf(wv, x1, acc[c][1]);
      acc[c][2] = fmaf(wv, x2, acc[c][2]);
      acc[c][3] = fmaf(wv, x3, acc[c][3]);
    }
  }
  #pragma unroll
  for (int c = 0; c < 4; ++c) {
    float* op = out + (size_t)(n * Cout + co0 + c) * HW + tid;
    #pragma unroll
    for (int k = 0; k < 4; ++k) {
      float v = acc[c][k];
      if (ACCUM) v += op[k * 256];
      if (OUT_RELU) v = fmaxf(v, 0.f);
      op[k * 256] = v;
    }
  }
}

// ---- ConvTranspose s2 k4 p1 parity-quad macros ----
#define LOADW16V(BASE) { \
  const float4* w4_ = (const float4*)(BASE); \
  float4 t0_ = w4_[0], t1_ = w4_[1], t2_ = w4_[2], t3_ = w4_[3]; \
  w00 = t0_.x; w01 = t0_.y; w02 = t0_.z; w03 = t0_.w; \
  w10 = t1_.x; w11 = t1_.y; w12 = t1_.z; w13 = t1_.w; \
  w20 = t2_.x; w21 = t2_.y; w22 = t2_.z; w23 = t2_.w; \
  w30 = t3_.x; w31 = t3_.y; w32 = t3_.z; w33 = t3_.w; }

#define CT_J(P00, P01, P10, P11, M0, M1, M2, C0, C1, C2, D0, D1, D2) \
  P00 = fmaf(w11, C1, fmaf(w13, C0, fmaf(w31, M1, fmaf(w33, M0, P00)))); \
  P01 = fmaf(w10, C2, fmaf(w12, C1, fmaf(w30, M2, fmaf(w32, M1, P01)))); \
  P10 = fmaf(w01, D1, fmaf(w03, D0, fmaf(w21, C1, fmaf(w23, C0, P10)))); \
  P11 = fmaf(w00, D2, fmaf(w02, D1, fmaf(w20, C2, fmaf(w22, C1, P11))));

#define DECL16(PX, BV) \
  float PX##A0=BV, PX##A1=BV, PX##A2=BV, PX##A3=BV, \
        PX##B0=BV, PX##B1=BV, PX##B2=BV, PX##B3=BV, \
        PX##C0=BV, PX##C1=BV, PX##C2=BV, PX##C3=BV, \
        PX##D0=BV, PX##D1=BV, PX##D2=BV, PX##D3=BV;

#define CT_CO(PX) \
  CT_J(PX##A0, PX##B0, PX##C0, PX##D0, m0, m1, m2, c0, c1, c2, d0, d1, d2) \
  CT_J(PX##A1, PX##B1, PX##C1, PX##D1, m1, m2, m3, c1, c2, c3, d1, d2, d3) \
  CT_J(PX##A2, PX##B2, PX##C2, PX##D2, m2, m3, m4, c2, c3, c4, d2, d3, d4) \
  CT_J(PX##A3, PX##B3, PX##C3, PX##D3, m3, m4, m5, c3, c4, c5, d3, d4, d5)

#define CT_STORE(PX, PTR, HO) \
  (PTR)[0] = fmaxf(PX##A0, 0.f); (PTR)[1] = fmaxf(PX##B0, 0.f); \
  (PTR)[2] = fmaxf(PX##A1, 0.f); (PTR)[3] = fmaxf(PX##B1, 0.f); \
  (PTR)[4] = fmaxf(PX##A2, 0.f); (PTR)[5] = fmaxf(PX##B2, 0.f); \
  (PTR)[6] = fmaxf(PX##A3, 0.f); (PTR)[7] = fmaxf(PX##B3, 0.f); \
  (PTR)[HO]     = fmaxf(PX##C0, 0.f); (PTR)[HO + 1] = fmaxf(PX##D0, 0.f); \
  (PTR)[HO + 2] = fmaxf(PX##C1, 0.f); (PTR)[HO + 3] = fmaxf(PX##D1, 0.f); \
  (PTR)[HO + 4] = fmaxf(PX##C2, 0.f); (PTR)[HO + 5] = fmaxf(PX##D2, 0.f); \
  (PTR)[HO + 6] = fmaxf(PX##C3, 0.f); (PTR)[HO + 7] = fmaxf(PX##D3, 0.f);

// ---------------- up1: convT s2 k4, 128ch 32x32 -> 64ch 64x64, 4 co/thread, staged input ----
__global__ __launch_bounds__(256) void k_convT_up1(
    const float* __restrict__ in, const void* __restrict__ w,
    const void* __restrict__ bias, float* __restrict__ out,
    const int* __restrict__ flag)
{
  const int Cin = 128, Cout = 64;
  const int PP = 33;
  __shared__ __align__(16) float sW[8192];
  __shared__ float sIn[32 * PP];
  int fl = flag[0];
  int bid = blockIdx.x;
  int cp = bid & 15, n = bid >> 4;
  int co0 = cp * 4;
  int tid = threadIdx.x;
  for (int i = tid; i < 8192; i += 256) {
    int cl = i >> 11, rem = i & 2047;
    int ci = rem >> 4, k = rem & 15;
    sW[i] = ldg_in(w, (ci * Cout + co0 + cl) * 16 + k, fl);
  }
  int qa = tid >> 3;
  int qb0 = (tid & 7) * 4;
  float bv0 = ldg_in(bias, co0, fl), bv1 = ldg_in(bias, co0 + 1, fl);
  float bv2 = ldg_in(bias, co0 + 2, fl), bv3 = ldg_in(bias, co0 + 3, fl);
  DECL16(u, bv0) DECL16(v, bv1) DECL16(y, bv2) DECL16(z, bv3)
  const float* ip = in + (size_t)n * Cin * 1024;
  bool vm = qa >= 1, vd = qa + 1 < 32;
  bool vl = qb0 > 0, vr = qb0 < 28;
  for (int ci = 0; ci < Cin; ++ci) {
    __syncthreads();
    {
      float4 g = ((const float4*)(ip + ci * 1024))[tid];
      float* dst = sIn + (tid >> 3) * PP + (tid & 7) * 4;
      dst[0] = g.x; dst[1] = g.y; dst[2] = g.z; dst[3] = g.w;
    }
    __syncthreads();
    const float* rm = sIn + (qa - 1) * PP;
    const float* rc = sIn + qa * PP;
    const float* rd = sIn + (qa + 1) * PP;
    float m0 = (vm && vl) ? rm[qb0 - 1] : 0.f;
    float m1 = vm ? rm[qb0] : 0.f, m2 = vm ? rm[qb0 + 1] : 0.f;
    float m3 = vm ? rm[qb0 + 2] : 0.f, m4 = vm ? rm[qb0 + 3] : 0.f;
    float m5 = (vm && vr) ? rm[qb0 + 4] : 0.f;
    float c0 = vl ? rc[qb0 - 1] : 0.f;
    float c1 = rc[qb0], c2 = rc[qb0 + 1], c3 = rc[qb0 + 2], c4 = rc[qb0 + 3];
    float c5 = vr ? rc[qb0 + 4] : 0.f;
    float d0 = (vd && vl) ? rd[qb0 - 1] : 0.f;
    float d1 = vd ? rd[qb0] : 0.f, d2 = vd ? rd[qb0 + 1] : 0.f;
    float d3 = vd ? rd[qb0 + 2] : 0.f, d4 = vd ? rd[qb0 + 3] : 0.f;
    float d5 = (vd && vr) ? rd[qb0 + 4] : 0.f;
    float w00, w01, w02, w03, w10, w11, w12, w13, w20, w21, w22, w23, w30, w31, w32, w33;
    { LOADW16V(sW + ci * 16)        CT_CO(u) }
    { LOADW16V(sW + 2048 + ci * 16) CT_CO(v) }
    { LOADW16V(sW + 4096 + ci * 16) CT_CO(y) }
    { LOADW16V(sW + 6144 + ci * 16) CT_CO(z) }
  }
  float* op = out + ((size_t)(n * Cout + co0) * 64 + 2 * qa) * 64 + 2 * qb0;
  CT_STORE(u, op, 64) op += (size_t)64 * 64;
  CT_STORE(v, op, 64) op += (size_t)64 * 64;
  CT_STORE(y, op, 64) op += (size_t)64 * 64;
  CT_STORE(z, op, 64)
}

// ---------------- up2: convT s2 k4, 64ch 64x64 -> 3ch 128x128, all 3 co/thread ----------------
__global__ __launch_bounds__(256) void k_convT_up2(
    const float* __restrict__ in, const void* __restrict__ w,
    const void* __restrict__ bias, float* __restrict__ out,
    const int* __restrict__ flag)
{
  const int Cin = 64;
  __shared__ __align__(16) float sW[3072];
  int fl = flag[0];
  int bid = blockIdx.x;
  int s = bid & 7, n = bid >> 3;
  int tid = threadIdx.x;
  for (int i = tid; i < 3072; i += 256)
    sW[i] = ldg_in(w, i, fl);
  __syncthreads();
  int qa = s * 8 + (tid >> 5);
  int qb0 = (tid & 31) * 2;
  float bp = ldg_in(bias, 0, fl), bq = ldg_in(bias, 1, fl), br = ldg_in(bias, 2, fl);
  float pA0 = bp, pA1 = bp, pB0 = bp, pB1 = bp, pC0 = bp, pC1 = bp, pD0 = bp, pD1 = bp;
  float qA0 = bq, qA1 = bq, qB0_ = bq, qB1 = bq, qC0 = bq, qC1 = bq, qD0 = bq, qD1 = bq;
  float rA0 = br, rA1 = br, rB0 = br, rB1 = br, rC0 = br, rC1 = br, rD0 = br, rD1 = br;
  const float* ip = in + (size_t)n * Cin * 4096;
  bool vm = qa >= 1, vd = qa + 1 < 64;
  bool vl = qb0 > 0, vr = qb0 < 62;
  for (int ci = 0; ci < Cin; ++ci) {
    const float* p = ip + ci * 4096;
    const float* rm = p + (qa - 1) * 64;
    const float* rc = p + qa * 64;
    const float* rd = p + (qa + 1) * 64;
    float m0 = (vm && vl) ? rm[qb0 - 1] : 0.f;
    float m1 = vm ? rm[qb0] : 0.f, m2 = vm ? rm[qb0 + 1] : 0.f;
    float m3 = (vm && vr) ? rm[qb0 + 2] : 0.f;
    float c0 = vl ? rc[qb0 - 1] : 0.f;
    float c1 = rc[qb0], c2 = rc[qb0 + 1];
    float c3 = vr ? rc[qb0 + 2] : 0.f;
    float d0 = (vd && vl) ? rd[qb0 - 1] : 0.f;
    float d1 = vd ? rd[qb0] : 0.f, d2 = vd ? rd[qb0 + 1] : 0.f;
    float d3 = (vd && vr) ? rd[qb0 + 2] : 0.f;
    float w00, w01, w02, w03, w10, w11, w12, w13, w20, w21, w22, w23, w30, w31, w32, w33;
    {
      LOADW16V(sW + ci * 48)
      CT_J(pA0, pB0, pC0, pD0, m0, m1, m2, c0, c1, c2, d0, d1, d2)
      CT_J(pA1, pB1, pC1, pD1, m1, m2, m3, c1, c2, c3, d1, d2, d3)
    }
    {
      LOADW16V(sW + ci * 48 + 16)
      CT_J(qA0, qB0_, qC0, qD0, m0, m1, m2, c0, c1, c2, d0, d1, d2)
      CT_J(qA1, qB1, qC1, qD1, m1, m2, m3, c1, c2, c3, d1, d2, d3)
    }
    {
      LOADW16V(sW + ci * 48 + 32)
      CT_J(rA0, rB0, rC0, rD0, m0, m1, m2, c0, c1, c2, d0, d1, d2)
      CT_J(rA1, rB1, rC1, rD1, m1, m2, m3, c1, c2, c3, d1, d2, d3)
    }
  }
  float* op = out + ((size_t)(n * 3 + 0) * 128 + 2 * qa) * 128 + 2 * qb0;
  op[0] = pA0; op[1] = pB0; op[2] = pA1; op[3] = pB1;
  op[128] = pC0; op[129] = pD0; op[130] = pC1; op[131] = pD1;
  op += (size_t)128 * 128;
  op[0] = qA0; op[1] = qB0_; op[2] = qA1; op[3] = qB1;
  op[128] = qC0; op[129] = qD0; op[130] = qC1; op[131] = qD1;
  op += (size_t)128 * 128;
  op[0] = rA0; op[1] = rB0; op[2] = rA1; op[3] = rB1;
  op[128] = rC0; op[129] = rD0; op[130] = rC1; op[131] = rD1;
}

// ---------------- VQ phase 1: per-chunk argmin (256 codebook rows per chunk) ----------------
__global__ __launch_bounds__(256) void k_vq1(
    const float* __restrict__ z, const void* __restrict__ emb,
    const int* __restrict__ flag, float* __restrict__ distb, float* __restrict__ idxb)
{
  const int PE = 65;
  __shared__ float sE[128 * PE];
  __shared__ float sEE[128];
  int fl = flag[0];
  int tid = threadIdx.x;
  int bid = blockIdx.x;
  int ch = bid & 3, vb = bid >> 2;
  int n = vb * 256 + tid;
  int nb = n >> 10, p = n & 1023;
  const float* zp = z + nb * 65536 + p;
  float zv[64];
  float zz = 0.f;
  #pragma unroll
  for (int d = 0; d < 64; ++d) { zv[d] = zp[d * 1024]; zz = fmaf(zv[d], zv[d], zz); }
  float best = 3.4e38f; int bidx = ch * 256;
  for (int kb = ch * 2; kb < ch * 2 + 2; ++kb) {
    __syncthreads();
    for (int i = tid; i < 8192; i += 256)
      sE[(i >> 6) * PE + (i & 63)] = ldg_in(emb, kb * 8192 + i, fl);
    __syncthreads();
    if (tid < 128) {
      const float* ep = sE + tid * PE;
      float s = 0.f;
      #pragma unroll
      for (int d = 0; d < 64; ++d) s = fmaf(ep[d], ep[d], s);
      sEE[tid] = s;
    }
    __syncthreads();
    for (int k = 0; k < 128; ++k) {
      const float* ep = sE + k * PE;
      float dot = 0.f;
      #pragma unroll
      for (int d = 0; d < 64; ++d) dot = fmaf(zv[d], ep[d], dot);
      float dist = zz + sEE[k] - 2.f * dot;
      if (dist < best) { best = dist; bidx = kb * 128 + k; }  // strict <: first min wins
    }
  }
  distb[ch * 65536 + n] = best;
  idxb[ch * 65536 + n] = (float)bidx;
}

// ---------------- VQ phase 2: combine chunks, gather zq, loss partials ----------------
__global__ __launch_bounds__(256) void k_vq2(
    const float* __restrict__ z, const void* __restrict__ emb,
    const int* __restrict__ flag, const float* __restrict__ distb,
    const float* __restrict__ idxb, float* __restrict__ zq,
    float* __restrict__ idx_out, float* __restrict__ lossp, int lossbase)
{
  __shared__ float wsum[4];
  int fl = flag[0];
  int tid = threadIdx.x;
  int n = blockIdx.x * 256 + tid;
  float best = distb[n];
  int bidx = (int)idxb[n];
  #pragma unroll
  for (int c = 1; c < 4; ++c) {
    float d = distb[c * 65536 + n];
    if (d < best) { best = d; bidx = (int)idxb[c * 65536 + n]; }  // earlier chunk wins ties
  }
  idx_out[n] = (float)bidx;
  int nb = n >> 10, p = n & 1023;
  const float* zp = z + nb * 65536 + p;
  float* qp = zq + nb * 65536 + p;
  float ls = 0.f;
  #pragma unroll
  for (int d = 0; d < 64; ++d) {
    float e = ldg_in(emb, bidx * 64 + d, fl);
    float zvd = zp[d * 1024];
    qp[d * 1024] = e;
    float df = e - zvd;
    ls = fmaf(df, df, ls);
  }
  #pragma unroll
  for (int off = 32; off > 0; off >>= 1) ls += __shfl_down(ls, off);
  if ((tid & 63) == 0) wsum[tid >> 6] = ls;
  __syncthreads();
  if (tid == 0) lossp[lossbase + blockIdx.x] = wsum[0] + wsum[1] + wsum[2] + wsum[3];
}

__global__ void k_loss_final(const float* __restrict__ lossp, float* __restrict__ out) {
  if (threadIdx.x == 0 && blockIdx.x == 0) {
    float s = 0.f;
    for (int i = 0; i < 256; ++i) s += lossp[i];
    float L = s * (1.f / 4194304.f);
    out[R_RECON + 0] = L;
    out[R_RECON + 1] = L;
  }
}

extern "C" void kernel_launch(void* const* d_in, const int* in_sizes, int n_in,
                              void* d_out, int out_size, void* d_ws, size_t ws_size,
                              hipStream_t stream)
{
  float* out = (float*)d_out;          // fp32 output (established R8-R10)

  float* F = (float*)d_ws;
  float* LOSSP = F;
  int* FLAG = (int*)(F + 256);
  float* VQD = F + 272;
  float* VQI = VQD + 262144;
  float* A = VQI + 262144;

  int Bc = 64;
  while (Bc > 1 && 4ull * (272ull + 524288ull + (size_t)Bc * 393216ull) > ws_size) Bc >>= 1;
  float* H1 = A;
  float* H2 = A + (size_t)Bc * 262144;
  float* H3 = A;
  float* T  = A + (size_t)Bc * 131072;
  float* Z  = A + (size_t)Bc * 163840;
  float* D1 = H2;
  float* D2 = A;

  const void* patch = d_in[0];
  const void* ew1 = d_in[1];  const void* eb1 = d_in[2];
  const void* ew2 = d_in[3];  const void* eb2 = d_in[4];
  const void* ew3 = d_in[5];  const void* eb3 = d_in[6];
  const void* er1a = d_in[7]; const void* er1b = d_in[8];
  const void* er2a = d_in[9]; const void* er2b = d_in[10];
  const void* pqw = d_in[11]; const void* pqb = d_in[12];
  const void* emb = d_in[13];
  const void* dw1 = d_in[14]; const void* db1 = d_in[15];
  const void* dr1a = d_in[16]; const void* dr1b = d_in[17];
  const void* dr2a = d_in[18]; const void* dr2b = d_in[19];
  const void* dw2 = d_in[20]; const void* db2 = d_in[21];
  const void* dw3 = d_in[22]; const void* db3 = d_in[23];

  k_detect<<<1, 256, 0, stream>>>((const u16*)patch, FLAG);

  int NC = 64 / Bc;
  for (int c = 0; c < NC; ++c) {
    int b0 = c * Bc;

    // ---- encoder ----
    k_enc1<<<Bc * 128, 256, 0, stream>>>(patch, ew1, eb1, H1, FLAG, b0);
    k_enc2<<<Bc * 32, 256, 0, stream>>>(H1, ew2, eb2, H2, FLAG);
    k_conv3x3_v4<false, false, false, true><<<Bc * 32, 256, 0, stream>>>(H2, ew3, eb3, H3, FLAG, 128, 128);
    k_conv3x3_v4<true, false, true, false><<<Bc * 8, 256, 0, stream>>>(H3, er1a, nullptr, T, FLAG, 128, 32);
    k_conv1x1_t4<true, false, false><<<Bc * 32, 256, 0, stream>>>(T, er1b, nullptr, H3, FLAG, 32, 128);
    k_conv3x3_v4<true, false, true, false><<<Bc * 8, 256, 0, stream>>>(H3, er2a, nullptr, T, FLAG, 128, 32);
    k_conv1x1_t4<true, false, true><<<Bc * 32, 256, 0, stream>>>(T, er2b, nullptr, H3, FLAG, 32, 128);
    k_conv1x1_t4<false, true, false><<<Bc * 16, 256, 0, stream>>>(H3, pqw, pqb, Z, FLAG, 128, 64);

    // ---- VQ ----
    k_vq1<<<Bc * 16, 256, 0, stream>>>(Z, emb, FLAG, VQD, VQI);
    k_vq2<<<Bc * 4, 256, 0, stream>>>(Z, emb, FLAG, VQD, VQI, Z,
                                      out + R_RECON + 2 + (size_t)b0 * 1024, LOSSP, b0 * 4);

    // ---- decoder ----
    k_conv3x3_v4<false, true, false, true><<<Bc * 32, 256, 0, stream>>>(Z, dw1, db1, D1, FLAG, 64, 128);
    k_conv3x3_v4<true, false, true, false><<<Bc * 8, 256, 0, stream>>>(D1, dr1a, nullptr, T, FLAG, 128, 32);
    k_conv1x1_t4<true, false, false><<<Bc * 32, 256, 0, stream>>>(T, dr1b, nullptr, D1, FLAG, 32, 128);
    k_conv3x3_v4<true, false, true, false><<<Bc * 8, 256, 0, stream>>>(D1, dr2a, nullptr, T, FLAG, 128, 32);
    k_conv1x1_t4<true, false, true><<<Bc * 32, 256, 0, stream>>>(T, dr2b, nullptr, D1, FLAG, 32, 128);
    k_convT_up1<<<Bc * 16, 256, 0, stream>>>(D1, dw2, db2, D2, FLAG);
    k_convT_up2<<<Bc * 8, 256, 0, stream>>>(D2, dw3, db3, out + (size_t)b0 * 49152, FLAG);
  }

  k_loss_final<<<1, 64, 0, stream>>>(LOSSP, out);
}